// Round 1
// baseline (2089.116 us; speedup 1.0000x reference)
//
#include <hip/hip_runtime.h>
#include <math.h>

// ---------------- workspace layout (bytes) ----------------
#define OFF_AGGR1   0            // 1,000,000 f32
#define OFF_X1      4000000      // 1,000,000 f32
#define OFF_KA      8000000      // 1,000,000 u32
#define OFF_VA      12000000     // 1,000,000 u32
#define OFF_KB      16000000     // 1,000,000 u32
#define OFF_VB      20000000     // 1,000,000 u32
#define OFF_NIDX    24000000     // 1,000,000 i32
#define OFF_HIST    28000000     // up to 245*256 u32
#define OFF_OFFS    28262144     // up to 245*256 u32
#define OFF_STATS   28524288     // [0,1]=conv1 sum/sumsq, [2,3]=conv2
#define OFF_CONST   28524352     // c1,c2,c3
#define OFF_X2      29000000     // 100,000 f32
#define OFF_AGGR2   29400000     // 100,000 f32
#define OFF_X3      29800000     // 100,000 f32
#define OFF_X4      30200000     // 10,000 f32
#define OFF_X5      30240000     // 2,500 f32

#define CHUNK 4096               // elements per radix-sort block

__device__ __forceinline__ float sigmoidf_(float x) {
    if (x >= 0.0f) { float e = expf(-x); return 1.0f / (1.0f + e); }
    float e = expf(x); return e / (1.0f + e);
}
__device__ __forceinline__ float softplusf_(float x) {
    return fmaxf(x, 0.0f) + log1pf(expf(-fabsf(x)));
}
__device__ __forceinline__ unsigned key_desc(float f) {
    unsigned u = __float_as_uint(f);
    unsigned ka = (u & 0x80000000u) ? ~u : (u | 0x80000000u);  // ascending map
    return ~ka;                                                 // descending
}

// ---------------- score constants c = sum(w)/norm(w) ----------------
__global__ void k_consts(const float* __restrict__ pw1, const float* __restrict__ pw2,
                         const float* __restrict__ pw3, float* __restrict__ consts,
                         int n1, int n2, int n3) {
    const float* w; int n;
    if (blockIdx.x == 0)      { w = pw1; n = n1; }
    else if (blockIdx.x == 1) { w = pw2; n = n2; }
    else                      { w = pw3; n = n3; }
    __shared__ float s1[256], s2[256];
    float a = 0.f, b = 0.f;
    for (int i = threadIdx.x; i < n; i += 256) { float v = w[i]; a += v; b += v * v; }
    s1[threadIdx.x] = a; s2[threadIdx.x] = b; __syncthreads();
    for (int o = 128; o > 0; o >>= 1) {
        if (threadIdx.x < o) { s1[threadIdx.x] += s1[threadIdx.x + o]; s2[threadIdx.x] += s2[threadIdx.x + o]; }
        __syncthreads();
    }
    if (threadIdx.x == 0) consts[blockIdx.x] = s1[0] / sqrtf(s2[0]);
}

// ---------------- cgconv edge kernels ----------------
__global__ void k_conv1(const float* __restrict__ x, const float* __restrict__ ea,
                        const int* __restrict__ src, const int* __restrict__ dst,
                        const float* __restrict__ Wf, const float* __restrict__ bf,
                        const float* __restrict__ Ws, const float* __restrict__ bs,
                        float* __restrict__ aggr, int E) {
    int e = blockIdx.x * blockDim.x + threadIdx.x;
    if (e >= E) return;
    int s = src[e], d = dst[e];
    float xd = x[d], xs = x[s], a = ea[e];
    float f = xd * Wf[0] + xs * Wf[1] + a * Wf[2] + bf[0];
    float g = xd * Ws[0] + xs * Ws[1] + a * Ws[2] + bs[0];
    atomicAdd(&aggr[d], sigmoidf_(f) * softplusf_(g));
}

__global__ void k_conv2(const float* __restrict__ x2, const float* __restrict__ ea,
                        const int* __restrict__ src, const int* __restrict__ dst,
                        const int* __restrict__ nidx,
                        const float* __restrict__ Wf, const float* __restrict__ bf,
                        const float* __restrict__ Ws, const float* __restrict__ bs,
                        float* __restrict__ aggr, int E) {
    int e = blockIdx.x * blockDim.x + threadIdx.x;
    if (e >= E) return;
    int ns = nidx[src[e]], nd = nidx[dst[e]];
    if ((ns | nd) < 0) return;
    float xd = x2[nd], xs = x2[ns], a = ea[e];
    float f = xd * Wf[0] + xs * Wf[1] + a * Wf[2] + bf[0];
    float g = xd * Ws[0] + xs * Ws[1] + a * Ws[2] + bs[0];
    atomicAdd(&aggr[nd], sigmoidf_(f) * softplusf_(g));
}

// ---------------- sum / sumsq reduction ----------------
__global__ void k_stats(const float* __restrict__ a, int n, float* __restrict__ stats) {
    float s = 0.f, q = 0.f;
    int stride = gridDim.x * blockDim.x;
    for (int i = blockIdx.x * blockDim.x + threadIdx.x; i < n; i += stride) {
        float v = a[i]; s += v; q += v * v;
    }
    __shared__ float s1[256], s2[256];
    s1[threadIdx.x] = s; s2[threadIdx.x] = q; __syncthreads();
    for (int o = 128; o > 0; o >>= 1) {
        if (threadIdx.x < o) { s1[threadIdx.x] += s1[threadIdx.x + o]; s2[threadIdx.x] += s2[threadIdx.x + o]; }
        __syncthreads();
    }
    if (threadIdx.x == 0) { atomicAdd(&stats[0], s1[0]); atomicAdd(&stats[1], s2[0]); }
}

// ---------------- batchnorm (batch stats, biased var) + residual ----------------
__global__ void k_bn(const float* __restrict__ aggr, const float* __restrict__ xin,
                     const float* __restrict__ stats, const float* __restrict__ g,
                     const float* __restrict__ be, float* __restrict__ xout,
                     int n, float invn) {
    int i = blockIdx.x * blockDim.x + threadIdx.x;
    if (i >= n) return;
    float mean = stats[0] * invn;
    float var  = stats[1] * invn - mean * mean;
    float inv  = 1.0f / sqrtf(var + 1e-5f);
    xout[i] = g[0] * (aggr[i] - mean) * inv + be[0] + xin[i];
}

// ---------------- radix sort: init keys/vals ----------------
__global__ void k_sortinit(const float* __restrict__ xv, const float* __restrict__ consts, int ci,
                           unsigned* __restrict__ keys, unsigned* __restrict__ vals, int n) {
    int i = blockIdx.x * blockDim.x + threadIdx.x;
    if (i >= n) return;
    float s = tanhf(xv[i] * consts[ci]);
    keys[i] = key_desc(s);
    vals[i] = (unsigned)i;
}

// ---------------- radix sort: per-chunk histogram ----------------
__global__ void k_hist(const unsigned* __restrict__ keys, unsigned* __restrict__ hist,
                       int n, int shift) {
    __shared__ unsigned h[256];
    h[threadIdx.x] = 0;
    __syncthreads();
    int base = blockIdx.x * CHUNK;
    int end = base + CHUNK; if (end > n) end = n;
    for (int i = base + threadIdx.x; i < end; i += 256)
        atomicAdd(&h[(keys[i] >> shift) & 255u], 1u);
    __syncthreads();
    hist[blockIdx.x * 256 + threadIdx.x] = h[threadIdx.x];
}

// ---------------- radix sort: digit/block offset scan (1 block, 256 thr) ----------------
__global__ void k_scan(const unsigned* __restrict__ hist, unsigned* __restrict__ offs, int G) {
    __shared__ unsigned tot[256];
    int d = threadIdx.x;
    unsigned run = 0;
    for (int g = 0; g < G; ++g) {
        unsigned h = hist[g * 256 + d];
        offs[g * 256 + d] = run;
        run += h;
    }
    unsigned mine = run;
    tot[d] = run;
    __syncthreads();
    for (int o = 1; o < 256; o <<= 1) {
        unsigned t = (d >= o) ? tot[d - o] : 0u;
        __syncthreads();
        tot[d] += t;
        __syncthreads();
    }
    unsigned base = tot[d] - mine;   // exclusive digit base
    for (int g = 0; g < G; ++g) offs[g * 256 + d] += base;
}

// ---------------- radix sort: stable scatter (1 wave per block) ----------------
__global__ void __launch_bounds__(64) k_scatter(const unsigned* __restrict__ keys,
                                                const unsigned* __restrict__ vals,
                                                unsigned* __restrict__ okeys,
                                                unsigned* __restrict__ ovals,
                                                const unsigned* __restrict__ offs,
                                                int n, int shift) {
    __shared__ unsigned run[256];
    __shared__ unsigned offl[256];
    int lane = threadIdx.x;
    for (int i = lane; i < 256; i += 64) { run[i] = 0; offl[i] = offs[blockIdx.x * 256 + i]; }
    __syncthreads();
    int base = blockIdx.x * CHUNK;
    int i0 = base + lane;
    bool a0 = i0 < n;
    unsigned k = a0 ? keys[i0] : 0u;
    unsigned v = a0 ? vals[i0] : 0u;
    const int SLOTS = CHUNK / 64;
    for (int slot = 0; slot < SLOTS; ++slot) {
        int inext = base + (slot + 1) * 64 + lane;
        bool an = (slot + 1 < SLOTS) && (inext < n);
        unsigned kn = an ? keys[inext] : 0u;
        unsigned vn = an ? vals[inext] : 0u;
        bool active = (base + slot * 64 + lane) < n;
        unsigned d = (k >> shift) & 255u;
        unsigned long long bb[8];
        unsigned long long amask = __ballot(active);
        #pragma unroll
        for (int bit = 0; bit < 8; ++bit) bb[bit] = __ballot(active && ((d >> bit) & 1u));
        unsigned long long m = amask;
        #pragma unroll
        for (int bit = 0; bit < 8; ++bit) m &= ((d >> bit) & 1u) ? bb[bit] : ~bb[bit];
        unsigned long long lt = (1ull << lane) - 1ull;
        unsigned rk = (unsigned)__popcll(m & lt);
        unsigned lrank = 0;
        if (active) lrank = run[d] + rk;
        __syncthreads();
        #pragma unroll
        for (int j = 0; j < 4; ++j) {
            unsigned dd = (unsigned)lane + j * 64u;
            unsigned long long mm = amask;
            #pragma unroll
            for (int bit = 0; bit < 8; ++bit) mm &= ((dd >> bit) & 1u) ? bb[bit] : ~bb[bit];
            run[dd] += (unsigned)__popcll(mm);
        }
        if (active) {
            unsigned pos = offl[d] + lrank;
            okeys[pos] = k;
            ovals[pos] = v;
        }
        __syncthreads();
        k = kn; v = vn;
    }
}

// ---------------- pool gather: x_new = x[perm]*score[perm]; optional new_idx ----------------
__global__ void k_pool(const unsigned* __restrict__ perm, const float* __restrict__ xin,
                       const float* __restrict__ consts, int ci,
                       float* __restrict__ xout, int* __restrict__ newidx, int k) {
    int r = blockIdx.x * blockDim.x + threadIdx.x;
    if (r >= k) return;
    unsigned p = perm[r];
    float xv = xin[p];
    float s = tanhf(xv * consts[ci]);
    xout[r] = xv * s;
    if (newidx) newidx[p] = r;
}

// ---------------- final MLP + log_softmax ----------------
__global__ void k_mlp(const float* __restrict__ x5, const float* __restrict__ Wl1,
                      const float* __restrict__ bl1, const float* __restrict__ Wl2,
                      const float* __restrict__ bl2, float* __restrict__ out, int n) {
    int i = blockIdx.x * blockDim.x + threadIdx.x;
    if (i >= n) return;
    float xv = x5[i];
    float l0 = bl2[0], l1 = bl2[1];
    #pragma unroll
    for (int j = 0; j < 8; ++j) {
        float h = fmaxf(xv * Wl1[j] + bl1[j], 0.0f);
        l0 += h * Wl2[2 * j];
        l1 += h * Wl2[2 * j + 1];
    }
    float mx = fmaxf(l0, l1);
    float lse = mx + logf(expf(l0 - mx) + expf(l1 - mx));
    out[2 * i]     = l0 - lse;
    out[2 * i + 1] = l1 - lse;
}

// ---------------- host-side radix sort driver ----------------
static void sort_pairs(hipStream_t stream, unsigned* kA, unsigned* vA,
                       unsigned* kB, unsigned* vB, unsigned* hist, unsigned* offs, int n) {
    int G = (n + CHUNK - 1) / CHUNK;
    unsigned *ki = kA, *vi = vA, *ko = kB, *vo = vB;
    for (int p = 0; p < 4; ++p) {
        int shift = p * 8;
        k_hist<<<G, 256, 0, stream>>>(ki, hist, n, shift);
        k_scan<<<1, 256, 0, stream>>>(hist, offs, G);
        k_scatter<<<G, 64, 0, stream>>>(ki, vi, ko, vo, offs, n, shift);
        unsigned* t;
        t = ki; ki = ko; ko = t;
        t = vi; vi = vo; vo = t;
    }
    // 4 passes (even): sorted result back in kA/vA
}

extern "C" void kernel_launch(void* const* d_in, const int* in_sizes, int n_in,
                              void* d_out, int out_size, void* d_ws, size_t ws_size,
                              hipStream_t stream) {
    const float* x   = (const float*)d_in[0];
    const float* ea  = (const float*)d_in[1];
    const int*   src = (const int*)d_in[2];
    const int*   dst = (const int*)d_in[3];
    // d_in[4] = batch (unused: single graph)
    const float *Wf1 = (const float*)d_in[5],  *bf1 = (const float*)d_in[6];
    const float *Ws1 = (const float*)d_in[7],  *bs1 = (const float*)d_in[8];
    const float *g1  = (const float*)d_in[9],  *be1 = (const float*)d_in[10];
    const float *Wf2 = (const float*)d_in[11], *bf2 = (const float*)d_in[12];
    const float *Ws2 = (const float*)d_in[13], *bs2 = (const float*)d_in[14];
    const float *g2  = (const float*)d_in[15], *be2 = (const float*)d_in[16];
    const float *pw1 = (const float*)d_in[17], *pw2 = (const float*)d_in[18], *pw3 = (const float*)d_in[19];
    const float *Wl1 = (const float*)d_in[20], *bl1 = (const float*)d_in[21];
    const float *Wl2 = (const float*)d_in[22], *bl2 = (const float*)d_in[23];

    const int N  = in_sizes[0];
    const int E  = in_sizes[1];
    const int K1 = 100000, K2 = 10000, K3 = 2500;

    char* ws = (char*)d_ws;
    float*    aggr1  = (float*)(ws + OFF_AGGR1);
    float*    x1     = (float*)(ws + OFF_X1);
    unsigned* kA     = (unsigned*)(ws + OFF_KA);
    unsigned* vA     = (unsigned*)(ws + OFF_VA);
    unsigned* kB     = (unsigned*)(ws + OFF_KB);
    unsigned* vB     = (unsigned*)(ws + OFF_VB);
    int*      nidx   = (int*)(ws + OFF_NIDX);
    unsigned* hist   = (unsigned*)(ws + OFF_HIST);
    unsigned* offs   = (unsigned*)(ws + OFF_OFFS);
    float*    stats  = (float*)(ws + OFF_STATS);
    float*    consts = (float*)(ws + OFF_CONST);
    float*    x2     = (float*)(ws + OFF_X2);
    float*    aggr2  = (float*)(ws + OFF_AGGR2);
    float*    x3     = (float*)(ws + OFF_X3);
    float*    x4     = (float*)(ws + OFF_X4);
    float*    x5     = (float*)(ws + OFF_X5);

    // zero/init state (harness does not re-poison between replays)
    hipMemsetAsync(aggr1, 0, (size_t)N * 4, stream);
    hipMemsetAsync(stats, 0, 64, stream);
    hipMemsetAsync(nidx, 0xFF, (size_t)N * 4, stream);   // -1
    hipMemsetAsync(aggr2, 0, (size_t)K1 * 4, stream);

    k_consts<<<3, 256, 0, stream>>>(pw1, pw2, pw3, consts,
                                    in_sizes[17], in_sizes[18], in_sizes[19]);

    // ---- cgconv 1 ----
    k_conv1<<<(E + 255) / 256, 256, 0, stream>>>(x, ea, src, dst, Wf1, bf1, Ws1, bs1, aggr1, E);
    k_stats<<<1024, 256, 0, stream>>>(aggr1, N, stats);
    k_bn<<<(N + 255) / 256, 256, 0, stream>>>(aggr1, x, stats, g1, be1, x1, N, 1.0f / (float)N);

    // ---- pool 1 : top 100K of 1M ----
    k_sortinit<<<(N + 255) / 256, 256, 0, stream>>>(x1, consts, 0, kA, vA, N);
    sort_pairs(stream, kA, vA, kB, vB, hist, offs, N);
    k_pool<<<(K1 + 255) / 256, 256, 0, stream>>>(vA, x1, consts, 0, x2, nidx, K1);

    // ---- cgconv 2 (filtered edges) ----
    k_conv2<<<(E + 255) / 256, 256, 0, stream>>>(x2, ea, src, dst, nidx, Wf2, bf2, Ws2, bs2, aggr2, E);
    k_stats<<<256, 256, 0, stream>>>(aggr2, K1, stats + 2);
    k_bn<<<(K1 + 255) / 256, 256, 0, stream>>>(aggr2, x2, stats + 2, g2, be2, x3, K1, 1.0f / (float)K1);

    // ---- pool 2 : top 10K of 100K (edges dead downstream) ----
    k_sortinit<<<(K1 + 255) / 256, 256, 0, stream>>>(x3, consts, 1, kA, vA, K1);
    sort_pairs(stream, kA, vA, kB, vB, hist, offs, K1);
    k_pool<<<(K2 + 255) / 256, 256, 0, stream>>>(vA, x3, consts, 1, x4, (int*)nullptr, K2);

    // ---- pool 3 : top 2500 of 10K ----
    k_sortinit<<<(K2 + 255) / 256, 256, 0, stream>>>(x4, consts, 2, kA, vA, K2);
    sort_pairs(stream, kA, vA, kB, vB, hist, offs, K2);
    k_pool<<<(K3 + 255) / 256, 256, 0, stream>>>(vA, x4, consts, 2, x5, (int*)nullptr, K3);

    // ---- MLP + log_softmax ----
    k_mlp<<<(K3 + 255) / 256, 256, 0, stream>>>(x5, Wl1, bl1, Wl2, bl2, (float*)d_out, K3);
}

// Round 2
// 1802.002 us; speedup vs baseline: 1.1593x; 1.1593x over previous
//
#include <hip/hip_runtime.h>
#include <math.h>

#define CHUNK 2048               // elements per radix-sort block
#define EC    32768              // edges per binning block
#define NBIN  1024               // conv1 dst buckets (bin = dst >> 10)

__device__ __forceinline__ float sigmoidf_(float x) {
    if (x >= 0.0f) { float e = expf(-x); return 1.0f / (1.0f + e); }
    float e = expf(x); return e / (1.0f + e);
}
__device__ __forceinline__ float softplusf_(float x) {
    return fmaxf(x, 0.0f) + log1pf(expf(-fabsf(x)));
}
__device__ __forceinline__ unsigned key_desc(float f) {
    unsigned u = __float_as_uint(f);
    unsigned ka = (u & 0x80000000u) ? ~u : (u | 0x80000000u);  // ascending map
    return ~ka;                                                 // descending
}
__device__ __forceinline__ float edge_m(float xd, float xs, float a,
                                        const float* Wf, const float* bf,
                                        const float* Ws, const float* bs) {
    float f = xd * Wf[0] + xs * Wf[1] + a * Wf[2] + bf[0];
    float g = xd * Ws[0] + xs * Ws[1] + a * Ws[2] + bs[0];
    return sigmoidf_(f) * softplusf_(g);
}

// ---------------- score constants c = sum(w)/norm(w) ----------------
__global__ void k_consts(const float* __restrict__ pw1, const float* __restrict__ pw2,
                         const float* __restrict__ pw3, float* __restrict__ consts,
                         int n1, int n2, int n3) {
    const float* w; int n;
    if (blockIdx.x == 0)      { w = pw1; n = n1; }
    else if (blockIdx.x == 1) { w = pw2; n = n2; }
    else                      { w = pw3; n = n3; }
    __shared__ float s1[256], s2[256];
    float a = 0.f, b = 0.f;
    for (int i = threadIdx.x; i < n; i += 256) { float v = w[i]; a += v; b += v * v; }
    s1[threadIdx.x] = a; s2[threadIdx.x] = b; __syncthreads();
    for (int o = 128; o > 0; o >>= 1) {
        if (threadIdx.x < o) { s1[threadIdx.x] += s1[threadIdx.x + o]; s2[threadIdx.x] += s2[threadIdx.x + o]; }
        __syncthreads();
    }
    if (threadIdx.x == 0) consts[blockIdx.x] = s1[0] / sqrtf(s2[0]);
}

// ============== conv1: binned (atomic-free) segment sum ==============
// Phase A: per-block histogram of dst>>10 over an edge chunk
__global__ void k_ehist(const int* __restrict__ dst, unsigned* __restrict__ ehist,
                        int e0, int e1) {
    __shared__ unsigned h[NBIN];
    for (int i = threadIdx.x; i < NBIN; i += 256) h[i] = 0;
    __syncthreads();
    int base = e0 + blockIdx.x * EC;
    int end = base + EC; if (end > e1) end = e1;
    for (int i = base + threadIdx.x; i < end; i += 256)
        atomicAdd(&h[((unsigned)dst[i]) >> 10], 1u);
    __syncthreads();
    for (int i = threadIdx.x; i < NBIN; i += 256)
        ehist[blockIdx.x * NBIN + i] = h[i];
}

// generic scanA: one block per digit d (gridDim.x = ND); computes within-digit
// exclusive prefix over blocks g -> offs[g*ND+d]; writes digit total tot[d]
__global__ void k_scanA(const unsigned* __restrict__ hist, unsigned* __restrict__ offs,
                        unsigned* __restrict__ tot, int G) {
    int d = blockIdx.x, ND = gridDim.x, t = threadIdx.x;
    __shared__ unsigned s[256];
    unsigned carry = 0;
    for (int tile = 0; tile * 256 < G; ++tile) {
        int g = tile * 256 + t;
        unsigned v = (g < G) ? hist[(size_t)g * ND + d] : 0u;
        s[t] = v; __syncthreads();
        for (int o = 1; o < 256; o <<= 1) {
            unsigned u = (t >= o) ? s[t - o] : 0u;
            __syncthreads();
            s[t] += u; __syncthreads();
        }
        if (g < G) offs[(size_t)g * ND + d] = s[t] - v + carry;
        unsigned tl = s[255]; __syncthreads();
        carry += tl;
    }
    if (t == 0) tot[d] = carry;
}

// generic scanB: single block; exclusive scan of tot[ND] -> base[ND], base[ND]=total
__global__ void k_scanB(const unsigned* __restrict__ tot, unsigned* __restrict__ base, int ND) {
    __shared__ unsigned s[256];
    int t = threadIdx.x;
    unsigned carry = 0;
    for (int tile = 0; tile * 256 < ND; ++tile) {
        int d = tile * 256 + t;
        unsigned v = (d < ND) ? tot[d] : 0u;
        s[t] = v; __syncthreads();
        for (int o = 1; o < 256; o <<= 1) {
            unsigned u = (t >= o) ? s[t - o] : 0u;
            __syncthreads();
            s[t] += u; __syncthreads();
        }
        if (d < ND) base[d] = s[t] - v + carry;
        unsigned tl = s[255]; __syncthreads();
        carry += tl;
    }
    if (t == 0) base[ND] = carry;
}

// Phase C: compute m per edge, scatter (m, dst&1023) to bucket-contiguous storage
__global__ void k_escatter(const float* __restrict__ x, const float* __restrict__ ea,
                           const int* __restrict__ src, const int* __restrict__ dst,
                           const float* __restrict__ Wf, const float* __restrict__ bf,
                           const float* __restrict__ Ws, const float* __restrict__ bs,
                           const unsigned* __restrict__ eoffs, const unsigned* __restrict__ binBase,
                           float* __restrict__ bm, unsigned short* __restrict__ bdl,
                           int e0, int e1) {
    __shared__ unsigned cur[NBIN];
    for (int i = threadIdx.x; i < NBIN; i += 256)
        cur[i] = binBase[i] + eoffs[(size_t)blockIdx.x * NBIN + i];
    __syncthreads();
    int base = e0 + blockIdx.x * EC;
    int end = base + EC; if (end > e1) end = e1;
    float wf0 = Wf[0], wf1 = Wf[1], wf2 = Wf[2], b0 = bf[0];
    float ws0 = Ws[0], ws1 = Ws[1], ws2 = Ws[2], b1 = bs[0];
    for (int e = base + threadIdx.x; e < end; e += 256) {
        int s = src[e], d = dst[e];
        float xd = x[d], xs = x[s], a = ea[e];
        float f = xd * wf0 + xs * wf1 + a * wf2 + b0;
        float g = xd * ws0 + xs * ws1 + a * ws2 + b1;
        float m = sigmoidf_(f) * softplusf_(g);
        unsigned bin = ((unsigned)d) >> 10;
        unsigned pos = atomicAdd(&cur[bin], 1u);
        bm[pos] = m;
        bdl[pos] = (unsigned short)(d & 1023);
    }
}

// Phase D: per-bucket LDS aggregation -> aggr (no global atomics)
__global__ void k_eaggr(const float* __restrict__ bm, const unsigned short* __restrict__ bdl,
                        const unsigned* __restrict__ binBase, float* __restrict__ aggr,
                        int n, int accumulate) {
    __shared__ float acc[NBIN];
    for (int i = threadIdx.x; i < NBIN; i += 256) acc[i] = 0.0f;
    __syncthreads();
    int b = blockIdx.x;
    unsigned lo = binBase[b], hi = binBase[b + 1];
    for (unsigned i = lo + threadIdx.x; i < hi; i += 256)
        atomicAdd(&acc[bdl[i]], bm[i]);
    __syncthreads();
    int nbase = b << 10;
    for (int i = threadIdx.x; i < NBIN; i += 256) {
        int node = nbase + i;
        if (node < n) {
            float v = acc[i];
            if (accumulate) v += aggr[node];
            aggr[node] = v;
        }
    }
}

// ---------------- conv1 atomic fallback ----------------
__global__ void k_conv1(const float* __restrict__ x, const float* __restrict__ ea,
                        const int* __restrict__ src, const int* __restrict__ dst,
                        const float* __restrict__ Wf, const float* __restrict__ bf,
                        const float* __restrict__ Ws, const float* __restrict__ bs,
                        float* __restrict__ aggr, int E) {
    int e = blockIdx.x * blockDim.x + threadIdx.x;
    if (e >= E) return;
    int s = src[e], d = dst[e];
    atomicAdd(&aggr[d], edge_m(x[d], x[s], ea[e], Wf, bf, Ws, bs));
}

// ---------------- conv2: filtered edges, sparse atomics ----------------
__global__ void k_conv2(const float* __restrict__ x2, const float* __restrict__ ea,
                        const int* __restrict__ src, const int* __restrict__ dst,
                        const int* __restrict__ nidx,
                        const float* __restrict__ Wf, const float* __restrict__ bf,
                        const float* __restrict__ Ws, const float* __restrict__ bs,
                        float* __restrict__ aggr, int E) {
    int e = blockIdx.x * blockDim.x + threadIdx.x;
    if (e >= E) return;
    int ns = nidx[src[e]], nd = nidx[dst[e]];
    if ((ns | nd) < 0) return;
    atomicAdd(&aggr[nd], edge_m(x2[nd], x2[ns], ea[e], Wf, bf, Ws, bs));
}

// ---------------- sum / sumsq reduction ----------------
__global__ void k_stats(const float* __restrict__ a, int n, float* __restrict__ stats) {
    float s = 0.f, q = 0.f;
    int stride = gridDim.x * blockDim.x;
    for (int i = blockIdx.x * blockDim.x + threadIdx.x; i < n; i += stride) {
        float v = a[i]; s += v; q += v * v;
    }
    __shared__ float s1[256], s2[256];
    s1[threadIdx.x] = s; s2[threadIdx.x] = q; __syncthreads();
    for (int o = 128; o > 0; o >>= 1) {
        if (threadIdx.x < o) { s1[threadIdx.x] += s1[threadIdx.x + o]; s2[threadIdx.x] += s2[threadIdx.x + o]; }
        __syncthreads();
    }
    if (threadIdx.x == 0) { atomicAdd(&stats[0], s1[0]); atomicAdd(&stats[1], s2[0]); }
}

// ---------------- batchnorm + residual (+ fused sort-key emit) ----------------
__global__ void k_bn(const float* __restrict__ aggr, const float* __restrict__ xin,
                     const float* __restrict__ stats, const float* __restrict__ g,
                     const float* __restrict__ be, float* __restrict__ xout,
                     int n, float invn, const float* __restrict__ consts, int ci,
                     unsigned* __restrict__ keys, unsigned* __restrict__ vals) {
    int i = blockIdx.x * blockDim.x + threadIdx.x;
    if (i >= n) return;
    float mean = stats[0] * invn;
    float var  = stats[1] * invn - mean * mean;
    float inv  = 1.0f / sqrtf(var + 1e-5f);
    float v = g[0] * (aggr[i] - mean) * inv + be[0] + xin[i];
    xout[i] = v;
    if (keys) {
        float s = tanhf(v * consts[ci]);
        keys[i] = key_desc(s);
        vals[i] = (unsigned)i;
    }
}

// ---------------- radix sort: per-chunk histogram ----------------
__global__ void k_hist(const unsigned* __restrict__ keys, unsigned* __restrict__ hist,
                       int n, int shift) {
    __shared__ unsigned h[256];
    h[threadIdx.x] = 0;
    __syncthreads();
    int base = blockIdx.x * CHUNK;
    int end = base + CHUNK; if (end > n) end = n;
    for (int i = base + threadIdx.x; i < end; i += 256)
        atomicAdd(&h[(keys[i] >> shift) & 255u], 1u);
    __syncthreads();
    hist[blockIdx.x * 256 + threadIdx.x] = h[threadIdx.x];
}

// ---------------- radix sort: stable scatter (1 wave per block) ----------------
__global__ void __launch_bounds__(64) k_scatter(const unsigned* __restrict__ keys,
                                                const unsigned* __restrict__ vals,
                                                unsigned* __restrict__ okeys,
                                                unsigned* __restrict__ ovals,
                                                const unsigned* __restrict__ offs,
                                                const unsigned* __restrict__ base_,
                                                int n, int shift) {
    __shared__ unsigned run[256];
    __shared__ unsigned offl[256];
    int lane = threadIdx.x;
    for (int i = lane; i < 256; i += 64) { run[i] = 0; offl[i] = offs[blockIdx.x * 256 + i] + base_[i]; }
    __syncthreads();
    int base = blockIdx.x * CHUNK;
    int i0 = base + lane;
    bool a0 = i0 < n;
    unsigned k = a0 ? keys[i0] : 0u;
    unsigned v = a0 ? vals[i0] : 0u;
    const int SLOTS = CHUNK / 64;
    for (int slot = 0; slot < SLOTS; ++slot) {
        int inext = base + (slot + 1) * 64 + lane;
        bool an = (slot + 1 < SLOTS) && (inext < n);
        unsigned kn = an ? keys[inext] : 0u;
        unsigned vn = an ? vals[inext] : 0u;
        bool active = (base + slot * 64 + lane) < n;
        unsigned d = (k >> shift) & 255u;
        unsigned long long bb[8];
        unsigned long long amask = __ballot(active);
        #pragma unroll
        for (int bit = 0; bit < 8; ++bit) bb[bit] = __ballot(active && ((d >> bit) & 1u));
        unsigned long long m = amask;
        #pragma unroll
        for (int bit = 0; bit < 8; ++bit) m &= ((d >> bit) & 1u) ? bb[bit] : ~bb[bit];
        unsigned long long lt = (1ull << lane) - 1ull;
        unsigned rk = (unsigned)__popcll(m & lt);
        unsigned lrank = 0;
        if (active) lrank = run[d] + rk;
        __syncthreads();
        #pragma unroll
        for (int j = 0; j < 4; ++j) {
            unsigned dd = (unsigned)lane + j * 64u;
            unsigned long long mm = amask;
            #pragma unroll
            for (int bit = 0; bit < 8; ++bit) mm &= ((dd >> bit) & 1u) ? bb[bit] : ~bb[bit];
            run[dd] += (unsigned)__popcll(mm);
        }
        if (active) {
            unsigned pos = offl[d] + lrank;
            okeys[pos] = k;
            ovals[pos] = v;
        }
        __syncthreads();
        k = kn; v = vn;
    }
}

// ---------------- pool gather (+ optional new_idx, + optional next-sort keys) ----------------
__global__ void k_pool(const unsigned* __restrict__ perm, const float* __restrict__ xin,
                       const float* __restrict__ consts, int ci,
                       float* __restrict__ xout, int* __restrict__ newidx, int k,
                       unsigned* __restrict__ okeys, unsigned* __restrict__ ovals, int nci) {
    int r = blockIdx.x * blockDim.x + threadIdx.x;
    if (r >= k) return;
    unsigned p = perm[r];
    float xv = xin[p];
    float s = tanhf(xv * consts[ci]);
    float o = xv * s;
    xout[r] = o;
    if (newidx) newidx[p] = r;
    if (okeys) {
        float s2 = tanhf(o * consts[nci]);
        okeys[r] = key_desc(s2);
        ovals[r] = (unsigned)r;
    }
}

// ---------------- final MLP + log_softmax ----------------
__global__ void k_mlp(const float* __restrict__ x5, const float* __restrict__ Wl1,
                      const float* __restrict__ bl1, const float* __restrict__ Wl2,
                      const float* __restrict__ bl2, float* __restrict__ out, int n) {
    int i = blockIdx.x * blockDim.x + threadIdx.x;
    if (i >= n) return;
    float xv = x5[i];
    float l0 = bl2[0], l1 = bl2[1];
    #pragma unroll
    for (int j = 0; j < 8; ++j) {
        float h = fmaxf(xv * Wl1[j] + bl1[j], 0.0f);
        l0 += h * Wl2[2 * j];
        l1 += h * Wl2[2 * j + 1];
    }
    float mx = fmaxf(l0, l1);
    float lse = mx + logf(expf(l0 - mx) + expf(l1 - mx));
    out[2 * i]     = l0 - lse;
    out[2 * i + 1] = l1 - lse;
}

// ---------------- host-side radix sort driver ----------------
static void sort_pairs(hipStream_t stream, unsigned* kA, unsigned* vA,
                       unsigned* kB, unsigned* vB, unsigned* hist, unsigned* offs,
                       unsigned* tot, unsigned* base, int n) {
    int G = (n + CHUNK - 1) / CHUNK;
    unsigned *ki = kA, *vi = vA, *ko = kB, *vo = vB;
    for (int p = 0; p < 4; ++p) {
        int shift = p * 8;
        k_hist<<<G, 256, 0, stream>>>(ki, hist, n, shift);
        k_scanA<<<256, 256, 0, stream>>>(hist, offs, tot, G);
        k_scanB<<<1, 256, 0, stream>>>(tot, base, 256);
        k_scatter<<<G, 64, 0, stream>>>(ki, vi, ko, vo, offs, base, n, shift);
        unsigned* t;
        t = ki; ki = ko; ko = t;
        t = vi; vi = vo; vo = t;
    }
    // 4 passes (even): sorted result back in kA/vA
}

extern "C" void kernel_launch(void* const* d_in, const int* in_sizes, int n_in,
                              void* d_out, int out_size, void* d_ws, size_t ws_size,
                              hipStream_t stream) {
    const float* x   = (const float*)d_in[0];
    const float* ea  = (const float*)d_in[1];
    const int*   src = (const int*)d_in[2];
    const int*   dst = (const int*)d_in[3];
    const float *Wf1 = (const float*)d_in[5],  *bf1 = (const float*)d_in[6];
    const float *Ws1 = (const float*)d_in[7],  *bs1 = (const float*)d_in[8];
    const float *g1  = (const float*)d_in[9],  *be1 = (const float*)d_in[10];
    const float *Wf2 = (const float*)d_in[11], *bf2 = (const float*)d_in[12];
    const float *Ws2 = (const float*)d_in[13], *bs2 = (const float*)d_in[14];
    const float *g2  = (const float*)d_in[15], *be2 = (const float*)d_in[16];
    const float *pw1 = (const float*)d_in[17], *pw2 = (const float*)d_in[18], *pw3 = (const float*)d_in[19];
    const float *Wl1 = (const float*)d_in[20], *bl1 = (const float*)d_in[21];
    const float *Wl2 = (const float*)d_in[22], *bl2 = (const float*)d_in[23];

    const int N  = in_sizes[0];
    const int E  = in_sizes[1];
    const int K1 = 100000, K2 = 10000, K3 = 2500;

    // ---- runtime workspace layout ----
    size_t off = 0;
    auto alloc = [&](size_t bytes) { size_t o = off; off = (off + bytes + 255) & ~(size_t)255; return o; };
    char* ws = (char*)d_ws;
    size_t o_x1    = alloc((size_t)N * 4);
    size_t o_nidx  = alloc((size_t)N * 4);
    size_t o_stats = alloc(256);
    size_t o_const = alloc(256);
    size_t o_tot   = alloc(4096);                 // up to 1024 digits
    size_t o_base  = alloc(8192);                 // up to 1024+1
    size_t o_x2    = alloc((size_t)K1 * 4);
    size_t o_x3    = alloc((size_t)K1 * 4);
    size_t o_ag2   = alloc((size_t)K1 * 4);
    size_t o_x4    = alloc((size_t)K2 * 4);
    size_t o_x5    = alloc((size_t)K3 * 4);
    size_t o_ag1   = alloc((size_t)N * 4);
    size_t o_arena = off;  // overlay: conv1 binning scratch OR sort scratch

    // sort scratch (within arena)
    int G1 = (N + CHUNK - 1) / CHUNK;
    size_t s_kA = 0;
    size_t s_vA = s_kA + (((size_t)N * 4 + 255) & ~(size_t)255);
    size_t s_kB = s_vA + (((size_t)N * 4 + 255) & ~(size_t)255);
    size_t s_vB = s_kB + (((size_t)N * 4 + 255) & ~(size_t)255);
    size_t s_h  = s_vB + (((size_t)N * 4 + 255) & ~(size_t)255);
    size_t s_o  = s_h  + (((size_t)G1 * 256 * 4 + 255) & ~(size_t)255);
    size_t sortSz = s_o + (size_t)G1 * 256 * 4;

    // pick split factor H for binning scratch
    int H = 0;
    size_t c_bm = 0, c_bdl = 0, c_eh = 0, c_eo = 0;
    for (int h = 1; h <= 8; h <<= 1) {
        int Eh = (E + h - 1) / h;
        int GE = (Eh + EC - 1) / EC;
        size_t bmB  = ((size_t)Eh * 4 + 255) & ~(size_t)255;
        size_t bdlB = ((size_t)Eh * 2 + 255) & ~(size_t)255;
        size_t ehB  = ((size_t)GE * NBIN * 4 + 255) & ~(size_t)255;
        size_t eoB  = ((size_t)GE * NBIN * 4 + 255) & ~(size_t)255;
        size_t need = bmB + bdlB + ehB + eoB;
        size_t total = o_arena + (need > sortSz ? need : sortSz);
        if (total <= ws_size && N <= NBIN * NBIN) {
            H = h;
            c_bm = 0; c_bdl = c_bm + bmB; c_eh = c_bdl + bdlB; c_eo = c_eh + ehB;
            break;
        }
    }

    float*    x1     = (float*)(ws + o_x1);
    int*      nidx   = (int*)(ws + o_nidx);
    float*    stats  = (float*)(ws + o_stats);
    float*    consts = (float*)(ws + o_const);
    unsigned* tot    = (unsigned*)(ws + o_tot);
    unsigned* base   = (unsigned*)(ws + o_base);
    float*    x2     = (float*)(ws + o_x2);
    float*    x3     = (float*)(ws + o_x3);
    float*    aggr2  = (float*)(ws + o_ag2);
    float*    x4     = (float*)(ws + o_x4);
    float*    x5     = (float*)(ws + o_x5);
    float*    aggr1  = (float*)(ws + o_ag1);
    unsigned* kA     = (unsigned*)(ws + o_arena + s_kA);
    unsigned* vA     = (unsigned*)(ws + o_arena + s_vA);
    unsigned* kB     = (unsigned*)(ws + o_arena + s_kB);
    unsigned* vB     = (unsigned*)(ws + o_arena + s_vB);
    unsigned* hist   = (unsigned*)(ws + o_arena + s_h);
    unsigned* offs   = (unsigned*)(ws + o_arena + s_o);

    // init state (harness does not re-poison between replays)
    hipMemsetAsync(nidx, 0xFF, (size_t)N * 4, stream);   // -1
    hipMemsetAsync(stats, 0, 64, stream);
    hipMemsetAsync(aggr2, 0, (size_t)K1 * 4, stream);

    k_consts<<<3, 256, 0, stream>>>(pw1, pw2, pw3, consts,
                                    in_sizes[17], in_sizes[18], in_sizes[19]);

    // ---- cgconv 1 ----
    if (H > 0) {
        float*          bm   = (float*)(ws + o_arena + c_bm);
        unsigned short* bdl  = (unsigned short*)(ws + o_arena + c_bdl);
        unsigned*       eh   = (unsigned*)(ws + o_arena + c_eh);
        unsigned*       eo   = (unsigned*)(ws + o_arena + c_eo);
        int Eh = (E + H - 1) / H;
        for (int h = 0; h < H; ++h) {
            int e0 = h * Eh;
            int e1 = e0 + Eh; if (e1 > E) e1 = E;
            if (e0 >= e1) break;
            int GE = (e1 - e0 + EC - 1) / EC;
            k_ehist<<<GE, 256, 0, stream>>>(dst, eh, e0, e1);
            k_scanA<<<NBIN, 256, 0, stream>>>(eh, eo, tot, GE);
            k_scanB<<<1, 256, 0, stream>>>(tot, base, NBIN);
            k_escatter<<<GE, 256, 0, stream>>>(x, ea, src, dst, Wf1, bf1, Ws1, bs1,
                                               eo, base, bm, bdl, e0, e1);
            int NBLK = (N + NBIN - 1) / NBIN;
            k_eaggr<<<NBLK, 256, 0, stream>>>(bm, bdl, base, aggr1, N, h > 0);
        }
    } else {
        hipMemsetAsync(aggr1, 0, (size_t)N * 4, stream);
        k_conv1<<<(E + 255) / 256, 256, 0, stream>>>(x, ea, src, dst, Wf1, bf1, Ws1, bs1, aggr1, E);
    }
    k_stats<<<1024, 256, 0, stream>>>(aggr1, N, stats);
    k_bn<<<(N + 255) / 256, 256, 0, stream>>>(aggr1, x, stats, g1, be1, x1, N, 1.0f / (float)N,
                                              consts, 0, kA, vA);

    // ---- pool 1 : top 100K of 1M ----
    sort_pairs(stream, kA, vA, kB, vB, hist, offs, tot, base, N);
    k_pool<<<(K1 + 255) / 256, 256, 0, stream>>>(vA, x1, consts, 0, x2, nidx, K1,
                                                 (unsigned*)nullptr, (unsigned*)nullptr, 0);

    // ---- cgconv 2 (filtered edges; sparse atomics) ----
    k_conv2<<<(E + 255) / 256, 256, 0, stream>>>(x2, ea, src, dst, nidx, Wf2, bf2, Ws2, bs2, aggr2, E);
    k_stats<<<256, 256, 0, stream>>>(aggr2, K1, stats + 2);
    k_bn<<<(K1 + 255) / 256, 256, 0, stream>>>(aggr2, x2, stats + 2, g2, be2, x3, K1, 1.0f / (float)K1,
                                               consts, 1, kA, vA);

    // ---- pool 2 : top 10K of 100K (emits keys for pool-3 sort) ----
    sort_pairs(stream, kA, vA, kB, vB, hist, offs, tot, base, K1);
    k_pool<<<(K2 + 255) / 256, 256, 0, stream>>>(vA, x3, consts, 1, x4, (int*)nullptr, K2,
                                                 kA, vA, 2);

    // ---- pool 3 : top 2500 of 10K ----
    sort_pairs(stream, kA, vA, kB, vB, hist, offs, tot, base, K2);
    k_pool<<<(K3 + 255) / 256, 256, 0, stream>>>(vA, x4, consts, 2, x5, (int*)nullptr, K3,
                                                 (unsigned*)nullptr, (unsigned*)nullptr, 0);

    // ---- MLP + log_softmax ----
    k_mlp<<<(K3 + 255) / 256, 256, 0, stream>>>(x5, Wl1, bl1, Wl2, bl2, (float*)d_out, K3);
}

// Round 3
// 1438.857 us; speedup vs baseline: 1.4519x; 1.2524x over previous
//
#include <hip/hip_runtime.h>
#include <math.h>

#define CHUNK 4096               // elements per radix-sort block
#define NC    8                  // XCD count (gfx950 / MI355X)

__device__ __forceinline__ float sigmoidf_(float x) {
    if (x >= 0.0f) { float e = expf(-x); return 1.0f / (1.0f + e); }
    float e = expf(x); return e / (1.0f + e);
}
__device__ __forceinline__ float softplusf_(float x) {
    return fmaxf(x, 0.0f) + log1pf(expf(-fabsf(x)));
}
__device__ __forceinline__ unsigned key_desc(float f) {
    unsigned u = __float_as_uint(f);
    unsigned ka = (u & 0x80000000u) ? ~u : (u | 0x80000000u);  // ascending map
    return ~ka;                                                 // descending
}
__device__ __forceinline__ float edge_m(float xd, float xs, float a,
                                        float wf0, float wf1, float wf2, float b0,
                                        float ws0, float ws1, float ws2, float b1) {
    float f = xd * wf0 + xs * wf1 + a * wf2 + b0;
    float g = xd * ws0 + xs * ws1 + a * ws2 + b1;
    return sigmoidf_(f) * softplusf_(g);
}

// ---------------- score constants c = sum(w)/norm(w) ----------------
__global__ void k_consts(const float* __restrict__ pw1, const float* __restrict__ pw2,
                         const float* __restrict__ pw3, float* __restrict__ consts,
                         int n1, int n2, int n3) {
    const float* w; int n;
    if (blockIdx.x == 0)      { w = pw1; n = n1; }
    else if (blockIdx.x == 1) { w = pw2; n = n2; }
    else                      { w = pw3; n = n3; }
    __shared__ float s1[256], s2[256];
    float a = 0.f, b = 0.f;
    for (int i = threadIdx.x; i < n; i += 256) { float v = w[i]; a += v; b += v * v; }
    s1[threadIdx.x] = a; s2[threadIdx.x] = b; __syncthreads();
    for (int o = 128; o > 0; o >>= 1) {
        if (threadIdx.x < o) { s1[threadIdx.x] += s1[threadIdx.x + o]; s2[threadIdx.x] += s2[threadIdx.x + o]; }
        __syncthreads();
    }
    if (threadIdx.x == 0) consts[blockIdx.x] = s1[0] / sqrtf(s2[0]);
}

// ---------------- conv1: per-XCD copies + L2-local atomics ----------------
__global__ void k_conv1x(const float* __restrict__ x, const float* __restrict__ ea,
                         const int* __restrict__ src, const int* __restrict__ dst,
                         const float* __restrict__ Wf, const float* __restrict__ bf,
                         const float* __restrict__ Ws, const float* __restrict__ bs,
                         float* __restrict__ copies, int N, int E) {
    unsigned xcc;
    asm volatile("s_getreg_b32 %0, hwreg(HW_REG_XCC_ID)" : "=s"(xcc));
    float* aggr = copies + (size_t)(xcc & (NC - 1)) * (size_t)N;
    int e = blockIdx.x * blockDim.x + threadIdx.x;
    if (e >= E) return;
    int s = src[e], d = dst[e];
    float m = edge_m(x[d], x[s], ea[e], Wf[0], Wf[1], Wf[2], bf[0],
                     Ws[0], Ws[1], Ws[2], bs[0]);
    // workgroup-scope relaxed: executes at local XCD L2 (no cross-XCD RMW traffic)
    __hip_atomic_fetch_add(&aggr[d], m, __ATOMIC_RELAXED, __HIP_MEMORY_SCOPE_WORKGROUP);
}

// reduce the NC copies -> aggr, fused sum/sumsq stats
__global__ void k_red8(const float* __restrict__ copies, int n,
                       float* __restrict__ aggr, float* __restrict__ stats) {
    int i = blockIdx.x * blockDim.x + threadIdx.x;
    float v = 0.f;
    if (i < n) {
        #pragma unroll
        for (int c = 0; c < NC; ++c) v += copies[(size_t)c * n + i];
        aggr[i] = v;
    }
    __shared__ float s1[256], s2[256];
    s1[threadIdx.x] = (i < n) ? v : 0.f;
    s2[threadIdx.x] = (i < n) ? v * v : 0.f;
    __syncthreads();
    for (int o = 128; o > 0; o >>= 1) {
        if (threadIdx.x < o) { s1[threadIdx.x] += s1[threadIdx.x + o]; s2[threadIdx.x] += s2[threadIdx.x + o]; }
        __syncthreads();
    }
    if (threadIdx.x == 0) { atomicAdd(&stats[0], s1[0]); atomicAdd(&stats[1], s2[0]); }
}

// ---------------- conv1 atomic fallback (ws too small) ----------------
__global__ void k_conv1(const float* __restrict__ x, const float* __restrict__ ea,
                        const int* __restrict__ src, const int* __restrict__ dst,
                        const float* __restrict__ Wf, const float* __restrict__ bf,
                        const float* __restrict__ Ws, const float* __restrict__ bs,
                        float* __restrict__ aggr, int E) {
    int e = blockIdx.x * blockDim.x + threadIdx.x;
    if (e >= E) return;
    int s = src[e], d = dst[e];
    atomicAdd(&aggr[d], edge_m(x[d], x[s], ea[e], Wf[0], Wf[1], Wf[2], bf[0],
                               Ws[0], Ws[1], Ws[2], bs[0]));
}

// ---------------- conv2: filtered edges, sparse atomics ----------------
__global__ void k_conv2(const float* __restrict__ x2, const float* __restrict__ ea,
                        const int* __restrict__ src, const int* __restrict__ dst,
                        const int* __restrict__ nidx,
                        const float* __restrict__ Wf, const float* __restrict__ bf,
                        const float* __restrict__ Ws, const float* __restrict__ bs,
                        float* __restrict__ aggr, int E) {
    int e = blockIdx.x * blockDim.x + threadIdx.x;
    if (e >= E) return;
    int ns = nidx[src[e]], nd = nidx[dst[e]];
    if ((ns | nd) < 0) return;
    atomicAdd(&aggr[nd], edge_m(x2[nd], x2[ns], ea[e], Wf[0], Wf[1], Wf[2], bf[0],
                                Ws[0], Ws[1], Ws[2], bs[0]));
}

// ---------------- sum / sumsq reduction ----------------
__global__ void k_stats(const float* __restrict__ a, int n, float* __restrict__ stats) {
    float s = 0.f, q = 0.f;
    int stride = gridDim.x * blockDim.x;
    for (int i = blockIdx.x * blockDim.x + threadIdx.x; i < n; i += stride) {
        float v = a[i]; s += v; q += v * v;
    }
    __shared__ float s1[256], s2[256];
    s1[threadIdx.x] = s; s2[threadIdx.x] = q; __syncthreads();
    for (int o = 128; o > 0; o >>= 1) {
        if (threadIdx.x < o) { s1[threadIdx.x] += s1[threadIdx.x + o]; s2[threadIdx.x] += s2[threadIdx.x + o]; }
        __syncthreads();
    }
    if (threadIdx.x == 0) { atomicAdd(&stats[0], s1[0]); atomicAdd(&stats[1], s2[0]); }
}

// ---------------- batchnorm + residual (+ fused sort-key emit) ----------------
__global__ void k_bn(const float* __restrict__ aggr, const float* __restrict__ xin,
                     const float* __restrict__ stats, const float* __restrict__ g,
                     const float* __restrict__ be, float* __restrict__ xout,
                     int n, float invn, const float* __restrict__ consts, int ci,
                     unsigned* __restrict__ keys, unsigned* __restrict__ vals) {
    int i = blockIdx.x * blockDim.x + threadIdx.x;
    if (i >= n) return;
    float mean = stats[0] * invn;
    float var  = stats[1] * invn - mean * mean;
    float inv  = 1.0f / sqrtf(var + 1e-5f);
    float v = g[0] * (aggr[i] - mean) * inv + be[0] + xin[i];
    xout[i] = v;
    if (keys) {
        float s = tanhf(v * consts[ci]);
        keys[i] = key_desc(s);
        vals[i] = (unsigned)i;
    }
}

// ---------------- radix sort: per-chunk histogram ----------------
__global__ void k_hist(const unsigned* __restrict__ keys, unsigned* __restrict__ hist,
                       int n, int shift) {
    __shared__ unsigned h[256];
    h[threadIdx.x] = 0;
    __syncthreads();
    int base = blockIdx.x * CHUNK;
    int end = base + CHUNK; if (end > n) end = n;
    for (int i = base + threadIdx.x; i < end; i += 256)
        atomicAdd(&h[(keys[i] >> shift) & 255u], 1u);
    __syncthreads();
    hist[blockIdx.x * 256 + threadIdx.x] = h[threadIdx.x];
}

// generic scanA: one block per digit d; within-digit exclusive prefix over blocks
__global__ void k_scanA(const unsigned* __restrict__ hist, unsigned* __restrict__ offs,
                        unsigned* __restrict__ tot, int G) {
    int d = blockIdx.x, ND = gridDim.x, t = threadIdx.x;
    __shared__ unsigned s[256];
    unsigned carry = 0;
    for (int tile = 0; tile * 256 < G; ++tile) {
        int g = tile * 256 + t;
        unsigned v = (g < G) ? hist[(size_t)g * ND + d] : 0u;
        s[t] = v; __syncthreads();
        for (int o = 1; o < 256; o <<= 1) {
            unsigned u = (t >= o) ? s[t - o] : 0u;
            __syncthreads();
            s[t] += u; __syncthreads();
        }
        if (g < G) offs[(size_t)g * ND + d] = s[t] - v + carry;
        unsigned tl = s[255]; __syncthreads();
        carry += tl;
    }
    if (t == 0) tot[d] = carry;
}

// generic scanB: single block; exclusive scan of tot[ND] -> base[ND]
__global__ void k_scanB(const unsigned* __restrict__ tot, unsigned* __restrict__ base, int ND) {
    __shared__ unsigned s[256];
    int t = threadIdx.x;
    unsigned carry = 0;
    for (int tile = 0; tile * 256 < ND; ++tile) {
        int d = tile * 256 + t;
        unsigned v = (d < ND) ? tot[d] : 0u;
        s[t] = v; __syncthreads();
        for (int o = 1; o < 256; o <<= 1) {
            unsigned u = (t >= o) ? s[t - o] : 0u;
            __syncthreads();
            s[t] += u; __syncthreads();
        }
        if (d < ND) base[d] = s[t] - v + carry;
        unsigned tl = s[255]; __syncthreads();
        carry += tl;
    }
    if (t == 0) base[ND] = carry;
}

// ---------------- radix sort: stable scatter (4 waves / block) ----------------
__global__ void __launch_bounds__(256) k_scatter(const unsigned* __restrict__ keys,
                                                 const unsigned* __restrict__ vals,
                                                 unsigned* __restrict__ okeys,
                                                 unsigned* __restrict__ ovals,
                                                 const unsigned* __restrict__ offs,
                                                 const unsigned* __restrict__ base_,
                                                 int n, int shift) {
    __shared__ unsigned run[256];      // running per-digit count within chunk
    __shared__ unsigned offl[256];     // global digit base for this block
    __shared__ unsigned wcnt[4][256];  // per-wave per-digit counts (current group)
    __shared__ unsigned wpre[4][256];  // per-wave per-digit bases  (current group)
    int t = threadIdx.x;
    int wave = t >> 6, lane = t & 63;
    run[t] = 0;
    offl[t] = offs[(size_t)blockIdx.x * 256 + t] + base_[t];
    __syncthreads();
    int cbase = blockIdx.x * CHUNK;
    const int GROUPS = CHUNK / 256;
    for (int gix = 0; gix < GROUPS; ++gix) {
        int i = cbase + gix * 256 + t;
        bool active = i < n;
        unsigned k = active ? keys[i] : 0u;
        unsigned v = active ? vals[i] : 0u;
        unsigned d = (k >> shift) & 255u;
        unsigned long long amask = __ballot(active);
        unsigned long long bb[8];
        #pragma unroll
        for (int bit = 0; bit < 8; ++bit) bb[bit] = __ballot(active && ((d >> bit) & 1u));
        unsigned long long m = amask;
        #pragma unroll
        for (int bit = 0; bit < 8; ++bit) m &= ((d >> bit) & 1u) ? bb[bit] : ~bb[bit];
        unsigned rk = (unsigned)__popcll(m & ((1ull << lane) - 1ull));
        #pragma unroll
        for (int j = 0; j < 4; ++j) {
            unsigned dd = (unsigned)lane + j * 64u;
            unsigned long long mm = amask;
            #pragma unroll
            for (int bit = 0; bit < 8; ++bit) mm &= ((dd >> bit) & 1u) ? bb[bit] : ~bb[bit];
            wcnt[wave][dd] = (unsigned)__popcll(mm);
        }
        __syncthreads();
        {   // thread t owns digit t: wave-prefix bases + run update
            unsigned r = run[t];
            unsigned c0 = wcnt[0][t], c1 = wcnt[1][t], c2 = wcnt[2][t], c3 = wcnt[3][t];
            wpre[0][t] = r;
            wpre[1][t] = r + c0;
            wpre[2][t] = r + c0 + c1;
            wpre[3][t] = r + c0 + c1 + c2;
            run[t] = r + c0 + c1 + c2 + c3;
        }
        __syncthreads();
        if (active) {
            unsigned pos = offl[d] + wpre[wave][d] + rk;
            okeys[pos] = k;
            ovals[pos] = v;
        }
    }
}

// ---------------- pool gather (+ optional new_idx, + optional next-sort keys) ----------------
__global__ void k_pool(const unsigned* __restrict__ perm, const float* __restrict__ xin,
                       const float* __restrict__ consts, int ci,
                       float* __restrict__ xout, int* __restrict__ newidx, int k,
                       unsigned* __restrict__ okeys, unsigned* __restrict__ ovals, int nci) {
    int r = blockIdx.x * blockDim.x + threadIdx.x;
    if (r >= k) return;
    unsigned p = perm[r];
    float xv = xin[p];
    float s = tanhf(xv * consts[ci]);
    float o = xv * s;
    xout[r] = o;
    if (newidx) newidx[p] = r;
    if (okeys) {
        float s2 = tanhf(o * consts[nci]);
        okeys[r] = key_desc(s2);
        ovals[r] = (unsigned)r;
    }
}

// ---------------- final MLP + log_softmax ----------------
__global__ void k_mlp(const float* __restrict__ x5, const float* __restrict__ Wl1,
                      const float* __restrict__ bl1, const float* __restrict__ Wl2,
                      const float* __restrict__ bl2, float* __restrict__ out, int n) {
    int i = blockIdx.x * blockDim.x + threadIdx.x;
    if (i >= n) return;
    float xv = x5[i];
    float l0 = bl2[0], l1 = bl2[1];
    #pragma unroll
    for (int j = 0; j < 8; ++j) {
        float h = fmaxf(xv * Wl1[j] + bl1[j], 0.0f);
        l0 += h * Wl2[2 * j];
        l1 += h * Wl2[2 * j + 1];
    }
    float mx = fmaxf(l0, l1);
    float lse = mx + logf(expf(l0 - mx) + expf(l1 - mx));
    out[2 * i]     = l0 - lse;
    out[2 * i + 1] = l1 - lse;
}

// ---------------- host-side radix sort driver ----------------
static void sort_pairs(hipStream_t stream, unsigned* kA, unsigned* vA,
                       unsigned* kB, unsigned* vB, unsigned* hist, unsigned* offs,
                       unsigned* tot, unsigned* base, int n) {
    int G = (n + CHUNK - 1) / CHUNK;
    unsigned *ki = kA, *vi = vA, *ko = kB, *vo = vB;
    for (int p = 0; p < 4; ++p) {
        int shift = p * 8;
        k_hist<<<G, 256, 0, stream>>>(ki, hist, n, shift);
        k_scanA<<<256, 256, 0, stream>>>(hist, offs, tot, G);
        k_scanB<<<1, 256, 0, stream>>>(tot, base, 256);
        k_scatter<<<G, 256, 0, stream>>>(ki, vi, ko, vo, offs, base, n, shift);
        unsigned* t;
        t = ki; ki = ko; ko = t;
        t = vi; vi = vo; vo = t;
    }
    // 4 passes (even): result back in the (kA,vA) role it started in
}

extern "C" void kernel_launch(void* const* d_in, const int* in_sizes, int n_in,
                              void* d_out, int out_size, void* d_ws, size_t ws_size,
                              hipStream_t stream) {
    const float* x   = (const float*)d_in[0];
    const float* ea  = (const float*)d_in[1];
    const int*   src = (const int*)d_in[2];
    const int*   dst = (const int*)d_in[3];
    const float *Wf1 = (const float*)d_in[5],  *bf1 = (const float*)d_in[6];
    const float *Ws1 = (const float*)d_in[7],  *bs1 = (const float*)d_in[8];
    const float *g1  = (const float*)d_in[9],  *be1 = (const float*)d_in[10];
    const float *Wf2 = (const float*)d_in[11], *bf2 = (const float*)d_in[12];
    const float *Ws2 = (const float*)d_in[13], *bs2 = (const float*)d_in[14];
    const float *g2  = (const float*)d_in[15], *be2 = (const float*)d_in[16];
    const float *pw1 = (const float*)d_in[17], *pw2 = (const float*)d_in[18], *pw3 = (const float*)d_in[19];
    const float *Wl1 = (const float*)d_in[20], *bl1 = (const float*)d_in[21];
    const float *Wl2 = (const float*)d_in[22], *bl2 = (const float*)d_in[23];

    const int N  = in_sizes[0];
    const int E  = in_sizes[1];
    const int K1 = 100000, K2 = 10000, K3 = 2500;

    // ---- workspace layout ----
    size_t off = 0;
    auto alloc = [&](size_t bytes) { size_t o = off; off = (off + bytes + 255) & ~(size_t)255; return o; };
    char* ws = (char*)d_ws;
    size_t o_x1    = alloc((size_t)N * 4);
    size_t o_nidx  = alloc((size_t)N * 4);
    size_t o_stats = alloc(256);
    size_t o_const = alloc(256);
    size_t o_tot   = alloc(4096);
    size_t o_base  = alloc(8192);
    size_t o_x2    = alloc((size_t)K1 * 4);
    size_t o_x3    = alloc((size_t)K1 * 4);
    size_t o_ag2   = alloc((size_t)K1 * 4);
    size_t o_x4    = alloc((size_t)K2 * 4);
    size_t o_x5    = alloc((size_t)K3 * 4);
    size_t o_ag1   = alloc((size_t)N * 4);
    size_t o_arena = off;

    // arena overlay A: conv1 per-XCD copies (NC * N floats) -- dead after k_red8
    size_t copiesSz = (size_t)NC * (size_t)N * 4;
    // arena overlay B: sort scratch -- live from k_bn onward
    int G1 = (N + CHUNK - 1) / CHUNK;
    size_t s_kA = 0;
    size_t s_vA = s_kA + (((size_t)N * 4 + 255) & ~(size_t)255);
    size_t s_kB = s_vA + (((size_t)N * 4 + 255) & ~(size_t)255);
    size_t s_vB = s_kB + (((size_t)N * 4 + 255) & ~(size_t)255);
    size_t s_h  = s_vB + (((size_t)N * 4 + 255) & ~(size_t)255);
    size_t s_o  = s_h  + (((size_t)G1 * 256 * 4 + 255) & ~(size_t)255);
    size_t sortSz = s_o + (size_t)G1 * 256 * 4;
    size_t arenaSz = copiesSz > sortSz ? copiesSz : sortSz;
    bool useXcd = (o_arena + arenaSz) <= ws_size;

    float*    x1     = (float*)(ws + o_x1);
    int*      nidx   = (int*)(ws + o_nidx);
    float*    stats  = (float*)(ws + o_stats);
    float*    consts = (float*)(ws + o_const);
    unsigned* tot    = (unsigned*)(ws + o_tot);
    unsigned* base   = (unsigned*)(ws + o_base);
    float*    x2     = (float*)(ws + o_x2);
    float*    x3     = (float*)(ws + o_x3);
    float*    aggr2  = (float*)(ws + o_ag2);
    float*    x4     = (float*)(ws + o_x4);
    float*    x5     = (float*)(ws + o_x5);
    float*    aggr1  = (float*)(ws + o_ag1);
    float*    copies = (float*)(ws + o_arena);
    unsigned* kA     = (unsigned*)(ws + o_arena + s_kA);
    unsigned* vA     = (unsigned*)(ws + o_arena + s_vA);
    unsigned* kB     = (unsigned*)(ws + o_arena + s_kB);
    unsigned* vB     = (unsigned*)(ws + o_arena + s_vB);
    unsigned* hist   = (unsigned*)(ws + o_arena + s_h);
    unsigned* offs   = (unsigned*)(ws + o_arena + s_o);

    // init (harness does not re-poison between replays)
    hipMemsetAsync(nidx, 0xFF, (size_t)N * 4, stream);   // -1
    hipMemsetAsync(stats, 0, 64, stream);
    hipMemsetAsync(aggr2, 0, (size_t)K1 * 4, stream);

    k_consts<<<3, 256, 0, stream>>>(pw1, pw2, pw3, consts,
                                    in_sizes[17], in_sizes[18], in_sizes[19]);

    // ---- cgconv 1 ----
    if (useXcd) {
        hipMemsetAsync(copies, 0, copiesSz, stream);
        k_conv1x<<<(E + 255) / 256, 256, 0, stream>>>(x, ea, src, dst, Wf1, bf1, Ws1, bs1,
                                                      copies, N, E);
        k_red8<<<(N + 255) / 256, 256, 0, stream>>>(copies, N, aggr1, stats);
    } else {
        hipMemsetAsync(aggr1, 0, (size_t)N * 4, stream);
        k_conv1<<<(E + 255) / 256, 256, 0, stream>>>(x, ea, src, dst, Wf1, bf1, Ws1, bs1, aggr1, E);
        k_stats<<<1024, 256, 0, stream>>>(aggr1, N, stats);
    }
    k_bn<<<(N + 255) / 256, 256, 0, stream>>>(aggr1, x, stats, g1, be1, x1, N, 1.0f / (float)N,
                                              consts, 0, kA, vA);

    // ---- pool 1 : top 100K of 1M ----
    sort_pairs(stream, kA, vA, kB, vB, hist, offs, tot, base, N);
    k_pool<<<(K1 + 255) / 256, 256, 0, stream>>>(vA, x1, consts, 0, x2, nidx, K1,
                                                 (unsigned*)nullptr, (unsigned*)nullptr, 0);

    // ---- cgconv 2 (filtered edges; sparse atomics) ----
    k_conv2<<<(E + 255) / 256, 256, 0, stream>>>(x2, ea, src, dst, nidx, Wf2, bf2, Ws2, bs2, aggr2, E);
    k_stats<<<256, 256, 0, stream>>>(aggr2, K1, stats + 2);
    k_bn<<<(K1 + 255) / 256, 256, 0, stream>>>(aggr2, x2, stats + 2, g2, be2, x3, K1, 1.0f / (float)K1,
                                               consts, 1, kA, vA);

    // ---- pool 2 : top 10K of 100K (emits keys for pool-3 sort into kB/vB) ----
    sort_pairs(stream, kA, vA, kB, vB, hist, offs, tot, base, K1);
    k_pool<<<(K2 + 255) / 256, 256, 0, stream>>>(vA, x3, consts, 1, x4, (int*)nullptr, K2,
                                                 kB, vB, 2);

    // ---- pool 3 : top 2500 of 10K ----
    sort_pairs(stream, kB, vB, kA, vA, hist, offs, tot, base, K2);
    k_pool<<<(K3 + 255) / 256, 256, 0, stream>>>(vB, x4, consts, 2, x5, (int*)nullptr, K3,
                                                 (unsigned*)nullptr, (unsigned*)nullptr, 0);

    // ---- MLP + log_softmax ----
    k_mlp<<<(K3 + 255) / 256, 256, 0, stream>>>(x5, Wl1, bl1, Wl2, bl2, (float*)d_out, K3);
}

// Round 4
// 1269.382 us; speedup vs baseline: 1.6458x; 1.1335x over previous
//
#include <hip/hip_runtime.h>
#include <math.h>

#define CHUNK 4096               // elements per radix-sort block
#define NB2   512                // conv1 partition bins
#define BSH   11                 // bin = dst >> BSH ; 2048 nodes per bin
#define CAP   8                  // LDS stage capacity per bin
#define RND   1024               // edges per staging round (256 thr * 4)

__device__ __forceinline__ float sigmoidf_(float x) {
    if (x >= 0.0f) { float e = expf(-x); return 1.0f / (1.0f + e); }
    float e = expf(x); return e / (1.0f + e);
}
__device__ __forceinline__ float softplusf_(float x) {
    return fmaxf(x, 0.0f) + log1pf(expf(-fabsf(x)));
}
__device__ __forceinline__ unsigned key_desc(float f) {
    unsigned u = __float_as_uint(f);
    unsigned ka = (u & 0x80000000u) ? ~u : (u | 0x80000000u);  // ascending map
    return ~ka;                                                 // descending
}
__device__ __forceinline__ float edge_m(float xd, float xs, float a,
                                        float wf0, float wf1, float wf2, float b0,
                                        float ws0, float ws1, float ws2, float b1) {
    float f = xd * wf0 + xs * wf1 + a * wf2 + b0;
    float g = xd * ws0 + xs * ws1 + a * ws2 + b1;
    return sigmoidf_(f) * softplusf_(g);
}

// ---------------- score constants c = sum(w)/norm(w) ----------------
__global__ void k_consts(const float* __restrict__ pw1, const float* __restrict__ pw2,
                         const float* __restrict__ pw3, float* __restrict__ consts,
                         int n1, int n2, int n3) {
    const float* w; int n;
    if (blockIdx.x == 0)      { w = pw1; n = n1; }
    else if (blockIdx.x == 1) { w = pw2; n = n2; }
    else                      { w = pw3; n = n3; }
    __shared__ float s1[256], s2[256];
    float a = 0.f, b = 0.f;
    for (int i = threadIdx.x; i < n; i += 256) { float v = w[i]; a += v; b += v * v; }
    s1[threadIdx.x] = a; s2[threadIdx.x] = b; __syncthreads();
    for (int o = 128; o > 0; o >>= 1) {
        if (threadIdx.x < o) { s1[threadIdx.x] += s1[threadIdx.x + o]; s2[threadIdx.x] += s2[threadIdx.x + o]; }
        __syncthreads();
    }
    if (threadIdx.x == 0) consts[blockIdx.x] = s1[0] / sqrtf(s2[0]);
}

// ============== conv1: atomic-free two-level partition ==============
// Phase A: per-chunk histogram of dst>>BSH
__global__ void k_ehist2(const int* __restrict__ dst, unsigned* __restrict__ hist,
                         int E, int EPB) {
    __shared__ unsigned h[NB2];
    for (int i = threadIdx.x; i < NB2; i += 256) h[i] = 0;
    __syncthreads();
    int cs = blockIdx.x * EPB;
    int ce = cs + EPB; if (ce > E) ce = E;
    int i = cs + threadIdx.x * 4;
    for (; i + 3 < ce && i >= cs; ) {   // vec4 fast path over full rounds
        if (cs + ((i - cs) / RND) * RND + RND <= ce && ((i - cs) & 3) == 0) break;
        break;
    }
    for (int e = cs + threadIdx.x; e < ce; e += 256)
        atomicAdd(&h[((unsigned)dst[e]) >> BSH], 1u);
    __syncthreads();
    for (int j = threadIdx.x; j < NB2; j += 256)
        hist[(size_t)blockIdx.x * NB2 + j] = h[j];
}

// generic scanA: one block per digit d; within-digit exclusive prefix over blocks
__global__ void k_scanA(const unsigned* __restrict__ hist, unsigned* __restrict__ offs,
                        unsigned* __restrict__ tot, int G) {
    int d = blockIdx.x, ND = gridDim.x, t = threadIdx.x;
    __shared__ unsigned s[256];
    unsigned carry = 0;
    for (int tile = 0; tile * 256 < G; ++tile) {
        int g = tile * 256 + t;
        unsigned v = (g < G) ? hist[(size_t)g * ND + d] : 0u;
        s[t] = v; __syncthreads();
        for (int o = 1; o < 256; o <<= 1) {
            unsigned u = (t >= o) ? s[t - o] : 0u;
            __syncthreads();
            s[t] += u; __syncthreads();
        }
        if (g < G) offs[(size_t)g * ND + d] = s[t] - v + carry;
        unsigned tl = s[255]; __syncthreads();
        carry += tl;
    }
    if (t == 0) tot[d] = carry;
}

// generic scanB: single block; exclusive scan of tot[ND] -> base[ND], base[ND]=total
__global__ void k_scanB(const unsigned* __restrict__ tot, unsigned* __restrict__ base, int ND) {
    __shared__ unsigned s[256];
    int t = threadIdx.x;
    unsigned carry = 0;
    for (int tile = 0; tile * 256 < ND; ++tile) {
        int d = tile * 256 + t;
        unsigned v = (d < ND) ? tot[d] : 0u;
        s[t] = v; __syncthreads();
        for (int o = 1; o < 256; o <<= 1) {
            unsigned u = (t >= o) ? s[t - o] : 0u;
            __syncthreads();
            s[t] += u; __syncthreads();
        }
        if (d < ND) base[d] = s[t] - v + carry;
        unsigned tl = s[255]; __syncthreads();
        carry += tl;
    }
    if (t == 0) base[ND] = carry;
}

// Phase C: compute m, stage (m, dlow) per bin in LDS, flush coalesced
__global__ void __launch_bounds__(256) k_part(
        const float* __restrict__ x, const float* __restrict__ ea,
        const int* __restrict__ src, const int* __restrict__ dst,
        const float* __restrict__ Wf, const float* __restrict__ bf,
        const float* __restrict__ Ws, const float* __restrict__ bs,
        const unsigned* __restrict__ offs, const unsigned* __restrict__ binBase,
        float* __restrict__ bm, unsigned short* __restrict__ bdl,
        int E, int EPB) {
    __shared__ float          smv[NB2][CAP + 1];   // +1 pad: odd stride, no bank conflict
    __shared__ unsigned short sdv[NB2][CAP + 2];   // stride 10 u16 = 20B, odd dword stride
    __shared__ unsigned gcur[NB2], fil[NB2];
    int t = threadIdx.x;
    for (int i = t; i < NB2; i += 256) {
        gcur[i] = binBase[i] + offs[(size_t)blockIdx.x * NB2 + i];
        fil[i] = 0;
    }
    __syncthreads();
    int cs = blockIdx.x * EPB;
    int ce = cs + EPB; if (ce > E) ce = E;
    float wf0 = Wf[0], wf1 = Wf[1], wf2 = Wf[2], b0 = bf[0];
    float ws0 = Ws[0], ws1 = Ws[1], ws2 = Ws[2], b1 = bs[0];
    for (int rb = cs; rb < ce; rb += RND) {
        int s4[4], d4[4]; float a4[4]; bool vl[4];
        int eb = rb + t * 4;
        if (rb + RND <= ce) {
            int4 sv = *(const int4*)(src + eb);
            int4 dv = *(const int4*)(dst + eb);
            float4 av = *(const float4*)(ea + eb);
            s4[0]=sv.x; s4[1]=sv.y; s4[2]=sv.z; s4[3]=sv.w;
            d4[0]=dv.x; d4[1]=dv.y; d4[2]=dv.z; d4[3]=dv.w;
            a4[0]=av.x; a4[1]=av.y; a4[2]=av.z; a4[3]=av.w;
            vl[0]=vl[1]=vl[2]=vl[3]=true;
        } else {
            #pragma unroll
            for (int j = 0; j < 4; ++j) {
                int e = eb + j;
                vl[j] = e < ce;
                s4[j] = vl[j] ? src[e] : 0;
                d4[j] = vl[j] ? dst[e] : 0;
                a4[j] = vl[j] ? ea[e]  : 0.f;
            }
        }
        #pragma unroll
        for (int j = 0; j < 4; ++j) {
            if (!vl[j]) continue;
            int d = d4[j];
            float m = edge_m(x[d], x[s4[j]], a4[j], wf0, wf1, wf2, b0, ws0, ws1, ws2, b1);
            unsigned bin = ((unsigned)d) >> BSH;
            unsigned short dl = (unsigned short)(d & ((1 << BSH) - 1));
            unsigned slot = atomicAdd(&fil[bin], 1u);
            if (slot < CAP) { smv[bin][slot] = m; sdv[bin][slot] = dl; }
            else { unsigned gp = gcur[bin] + slot; bm[gp] = m; bdl[gp] = dl; }  // rare overflow
        }
        __syncthreads();
        for (int b2 = t; b2 < NB2; b2 += 256) {
            unsigned c = fil[b2];
            if (c) {
                unsigned g = gcur[b2];
                unsigned cc = c < CAP ? c : CAP;
                for (unsigned k2 = 0; k2 < cc; ++k2) {
                    bm[g + k2]  = smv[b2][k2];
                    bdl[g + k2] = sdv[b2][k2];
                }
                gcur[b2] = g + c;
                fil[b2] = 0;
            }
        }
        __syncthreads();
    }
}

// Phase D: per-bin LDS aggregation -> aggr, fused sum/sumsq stats
__global__ void __launch_bounds__(256) k_aggr2(
        const float* __restrict__ bm, const unsigned short* __restrict__ bdl,
        const unsigned* __restrict__ binBase, float* __restrict__ aggr,
        float* __restrict__ stats, int N) {
    __shared__ float acc[1 << BSH];
    int t = threadIdx.x, b = blockIdx.x;
    for (int i = t; i < (1 << BSH); i += 256) acc[i] = 0.f;
    __syncthreads();
    unsigned lo = binBase[b], hi = binBase[b + 1];
    for (unsigned i = lo + t; i < hi; i += 256)
        atomicAdd(&acc[bdl[i]], bm[i]);
    __syncthreads();
    int nb = b << BSH;
    float s = 0.f, q = 0.f;
    for (int i = t; i < (1 << BSH); i += 256) {
        int node = nb + i;
        if (node < N) { float v = acc[i]; aggr[node] = v; s += v; q += v * v; }
    }
    __shared__ float s1[256], s2[256];
    s1[t] = s; s2[t] = q; __syncthreads();
    for (int o = 128; o > 0; o >>= 1) {
        if (t < o) { s1[t] += s1[t + o]; s2[t] += s2[t + o]; }
        __syncthreads();
    }
    if (t == 0) { atomicAdd(&stats[0], s1[0]); atomicAdd(&stats[1], s2[0]); }
}

// ---------------- conv1 atomic fallback (ws too small) ----------------
__global__ void k_conv1(const float* __restrict__ x, const float* __restrict__ ea,
                        const int* __restrict__ src, const int* __restrict__ dst,
                        const float* __restrict__ Wf, const float* __restrict__ bf,
                        const float* __restrict__ Ws, const float* __restrict__ bs,
                        float* __restrict__ aggr, int E) {
    int e = blockIdx.x * blockDim.x + threadIdx.x;
    if (e >= E) return;
    int s = src[e], d = dst[e];
    atomicAdd(&aggr[d], edge_m(x[d], x[s], ea[e], Wf[0], Wf[1], Wf[2], bf[0],
                               Ws[0], Ws[1], Ws[2], bs[0]));
}

// ---------------- conv2: filtered edges, sparse atomics ----------------
__global__ void k_conv2(const float* __restrict__ x2, const float* __restrict__ ea,
                        const int* __restrict__ src, const int* __restrict__ dst,
                        const int* __restrict__ nidx,
                        const float* __restrict__ Wf, const float* __restrict__ bf,
                        const float* __restrict__ Ws, const float* __restrict__ bs,
                        float* __restrict__ aggr, int E) {
    int e = blockIdx.x * blockDim.x + threadIdx.x;
    if (e >= E) return;
    int nd = nidx[dst[e]];
    if (nd < 0) return;                  // ~90% exit before touching src
    int ns = nidx[src[e]];
    if (ns < 0) return;                  // ~99% exit before touching ea
    atomicAdd(&aggr[nd], edge_m(x2[nd], x2[ns], ea[e], Wf[0], Wf[1], Wf[2], bf[0],
                                Ws[0], Ws[1], Ws[2], bs[0]));
}

// ---------------- sum / sumsq reduction (fallback path) ----------------
__global__ void k_stats(const float* __restrict__ a, int n, float* __restrict__ stats) {
    float s = 0.f, q = 0.f;
    int stride = gridDim.x * blockDim.x;
    for (int i = blockIdx.x * blockDim.x + threadIdx.x; i < n; i += stride) {
        float v = a[i]; s += v; q += v * v;
    }
    __shared__ float s1[256], s2[256];
    s1[threadIdx.x] = s; s2[threadIdx.x] = q; __syncthreads();
    for (int o = 128; o > 0; o >>= 1) {
        if (threadIdx.x < o) { s1[threadIdx.x] += s1[threadIdx.x + o]; s2[threadIdx.x] += s2[threadIdx.x + o]; }
        __syncthreads();
    }
    if (threadIdx.x == 0) { atomicAdd(&stats[0], s1[0]); atomicAdd(&stats[1], s2[0]); }
}

// ---------------- batchnorm + residual (+ fused sort-key emit) ----------------
__global__ void k_bn(const float* __restrict__ aggr, const float* __restrict__ xin,
                     const float* __restrict__ stats, const float* __restrict__ g,
                     const float* __restrict__ be, float* __restrict__ xout,
                     int n, float invn, const float* __restrict__ consts, int ci,
                     unsigned* __restrict__ keys, unsigned* __restrict__ vals) {
    int i = blockIdx.x * blockDim.x + threadIdx.x;
    if (i >= n) return;
    float mean = stats[0] * invn;
    float var  = stats[1] * invn - mean * mean;
    float inv  = 1.0f / sqrtf(var + 1e-5f);
    float v = g[0] * (aggr[i] - mean) * inv + be[0] + xin[i];
    xout[i] = v;
    if (keys) {
        float s = tanhf(v * consts[ci]);
        keys[i] = key_desc(s);
        vals[i] = (unsigned)i;
    }
}

// ---------------- radix sort: per-chunk histogram ----------------
__global__ void k_hist(const unsigned* __restrict__ keys, unsigned* __restrict__ hist,
                       int n, int shift) {
    __shared__ unsigned h[256];
    h[threadIdx.x] = 0;
    __syncthreads();
    int base = blockIdx.x * CHUNK;
    int end = base + CHUNK; if (end > n) end = n;
    for (int i = base + threadIdx.x; i < end; i += 256)
        atomicAdd(&h[(keys[i] >> shift) & 255u], 1u);
    __syncthreads();
    hist[blockIdx.x * 256 + threadIdx.x] = h[threadIdx.x];
}

// ---------------- radix sort: stable scatter (4 waves / block) ----------------
__global__ void __launch_bounds__(256) k_scatter(const unsigned* __restrict__ keys,
                                                 const unsigned* __restrict__ vals,
                                                 unsigned* __restrict__ okeys,
                                                 unsigned* __restrict__ ovals,
                                                 const unsigned* __restrict__ offs,
                                                 const unsigned* __restrict__ base_,
                                                 int n, int shift) {
    __shared__ unsigned run[256];
    __shared__ unsigned offl[256];
    __shared__ unsigned wcnt[4][256];
    __shared__ unsigned wpre[4][256];
    int t = threadIdx.x;
    int wave = t >> 6, lane = t & 63;
    run[t] = 0;
    offl[t] = offs[(size_t)blockIdx.x * 256 + t] + base_[t];
    __syncthreads();
    int cbase = blockIdx.x * CHUNK;
    const int GROUPS = CHUNK / 256;
    for (int gix = 0; gix < GROUPS; ++gix) {
        int i = cbase + gix * 256 + t;
        bool active = i < n;
        unsigned k = active ? keys[i] : 0u;
        unsigned v = active ? vals[i] : 0u;
        unsigned d = (k >> shift) & 255u;
        unsigned long long amask = __ballot(active);
        unsigned long long bb[8];
        #pragma unroll
        for (int bit = 0; bit < 8; ++bit) bb[bit] = __ballot(active && ((d >> bit) & 1u));
        unsigned long long m = amask;
        #pragma unroll
        for (int bit = 0; bit < 8; ++bit) m &= ((d >> bit) & 1u) ? bb[bit] : ~bb[bit];
        unsigned rk = (unsigned)__popcll(m & ((1ull << lane) - 1ull));
        #pragma unroll
        for (int j = 0; j < 4; ++j) {
            unsigned dd = (unsigned)lane + j * 64u;
            unsigned long long mm = amask;
            #pragma unroll
            for (int bit = 0; bit < 8; ++bit) mm &= ((dd >> bit) & 1u) ? bb[bit] : ~bb[bit];
            wcnt[wave][dd] = (unsigned)__popcll(mm);
        }
        __syncthreads();
        {
            unsigned r = run[t];
            unsigned c0 = wcnt[0][t], c1 = wcnt[1][t], c2 = wcnt[2][t], c3 = wcnt[3][t];
            wpre[0][t] = r;
            wpre[1][t] = r + c0;
            wpre[2][t] = r + c0 + c1;
            wpre[3][t] = r + c0 + c1 + c2;
            run[t] = r + c0 + c1 + c2 + c3;
        }
        __syncthreads();
        if (active) {
            unsigned pos = offl[d] + wpre[wave][d] + rk;
            okeys[pos] = k;
            ovals[pos] = v;
        }
    }
}

// ---------------- pool gather (+ optional new_idx, + optional next-sort keys) ----------------
__global__ void k_pool(const unsigned* __restrict__ perm, const float* __restrict__ xin,
                       const float* __restrict__ consts, int ci,
                       float* __restrict__ xout, int* __restrict__ newidx, int k,
                       unsigned* __restrict__ okeys, unsigned* __restrict__ ovals, int nci) {
    int r = blockIdx.x * blockDim.x + threadIdx.x;
    if (r >= k) return;
    unsigned p = perm[r];
    float xv = xin[p];
    float s = tanhf(xv * consts[ci]);
    float o = xv * s;
    xout[r] = o;
    if (newidx) newidx[p] = r;
    if (okeys) {
        float s2 = tanhf(o * consts[nci]);
        okeys[r] = key_desc(s2);
        ovals[r] = (unsigned)r;
    }
}

// ---------------- final MLP + log_softmax ----------------
__global__ void k_mlp(const float* __restrict__ x5, const float* __restrict__ Wl1,
                      const float* __restrict__ bl1, const float* __restrict__ Wl2,
                      const float* __restrict__ bl2, float* __restrict__ out, int n) {
    int i = blockIdx.x * blockDim.x + threadIdx.x;
    if (i >= n) return;
    float xv = x5[i];
    float l0 = bl2[0], l1 = bl2[1];
    #pragma unroll
    for (int j = 0; j < 8; ++j) {
        float h = fmaxf(xv * Wl1[j] + bl1[j], 0.0f);
        l0 += h * Wl2[2 * j];
        l1 += h * Wl2[2 * j + 1];
    }
    float mx = fmaxf(l0, l1);
    float lse = mx + logf(expf(l0 - mx) + expf(l1 - mx));
    out[2 * i]     = l0 - lse;
    out[2 * i + 1] = l1 - lse;
}

// ---------------- host-side radix sort driver ----------------
static void sort_pairs(hipStream_t stream, unsigned* kA, unsigned* vA,
                       unsigned* kB, unsigned* vB, unsigned* hist, unsigned* offs,
                       unsigned* tot, unsigned* base, int n) {
    int G = (n + CHUNK - 1) / CHUNK;
    unsigned *ki = kA, *vi = vA, *ko = kB, *vo = vB;
    for (int p = 0; p < 4; ++p) {
        int shift = p * 8;
        k_hist<<<G, 256, 0, stream>>>(ki, hist, n, shift);
        k_scanA<<<256, 256, 0, stream>>>(hist, offs, tot, G);
        k_scanB<<<1, 256, 0, stream>>>(tot, base, 256);
        k_scatter<<<G, 256, 0, stream>>>(ki, vi, ko, vo, offs, base, n, shift);
        unsigned* t;
        t = ki; ki = ko; ko = t;
        t = vi; vi = vo; vo = t;
    }
}

extern "C" void kernel_launch(void* const* d_in, const int* in_sizes, int n_in,
                              void* d_out, int out_size, void* d_ws, size_t ws_size,
                              hipStream_t stream) {
    const float* x   = (const float*)d_in[0];
    const float* ea  = (const float*)d_in[1];
    const int*   src = (const int*)d_in[2];
    const int*   dst = (const int*)d_in[3];
    const float *Wf1 = (const float*)d_in[5],  *bf1 = (const float*)d_in[6];
    const float *Ws1 = (const float*)d_in[7],  *bs1 = (const float*)d_in[8];
    const float *g1  = (const float*)d_in[9],  *be1 = (const float*)d_in[10];
    const float *Wf2 = (const float*)d_in[11], *bf2 = (const float*)d_in[12];
    const float *Ws2 = (const float*)d_in[13], *bs2 = (const float*)d_in[14];
    const float *g2  = (const float*)d_in[15], *be2 = (const float*)d_in[16];
    const float *pw1 = (const float*)d_in[17], *pw2 = (const float*)d_in[18], *pw3 = (const float*)d_in[19];
    const float *Wl1 = (const float*)d_in[20], *bl1 = (const float*)d_in[21];
    const float *Wl2 = (const float*)d_in[22], *bl2 = (const float*)d_in[23];

    const int N  = in_sizes[0];
    const int E  = in_sizes[1];
    const int K1 = 100000, K2 = 10000, K3 = 2500;

    // ---- workspace layout ----
    size_t off = 0;
    auto alloc = [&](size_t bytes) { size_t o = off; off = (off + bytes + 255) & ~(size_t)255; return o; };
    char* ws = (char*)d_ws;
    size_t o_x1    = alloc((size_t)N * 4);
    size_t o_nidx  = alloc((size_t)N * 4);
    size_t o_stats = alloc(256);
    size_t o_const = alloc(256);
    size_t o_tot   = alloc(4096);                 // up to 1024 digits
    size_t o_base  = alloc(8192);                 // up to 1024+1
    size_t o_x2    = alloc((size_t)K1 * 4);
    size_t o_x3    = alloc((size_t)K1 * 4);
    size_t o_ag2   = alloc((size_t)K1 * 4);
    size_t o_x4    = alloc((size_t)K2 * 4);
    size_t o_x5    = alloc((size_t)K3 * 4);
    size_t o_ag1   = alloc((size_t)N * 4);
    size_t o_arena = off;

    // conv1 partition chunking
    int EPB = (((E + 1023) / 1024 + 1023) & ~1023);            // ~E/1024 rounded to RND
    EPB = ((E + 1023) / 1024);                                  // target ~1024 chunks
    EPB = (EPB + RND - 1) & ~(RND - 1);                         // multiple of RND
    if (EPB < RND) EPB = RND;
    int GC = (E + EPB - 1) / EPB;                               // actual chunk count

    // arena overlay A: partition scratch (dead after k_aggr2)
    size_t p_bm  = 0;
    size_t p_bdl = p_bm  + (((size_t)E * 4 + 255) & ~(size_t)255);
    size_t p_eh  = p_bdl + (((size_t)E * 2 + 255) & ~(size_t)255);
    size_t p_eo  = p_eh  + (((size_t)GC * NB2 * 4 + 255) & ~(size_t)255);
    size_t partSz = p_eo + (size_t)GC * NB2 * 4;
    // arena overlay B: sort scratch (live from k_bn onward)
    int G1 = (N + CHUNK - 1) / CHUNK;
    size_t s_kA = 0;
    size_t s_vA = s_kA + (((size_t)N * 4 + 255) & ~(size_t)255);
    size_t s_kB = s_vA + (((size_t)N * 4 + 255) & ~(size_t)255);
    size_t s_vB = s_kB + (((size_t)N * 4 + 255) & ~(size_t)255);
    size_t s_h  = s_vB + (((size_t)N * 4 + 255) & ~(size_t)255);
    size_t s_o  = s_h  + (((size_t)G1 * 256 * 4 + 255) & ~(size_t)255);
    size_t sortSz = s_o + (size_t)G1 * 256 * 4;
    size_t arenaSz = partSz > sortSz ? partSz : sortSz;
    bool usePart = (o_arena + arenaSz) <= ws_size && N <= (NB2 << BSH);

    float*    x1     = (float*)(ws + o_x1);
    int*      nidx   = (int*)(ws + o_nidx);
    float*    stats  = (float*)(ws + o_stats);
    float*    consts = (float*)(ws + o_const);
    unsigned* tot    = (unsigned*)(ws + o_tot);
    unsigned* base   = (unsigned*)(ws + o_base);
    float*    x2     = (float*)(ws + o_x2);
    float*    x3     = (float*)(ws + o_x3);
    float*    aggr2  = (float*)(ws + o_ag2);
    float*    x4     = (float*)(ws + o_x4);
    float*    x5     = (float*)(ws + o_x5);
    float*    aggr1  = (float*)(ws + o_ag1);
    unsigned* kA     = (unsigned*)(ws + o_arena + s_kA);
    unsigned* vA     = (unsigned*)(ws + o_arena + s_vA);
    unsigned* kB     = (unsigned*)(ws + o_arena + s_kB);
    unsigned* vB     = (unsigned*)(ws + o_arena + s_vB);
    unsigned* hist   = (unsigned*)(ws + o_arena + s_h);
    unsigned* offs   = (unsigned*)(ws + o_arena + s_o);

    // init (harness does not re-poison between replays)
    hipMemsetAsync(nidx, 0xFF, (size_t)N * 4, stream);   // -1
    hipMemsetAsync(stats, 0, 64, stream);
    hipMemsetAsync(aggr2, 0, (size_t)K1 * 4, stream);

    k_consts<<<3, 256, 0, stream>>>(pw1, pw2, pw3, consts,
                                    in_sizes[17], in_sizes[18], in_sizes[19]);

    // ---- cgconv 1 (atomic-free partition path) ----
    if (usePart) {
        float*          bm  = (float*)(ws + o_arena + p_bm);
        unsigned short* bdl = (unsigned short*)(ws + o_arena + p_bdl);
        unsigned*       eh  = (unsigned*)(ws + o_arena + p_eh);
        unsigned*       eo  = (unsigned*)(ws + o_arena + p_eo);
        k_ehist2<<<GC, 256, 0, stream>>>(dst, eh, E, EPB);
        k_scanA<<<NB2, 256, 0, stream>>>(eh, eo, tot, GC);
        k_scanB<<<1, 256, 0, stream>>>(tot, base, NB2);
        k_part<<<GC, 256, 0, stream>>>(x, ea, src, dst, Wf1, bf1, Ws1, bs1,
                                       eo, base, bm, bdl, E, EPB);
        int NBN = (N + (1 << BSH) - 1) >> BSH;
        k_aggr2<<<NBN, 256, 0, stream>>>(bm, bdl, base, aggr1, stats, N);
    } else {
        hipMemsetAsync(aggr1, 0, (size_t)N * 4, stream);
        k_conv1<<<(E + 255) / 256, 256, 0, stream>>>(x, ea, src, dst, Wf1, bf1, Ws1, bs1, aggr1, E);
        k_stats<<<1024, 256, 0, stream>>>(aggr1, N, stats);
    }
    k_bn<<<(N + 255) / 256, 256, 0, stream>>>(aggr1, x, stats, g1, be1, x1, N, 1.0f / (float)N,
                                              consts, 0, kA, vA);

    // ---- pool 1 : top 100K of 1M ----
    sort_pairs(stream, kA, vA, kB, vB, hist, offs, tot, base, N);
    k_pool<<<(K1 + 255) / 256, 256, 0, stream>>>(vA, x1, consts, 0, x2, nidx, K1,
                                                 (unsigned*)nullptr, (unsigned*)nullptr, 0);

    // ---- cgconv 2 (filtered edges; sparse atomics) ----
    k_conv2<<<(E + 255) / 256, 256, 0, stream>>>(x2, ea, src, dst, nidx, Wf2, bf2, Ws2, bs2, aggr2, E);
    k_stats<<<256, 256, 0, stream>>>(aggr2, K1, stats + 2);
    k_bn<<<(K1 + 255) / 256, 256, 0, stream>>>(aggr2, x2, stats + 2, g2, be2, x3, K1, 1.0f / (float)K1,
                                               consts, 1, kA, vA);

    // ---- pool 2 : top 10K of 100K (emits keys for pool-3 sort into kB/vB) ----
    sort_pairs(stream, kA, vA, kB, vB, hist, offs, tot, base, K1);
    k_pool<<<(K2 + 255) / 256, 256, 0, stream>>>(vA, x3, consts, 1, x4, (int*)nullptr, K2,
                                                 kB, vB, 2);

    // ---- pool 3 : top 2500 of 10K ----
    sort_pairs(stream, kB, vB, kA, vA, hist, offs, tot, base, K2);
    k_pool<<<(K3 + 255) / 256, 256, 0, stream>>>(vB, x4, consts, 2, x5, (int*)nullptr, K3,
                                                 (unsigned*)nullptr, (unsigned*)nullptr, 0);

    // ---- MLP + log_softmax ----
    k_mlp<<<(K3 + 255) / 256, 256, 0, stream>>>(x5, Wl1, bl1, Wl2, bl2, (float*)d_out, K3);
}

// Round 5
// 931.909 us; speedup vs baseline: 2.2418x; 1.3621x over previous
//
#include <hip/hip_runtime.h>
#include <math.h>

#define CHUNK 4096               // elements per radix-sort block
#define NB2   256                // conv1 partition bins
#define BSH   12                 // bin = dst >> BSH ; 4096 nodes per bin
#define CAP   24                 // LDS stage capacity per bin (records)
#define CAPW  49                 // LDS words per bin (odd -> conflict-free)
#define FG    16                 // flush group: 16 records = 128 B
#define RND   1024               // edges per staging round (256 thr * 4)
#define EPB   32768              // edges per k_part block

__device__ __forceinline__ float sigmoidf_(float x) {
    if (x >= 0.0f) { float e = expf(-x); return 1.0f / (1.0f + e); }
    float e = expf(x); return e / (1.0f + e);
}
__device__ __forceinline__ float softplusf_(float x) {
    return fmaxf(x, 0.0f) + log1pf(expf(-fabsf(x)));
}
__device__ __forceinline__ unsigned key_desc(float f) {
    unsigned u = __float_as_uint(f);
    unsigned ka = (u & 0x80000000u) ? ~u : (u | 0x80000000u);  // ascending map
    return ~ka;                                                 // descending
}
__device__ __forceinline__ float edge_m(float xd, float xs, float a,
                                        float wf0, float wf1, float wf2, float b0,
                                        float ws0, float ws1, float ws2, float b1) {
    float f = xd * wf0 + xs * wf1 + a * wf2 + b0;
    float g = xd * ws0 + xs * ws1 + a * ws2 + b1;
    return sigmoidf_(f) * softplusf_(g);
}

// ---------------- score constants c = sum(w)/norm(w) ----------------
__global__ void k_consts(const float* __restrict__ pw1, const float* __restrict__ pw2,
                         const float* __restrict__ pw3, float* __restrict__ consts,
                         int n1, int n2, int n3) {
    const float* w; int n;
    if (blockIdx.x == 0)      { w = pw1; n = n1; }
    else if (blockIdx.x == 1) { w = pw2; n = n2; }
    else                      { w = pw3; n = n3; }
    __shared__ float s1[256], s2[256];
    float a = 0.f, b = 0.f;
    for (int i = threadIdx.x; i < n; i += 256) { float v = w[i]; a += v; b += v * v; }
    s1[threadIdx.x] = a; s2[threadIdx.x] = b; __syncthreads();
    for (int o = 128; o > 0; o >>= 1) {
        if (threadIdx.x < o) { s1[threadIdx.x] += s1[threadIdx.x + o]; s2[threadIdx.x] += s2[threadIdx.x + o]; }
        __syncthreads();
    }
    if (threadIdx.x == 0) consts[blockIdx.x] = s1[0] / sqrtf(s2[0]);
}

// ============== conv1: atomic-free two-level partition ==============
// Phase A: per-chunk histogram of dst>>BSH (vec4 streaming)
__global__ void __launch_bounds__(256) k_ehist2(const int* __restrict__ dst,
                                                unsigned* __restrict__ hist,
                                                int e0, int e1) {
    __shared__ unsigned h[NB2];
    int t = threadIdx.x;
    h[t] = 0;
    __syncthreads();
    int cs = e0 + blockIdx.x * EPB;
    int ce = cs + EPB; if (ce > e1) ce = e1;
    for (int eb = cs; eb < ce; eb += RND) {
        int i = eb + t * 4;
        if (eb + RND <= ce) {
            int4 d4 = *(const int4*)(dst + i);
            atomicAdd(&h[((unsigned)d4.x) >> BSH], 1u);
            atomicAdd(&h[((unsigned)d4.y) >> BSH], 1u);
            atomicAdd(&h[((unsigned)d4.z) >> BSH], 1u);
            atomicAdd(&h[((unsigned)d4.w) >> BSH], 1u);
        } else {
            #pragma unroll
            for (int j = 0; j < 4; ++j)
                if (i + j < ce) atomicAdd(&h[((unsigned)dst[i + j]) >> BSH], 1u);
        }
    }
    __syncthreads();
    hist[(size_t)blockIdx.x * NB2 + t] = h[t];
}

// generic scanA: one block per digit d; within-digit exclusive prefix over blocks
__global__ void k_scanA(const unsigned* __restrict__ hist, unsigned* __restrict__ offs,
                        unsigned* __restrict__ tot, int G) {
    int d = blockIdx.x, ND = gridDim.x, t = threadIdx.x;
    __shared__ unsigned s[256];
    unsigned carry = 0;
    for (int tile = 0; tile * 256 < G; ++tile) {
        int g = tile * 256 + t;
        unsigned v = (g < G) ? hist[(size_t)g * ND + d] : 0u;
        s[t] = v; __syncthreads();
        for (int o = 1; o < 256; o <<= 1) {
            unsigned u = (t >= o) ? s[t - o] : 0u;
            __syncthreads();
            s[t] += u; __syncthreads();
        }
        if (g < G) offs[(size_t)g * ND + d] = s[t] - v + carry;
        unsigned tl = s[255]; __syncthreads();
        carry += tl;
    }
    if (t == 0) tot[d] = carry;
}

// generic scanB: exclusive scan of tot[ND] -> base[ND]; per-digit totals rounded
// up by rmask (0 for sorts; FG-1 for conv1 so bin regions are 128B-aligned)
__global__ void k_scanB(const unsigned* __restrict__ tot, unsigned* __restrict__ base,
                        int ND, unsigned rmask) {
    __shared__ unsigned s[256];
    int t = threadIdx.x;
    unsigned carry = 0;
    for (int tile = 0; tile * 256 < ND; ++tile) {
        int d = tile * 256 + t;
        unsigned v = (d < ND) ? ((tot[d] + rmask) & ~rmask) : 0u;
        s[t] = v; __syncthreads();
        for (int o = 1; o < 256; o <<= 1) {
            unsigned u = (t >= o) ? s[t - o] : 0u;
            __syncthreads();
            s[t] += u; __syncthreads();
        }
        if (d < ND) base[d] = s[t] - v + carry;
        unsigned tl = s[255]; __syncthreads();
        carry += tl;
    }
    if (t == 0) base[ND] = carry;
}

// Phase C: compute m, stage 8B records per bin in LDS, flush 128B groups
__global__ void __launch_bounds__(256) k_part(
        const float* __restrict__ x, const float* __restrict__ ea,
        const int* __restrict__ src, const int* __restrict__ dst,
        const float* __restrict__ Wf, const float* __restrict__ bf,
        const float* __restrict__ Ws, const float* __restrict__ bs,
        const unsigned* __restrict__ offs, const unsigned* __restrict__ binBase,
        uint2* __restrict__ rec, int e0, int e1) {
    __shared__ unsigned stage[NB2 * CAPW];
    __shared__ unsigned gcur[NB2], fil[NB2];
    int t = threadIdx.x;
    gcur[t] = binBase[t] + offs[(size_t)blockIdx.x * NB2 + t];
    fil[t] = 0;
    __syncthreads();
    int cs = e0 + blockIdx.x * EPB;
    int ce = cs + EPB; if (ce > e1) ce = e1;
    float wf0 = Wf[0], wf1 = Wf[1], wf2 = Wf[2], b0 = bf[0];
    float ws0 = Ws[0], ws1 = Ws[1], ws2 = Ws[2], b1 = bs[0];
    for (int rb = cs; rb < ce; rb += RND) {
        int s4[4], d4[4]; float a4[4]; bool vl[4];
        int eb = rb + t * 4;
        if (rb + RND <= ce) {
            int4 sv = *(const int4*)(src + eb);
            int4 dv = *(const int4*)(dst + eb);
            float4 av = *(const float4*)(ea + eb);
            s4[0]=sv.x; s4[1]=sv.y; s4[2]=sv.z; s4[3]=sv.w;
            d4[0]=dv.x; d4[1]=dv.y; d4[2]=dv.z; d4[3]=dv.w;
            a4[0]=av.x; a4[1]=av.y; a4[2]=av.z; a4[3]=av.w;
            vl[0]=vl[1]=vl[2]=vl[3]=true;
        } else {
            #pragma unroll
            for (int j = 0; j < 4; ++j) {
                int e = eb + j;
                vl[j] = e < ce;
                s4[j] = vl[j] ? src[e] : 0;
                d4[j] = vl[j] ? dst[e] : 0;
                a4[j] = vl[j] ? ea[e]  : 0.f;
            }
        }
        #pragma unroll
        for (int j = 0; j < 4; ++j) {
            if (!vl[j]) continue;
            int d = d4[j];
            float m = edge_m(x[d], x[s4[j]], a4[j], wf0, wf1, wf2, b0, ws0, ws1, ws2, b1);
            unsigned bin = ((unsigned)d) >> BSH;
            unsigned dl  = (unsigned)(d & ((1 << BSH) - 1));
            unsigned slot = atomicAdd(&fil[bin], 1u);
            if (slot < CAP) {
                stage[bin * CAPW + 2 * slot]     = __float_as_uint(m);
                stage[bin * CAPW + 2 * slot + 1] = dl;
            } else {
                rec[gcur[bin] + slot] = make_uint2(__float_as_uint(m), dl);  // rare
            }
        }
        __syncthreads();
        {   // flush phase: thread t owns bin t
            unsigned c = fil[t], g = gcur[t];
            unsigned* st = &stage[t * CAPW];
            if (c > CAP) {           // rare drain-all (overflow already in place)
                for (unsigned k = 0; k < CAP; ++k)
                    rec[g + k] = make_uint2(st[2 * k], st[2 * k + 1]);
                gcur[t] = g + c; fil[t] = 0;
            } else {
                unsigned ngrp = c >> 4;
                if (ngrp) {
                    unsigned nfl = ngrp << 4;
                    for (unsigned k = 0; k < nfl; ++k)
                        rec[g + k] = make_uint2(st[2 * k], st[2 * k + 1]);
                    unsigned rem = c - nfl;
                    for (unsigned k = 0; k < rem; ++k) {
                        st[2 * k]     = st[2 * (nfl + k)];
                        st[2 * k + 1] = st[2 * (nfl + k) + 1];
                    }
                    gcur[t] = g + nfl; fil[t] = rem;
                }
            }
        }
        __syncthreads();
    }
    // tail drain
    {
        unsigned c = fil[t], g = gcur[t];
        unsigned* st = &stage[t * CAPW];
        unsigned cc = c < CAP ? c : CAP;
        for (unsigned k = 0; k < cc; ++k)
            rec[g + k] = make_uint2(st[2 * k], st[2 * k + 1]);
    }
}

// Phase D: per-bin LDS aggregation -> aggr, optional fused sum/sumsq stats
__global__ void __launch_bounds__(256) k_aggr2(
        const uint2* __restrict__ rec, const unsigned* __restrict__ base,
        const unsigned* __restrict__ tot, float* __restrict__ aggr,
        float* __restrict__ stats, int N, int accumulate, int doStats) {
    __shared__ float acc[1 << BSH];
    int t = threadIdx.x, b = blockIdx.x;
    for (int i = t; i < (1 << BSH); i += 256) acc[i] = 0.f;
    __syncthreads();
    unsigned lo = base[b], hi = lo + tot[b];
    for (unsigned i = lo + t; i < hi; i += 256) {
        uint2 r = rec[i];
        atomicAdd(&acc[r.y], __uint_as_float(r.x));
    }
    __syncthreads();
    int nb = b << BSH;
    float s = 0.f, q = 0.f;
    for (int i = t; i < (1 << BSH); i += 256) {
        int node = nb + i;
        if (node < N) {
            float v = acc[i];
            if (accumulate) v += aggr[node];
            aggr[node] = v;
            if (doStats) { s += v; q += v * v; }
        }
    }
    if (doStats) {
        __shared__ float s1[256], s2[256];
        s1[t] = s; s2[t] = q; __syncthreads();
        for (int o = 128; o > 0; o >>= 1) {
            if (t < o) { s1[t] += s1[t + o]; s2[t] += s2[t + o]; }
            __syncthreads();
        }
        if (t == 0) { atomicAdd(&stats[0], s1[0]); atomicAdd(&stats[1], s2[0]); }
    }
}

// ---------------- conv1 atomic fallback (ws too small) ----------------
__global__ void k_conv1(const float* __restrict__ x, const float* __restrict__ ea,
                        const int* __restrict__ src, const int* __restrict__ dst,
                        const float* __restrict__ Wf, const float* __restrict__ bf,
                        const float* __restrict__ Ws, const float* __restrict__ bs,
                        float* __restrict__ aggr, int E) {
    int e = blockIdx.x * blockDim.x + threadIdx.x;
    if (e >= E) return;
    int s = src[e], d = dst[e];
    atomicAdd(&aggr[d], edge_m(x[d], x[s], ea[e], Wf[0], Wf[1], Wf[2], bf[0],
                               Ws[0], Ws[1], Ws[2], bs[0]));
}

// ---------------- conv2: filtered edges, sparse atomics ----------------
__global__ void k_conv2(const float* __restrict__ x2, const float* __restrict__ ea,
                        const int* __restrict__ src, const int* __restrict__ dst,
                        const int* __restrict__ nidx,
                        const float* __restrict__ Wf, const float* __restrict__ bf,
                        const float* __restrict__ Ws, const float* __restrict__ bs,
                        float* __restrict__ aggr, int E) {
    int e = blockIdx.x * blockDim.x + threadIdx.x;
    if (e >= E) return;
    int nd = nidx[dst[e]];
    if (nd < 0) return;
    int ns = nidx[src[e]];
    if (ns < 0) return;
    atomicAdd(&aggr[nd], edge_m(x2[nd], x2[ns], ea[e], Wf[0], Wf[1], Wf[2], bf[0],
                                Ws[0], Ws[1], Ws[2], bs[0]));
}

// ---------------- sum / sumsq reduction ----------------
__global__ void k_stats(const float* __restrict__ a, int n, float* __restrict__ stats) {
    float s = 0.f, q = 0.f;
    int stride = gridDim.x * blockDim.x;
    for (int i = blockIdx.x * blockDim.x + threadIdx.x; i < n; i += stride) {
        float v = a[i]; s += v; q += v * v;
    }
    __shared__ float s1[256], s2[256];
    s1[threadIdx.x] = s; s2[threadIdx.x] = q; __syncthreads();
    for (int o = 128; o > 0; o >>= 1) {
        if (threadIdx.x < o) { s1[threadIdx.x] += s1[threadIdx.x + o]; s2[threadIdx.x] += s2[threadIdx.x + o]; }
        __syncthreads();
    }
    if (threadIdx.x == 0) { atomicAdd(&stats[0], s1[0]); atomicAdd(&stats[1], s2[0]); }
}

// ---------------- batchnorm + residual (+ fused sort-key emit) ----------------
__global__ void k_bn(const float* __restrict__ aggr, const float* __restrict__ xin,
                     const float* __restrict__ stats, const float* __restrict__ g,
                     const float* __restrict__ be, float* __restrict__ xout,
                     int n, float invn, const float* __restrict__ consts, int ci,
                     unsigned* __restrict__ keys, unsigned* __restrict__ vals) {
    int i = blockIdx.x * blockDim.x + threadIdx.x;
    if (i >= n) return;
    float mean = stats[0] * invn;
    float var  = stats[1] * invn - mean * mean;
    float inv  = 1.0f / sqrtf(var + 1e-5f);
    float v = g[0] * (aggr[i] - mean) * inv + be[0] + xin[i];
    xout[i] = v;
    if (keys) {
        float s = tanhf(v * consts[ci]);
        keys[i] = key_desc(s);
        vals[i] = (unsigned)i;
    }
}

// ---------------- radix sort: per-chunk histogram ----------------
__global__ void k_hist(const unsigned* __restrict__ keys, unsigned* __restrict__ hist,
                       int n, int shift) {
    __shared__ unsigned h[256];
    h[threadIdx.x] = 0;
    __syncthreads();
    int base = blockIdx.x * CHUNK;
    int end = base + CHUNK; if (end > n) end = n;
    for (int i = base + threadIdx.x; i < end; i += 256)
        atomicAdd(&h[(keys[i] >> shift) & 255u], 1u);
    __syncthreads();
    hist[blockIdx.x * 256 + threadIdx.x] = h[threadIdx.x];
}

// ---------------- radix sort: stable scatter (4 waves / block) ----------------
__global__ void __launch_bounds__(256) k_scatter(const unsigned* __restrict__ keys,
                                                 const unsigned* __restrict__ vals,
                                                 unsigned* __restrict__ okeys,
                                                 unsigned* __restrict__ ovals,
                                                 const unsigned* __restrict__ offs,
                                                 const unsigned* __restrict__ base_,
                                                 int n, int shift) {
    __shared__ unsigned run[256];
    __shared__ unsigned offl[256];
    __shared__ unsigned wcnt[4][256];
    __shared__ unsigned wpre[4][256];
    int t = threadIdx.x;
    int wave = t >> 6, lane = t & 63;
    run[t] = 0;
    offl[t] = offs[(size_t)blockIdx.x * 256 + t] + base_[t];
    __syncthreads();
    int cbase = blockIdx.x * CHUNK;
    const int GROUPS = CHUNK / 256;
    for (int gix = 0; gix < GROUPS; ++gix) {
        int i = cbase + gix * 256 + t;
        bool active = i < n;
        unsigned k = active ? keys[i] : 0u;
        unsigned v = active ? vals[i] : 0u;
        unsigned d = (k >> shift) & 255u;
        unsigned long long amask = __ballot(active);
        unsigned long long bb[8];
        #pragma unroll
        for (int bit = 0; bit < 8; ++bit) bb[bit] = __ballot(active && ((d >> bit) & 1u));
        unsigned long long m = amask;
        #pragma unroll
        for (int bit = 0; bit < 8; ++bit) m &= ((d >> bit) & 1u) ? bb[bit] : ~bb[bit];
        unsigned rk = (unsigned)__popcll(m & ((1ull << lane) - 1ull));
        #pragma unroll
        for (int j = 0; j < 4; ++j) {
            unsigned dd = (unsigned)lane + j * 64u;
            unsigned long long mm = amask;
            #pragma unroll
            for (int bit = 0; bit < 8; ++bit) mm &= ((dd >> bit) & 1u) ? bb[bit] : ~bb[bit];
            wcnt[wave][dd] = (unsigned)__popcll(mm);
        }
        __syncthreads();
        {
            unsigned r = run[t];
            unsigned c0 = wcnt[0][t], c1 = wcnt[1][t], c2 = wcnt[2][t], c3 = wcnt[3][t];
            wpre[0][t] = r;
            wpre[1][t] = r + c0;
            wpre[2][t] = r + c0 + c1;
            wpre[3][t] = r + c0 + c1 + c2;
            run[t] = r + c0 + c1 + c2 + c3;
        }
        __syncthreads();
        if (active) {
            unsigned pos = offl[d] + wpre[wave][d] + rk;
            okeys[pos] = k;
            ovals[pos] = v;
        }
    }
}

// ---------------- pool gather (+ optional new_idx, + optional next-sort keys) ----------------
__global__ void k_pool(const unsigned* __restrict__ perm, const float* __restrict__ xin,
                       const float* __restrict__ consts, int ci,
                       float* __restrict__ xout, int* __restrict__ newidx, int k,
                       unsigned* __restrict__ okeys, unsigned* __restrict__ ovals, int nci) {
    int r = blockIdx.x * blockDim.x + threadIdx.x;
    if (r >= k) return;
    unsigned p = perm[r];
    float xv = xin[p];
    float s = tanhf(xv * consts[ci]);
    float o = xv * s;
    xout[r] = o;
    if (newidx) newidx[p] = r;
    if (okeys) {
        float s2 = tanhf(o * consts[nci]);
        okeys[r] = key_desc(s2);
        ovals[r] = (unsigned)r;
    }
}

// ---------------- final MLP + log_softmax ----------------
__global__ void k_mlp(const float* __restrict__ x5, const float* __restrict__ Wl1,
                      const float* __restrict__ bl1, const float* __restrict__ Wl2,
                      const float* __restrict__ bl2, float* __restrict__ out, int n) {
    int i = blockIdx.x * blockDim.x + threadIdx.x;
    if (i >= n) return;
    float xv = x5[i];
    float l0 = bl2[0], l1 = bl2[1];
    #pragma unroll
    for (int j = 0; j < 8; ++j) {
        float h = fmaxf(xv * Wl1[j] + bl1[j], 0.0f);
        l0 += h * Wl2[2 * j];
        l1 += h * Wl2[2 * j + 1];
    }
    float mx = fmaxf(l0, l1);
    float lse = mx + logf(expf(l0 - mx) + expf(l1 - mx));
    out[2 * i]     = l0 - lse;
    out[2 * i + 1] = l1 - lse;
}

// ---------------- host-side radix sort driver ----------------
static void sort_pairs(hipStream_t stream, unsigned* kA, unsigned* vA,
                       unsigned* kB, unsigned* vB, unsigned* hist, unsigned* offs,
                       unsigned* tot, unsigned* base, int n) {
    int G = (n + CHUNK - 1) / CHUNK;
    unsigned *ki = kA, *vi = vA, *ko = kB, *vo = vB;
    for (int p = 0; p < 4; ++p) {
        int shift = p * 8;
        k_hist<<<G, 256, 0, stream>>>(ki, hist, n, shift);
        k_scanA<<<256, 256, 0, stream>>>(hist, offs, tot, G);
        k_scanB<<<1, 256, 0, stream>>>(tot, base, 256, 0u);
        k_scatter<<<G, 256, 0, stream>>>(ki, vi, ko, vo, offs, base, n, shift);
        unsigned* t;
        t = ki; ki = ko; ko = t;
        t = vi; vi = vo; vo = t;
    }
}

extern "C" void kernel_launch(void* const* d_in, const int* in_sizes, int n_in,
                              void* d_out, int out_size, void* d_ws, size_t ws_size,
                              hipStream_t stream) {
    const float* x   = (const float*)d_in[0];
    const float* ea  = (const float*)d_in[1];
    const int*   src = (const int*)d_in[2];
    const int*   dst = (const int*)d_in[3];
    const float *Wf1 = (const float*)d_in[5],  *bf1 = (const float*)d_in[6];
    const float *Ws1 = (const float*)d_in[7],  *bs1 = (const float*)d_in[8];
    const float *g1  = (const float*)d_in[9],  *be1 = (const float*)d_in[10];
    const float *Wf2 = (const float*)d_in[11], *bf2 = (const float*)d_in[12];
    const float *Ws2 = (const float*)d_in[13], *bs2 = (const float*)d_in[14];
    const float *g2  = (const float*)d_in[15], *be2 = (const float*)d_in[16];
    const float *pw1 = (const float*)d_in[17], *pw2 = (const float*)d_in[18], *pw3 = (const float*)d_in[19];
    const float *Wl1 = (const float*)d_in[20], *bl1 = (const float*)d_in[21];
    const float *Wl2 = (const float*)d_in[22], *bl2 = (const float*)d_in[23];

    const int N  = in_sizes[0];
    const int E  = in_sizes[1];
    const int K1 = 100000, K2 = 10000, K3 = 2500;

    // ---- workspace layout ----
    size_t off = 0;
    auto alloc = [&](size_t bytes) { size_t o = off; off = (off + bytes + 255) & ~(size_t)255; return o; };
    char* ws = (char*)d_ws;
    size_t o_x1    = alloc((size_t)N * 4);
    size_t o_nidx  = alloc((size_t)N * 4);
    size_t o_stats = alloc(256);
    size_t o_const = alloc(256);
    size_t o_tot   = alloc(4096);
    size_t o_base  = alloc(8192);
    size_t o_x2    = alloc((size_t)K1 * 4);
    size_t o_x3    = alloc((size_t)K1 * 4);
    size_t o_ag2   = alloc((size_t)K1 * 4);
    size_t o_x4    = alloc((size_t)K2 * 4);
    size_t o_x5    = alloc((size_t)K3 * 4);
    size_t o_ag1   = alloc((size_t)N * 4);
    size_t o_arena = off;

    // sort scratch (overlay B, live from k_bn onward)
    int G1 = (N + CHUNK - 1) / CHUNK;
    size_t s_kA = 0;
    size_t s_vA = s_kA + (((size_t)N * 4 + 255) & ~(size_t)255);
    size_t s_kB = s_vA + (((size_t)N * 4 + 255) & ~(size_t)255);
    size_t s_vB = s_kB + (((size_t)N * 4 + 255) & ~(size_t)255);
    size_t s_h  = s_vB + (((size_t)N * 4 + 255) & ~(size_t)255);
    size_t s_o  = s_h  + (((size_t)G1 * 256 * 4 + 255) & ~(size_t)255);
    size_t sortSz = s_o + (size_t)G1 * 256 * 4;

    // conv1 partition scratch (overlay A, dead after k_aggr2): pick split H
    int H = 0, Eh = 0;
    size_t p_rec = 0, p_eh = 0, p_eo = 0;
    for (int h = 1; h <= 8; h <<= 1) {
        int eh_ = (E + h - 1) / h;
        eh_ = (eh_ + RND - 1) & ~(RND - 1);
        int gc_ = (eh_ + EPB - 1) / EPB;
        size_t recB = (((size_t)(eh_ + NB2 * FG) * 8) + 255) & ~(size_t)255;
        size_t ehB  = (((size_t)gc_ * NB2 * 4) + 255) & ~(size_t)255;
        size_t eoB  = (((size_t)gc_ * NB2 * 4) + 255) & ~(size_t)255;
        size_t partSz = recB + ehB + eoB;
        size_t arenaSz = partSz > sortSz ? partSz : sortSz;
        if (o_arena + arenaSz <= ws_size && N <= (NB2 << BSH)) {
            H = h; Eh = eh_;
            p_rec = 0; p_eh = p_rec + recB; p_eo = p_eh + ehB;
            break;
        }
    }

    float*    x1     = (float*)(ws + o_x1);
    int*      nidx   = (int*)(ws + o_nidx);
    float*    stats  = (float*)(ws + o_stats);
    float*    consts = (float*)(ws + o_const);
    unsigned* tot    = (unsigned*)(ws + o_tot);
    unsigned* base   = (unsigned*)(ws + o_base);
    float*    x2     = (float*)(ws + o_x2);
    float*    x3     = (float*)(ws + o_x3);
    float*    aggr2  = (float*)(ws + o_ag2);
    float*    x4     = (float*)(ws + o_x4);
    float*    x5     = (float*)(ws + o_x5);
    float*    aggr1  = (float*)(ws + o_ag1);
    unsigned* kA     = (unsigned*)(ws + o_arena + s_kA);
    unsigned* vA     = (unsigned*)(ws + o_arena + s_vA);
    unsigned* kB     = (unsigned*)(ws + o_arena + s_kB);
    unsigned* vB     = (unsigned*)(ws + o_arena + s_vB);
    unsigned* hist   = (unsigned*)(ws + o_arena + s_h);
    unsigned* offs   = (unsigned*)(ws + o_arena + s_o);

    // init (harness does not re-poison between replays)
    hipMemsetAsync(nidx, 0xFF, (size_t)N * 4, stream);   // -1
    hipMemsetAsync(stats, 0, 64, stream);
    hipMemsetAsync(aggr2, 0, (size_t)K1 * 4, stream);

    k_consts<<<3, 256, 0, stream>>>(pw1, pw2, pw3, consts,
                                    in_sizes[17], in_sizes[18], in_sizes[19]);

    // ---- cgconv 1 (atomic-free partition path) ----
    if (H > 0) {
        uint2*    rec = (uint2*)(ws + o_arena + p_rec);
        unsigned* eh  = (unsigned*)(ws + o_arena + p_eh);
        unsigned* eo  = (unsigned*)(ws + o_arena + p_eo);
        int NBN = (N + (1 << BSH) - 1) >> BSH;
        for (int h = 0; h < H; ++h) {
            int e0 = h * Eh;
            int e1 = e0 + Eh; if (e1 > E) e1 = E;
            if (e0 >= e1) break;
            int GCh = (e1 - e0 + EPB - 1) / EPB;
            k_ehist2<<<GCh, 256, 0, stream>>>(dst, eh, e0, e1);
            k_scanA<<<NB2, 256, 0, stream>>>(eh, eo, tot, GCh);
            k_scanB<<<1, 256, 0, stream>>>(tot, base, NB2, (unsigned)(FG - 1));
            k_part<<<GCh, 256, 0, stream>>>(x, ea, src, dst, Wf1, bf1, Ws1, bs1,
                                            eo, base, rec, e0, e1);
            k_aggr2<<<NBN, 256, 0, stream>>>(rec, base, tot, aggr1, stats, N,
                                             h > 0, h == H - 1 ? 1 : 0);
        }
    } else {
        hipMemsetAsync(aggr1, 0, (size_t)N * 4, stream);
        k_conv1<<<(E + 255) / 256, 256, 0, stream>>>(x, ea, src, dst, Wf1, bf1, Ws1, bs1, aggr1, E);
        k_stats<<<1024, 256, 0, stream>>>(aggr1, N, stats);
    }
    k_bn<<<(N + 255) / 256, 256, 0, stream>>>(aggr1, x, stats, g1, be1, x1, N, 1.0f / (float)N,
                                              consts, 0, kA, vA);

    // ---- pool 1 : top 100K of 1M ----
    sort_pairs(stream, kA, vA, kB, vB, hist, offs, tot, base, N);
    k_pool<<<(K1 + 255) / 256, 256, 0, stream>>>(vA, x1, consts, 0, x2, nidx, K1,
                                                 (unsigned*)nullptr, (unsigned*)nullptr, 0);

    // ---- cgconv 2 (filtered edges; sparse atomics) ----
    k_conv2<<<(E + 255) / 256, 256, 0, stream>>>(x2, ea, src, dst, nidx, Wf2, bf2, Ws2, bs2, aggr2, E);
    k_stats<<<256, 256, 0, stream>>>(aggr2, K1, stats + 2);
    k_bn<<<(K1 + 255) / 256, 256, 0, stream>>>(aggr2, x2, stats + 2, g2, be2, x3, K1, 1.0f / (float)K1,
                                               consts, 1, kA, vA);

    // ---- pool 2 : top 10K of 100K (emits keys for pool-3 sort into kB/vB) ----
    sort_pairs(stream, kA, vA, kB, vB, hist, offs, tot, base, K1);
    k_pool<<<(K2 + 255) / 256, 256, 0, stream>>>(vA, x3, consts, 1, x4, (int*)nullptr, K2,
                                                 kB, vB, 2);

    // ---- pool 3 : top 2500 of 10K ----
    sort_pairs(stream, kB, vB, kA, vA, hist, offs, tot, base, K2);
    k_pool<<<(K3 + 255) / 256, 256, 0, stream>>>(vB, x4, consts, 2, x5, (int*)nullptr, K3,
                                                 (unsigned*)nullptr, (unsigned*)nullptr, 0);

    // ---- MLP + log_softmax ----
    k_mlp<<<(K3 + 255) / 256, 256, 0, stream>>>(x5, Wl1, bl1, Wl2, bl2, (float*)d_out, K3);
}

// Round 6
// 902.346 us; speedup vs baseline: 2.3152x; 1.0328x over previous
//
#include <hip/hip_runtime.h>
#include <math.h>

#define CHUNK 4096               // elements per radix-sort block
#define NB2   256                // conv1 partition bins
#define BSH   12                 // bin = dst >> BSH ; 4096 nodes per bin
#define CAP   24                 // LDS stage capacity per bin (records)
#define CAPW  49                 // LDS words per bin (odd -> conflict-free)
#define FG    16                 // flush group: 16 records = 128 B
#define RND   1024               // edges per staging round (256 thr * 4)
#define EPB   16384              // edges per k_part block (977 blocks -> 3/CU)

typedef int      i32x4 __attribute__((ext_vector_type(4)));
typedef float    f32x4 __attribute__((ext_vector_type(4)));
typedef unsigned u32x2 __attribute__((ext_vector_type(2)));

__device__ __forceinline__ i32x4 ntld4i(const int* p)   { return __builtin_nontemporal_load((const i32x4*)p); }
__device__ __forceinline__ f32x4 ntld4f(const float* p) { return __builtin_nontemporal_load((const f32x4*)p); }

__device__ __forceinline__ float sigmoidf_(float x) {
    if (x >= 0.0f) { float e = expf(-x); return 1.0f / (1.0f + e); }
    float e = expf(x); return e / (1.0f + e);
}
__device__ __forceinline__ float softplusf_(float x) {
    return fmaxf(x, 0.0f) + log1pf(expf(-fabsf(x)));
}
__device__ __forceinline__ unsigned key_desc(float f) {
    unsigned u = __float_as_uint(f);
    unsigned ka = (u & 0x80000000u) ? ~u : (u | 0x80000000u);  // ascending map
    return ~ka;                                                 // descending
}
__device__ __forceinline__ float edge_m(float xd, float xs, float a,
                                        float wf0, float wf1, float wf2, float b0,
                                        float ws0, float ws1, float ws2, float b1) {
    float f = xd * wf0 + xs * wf1 + a * wf2 + b0;
    float g = xd * ws0 + xs * ws1 + a * ws2 + b1;
    return sigmoidf_(f) * softplusf_(g);
}

// ---------------- score constants c = sum(w)/norm(w) ----------------
__global__ void k_consts(const float* __restrict__ pw1, const float* __restrict__ pw2,
                         const float* __restrict__ pw3, float* __restrict__ consts,
                         int n1, int n2, int n3) {
    const float* w; int n;
    if (blockIdx.x == 0)      { w = pw1; n = n1; }
    else if (blockIdx.x == 1) { w = pw2; n = n2; }
    else                      { w = pw3; n = n3; }
    __shared__ float s1[256], s2[256];
    float a = 0.f, b = 0.f;
    for (int i = threadIdx.x; i < n; i += 256) { float v = w[i]; a += v; b += v * v; }
    s1[threadIdx.x] = a; s2[threadIdx.x] = b; __syncthreads();
    for (int o = 128; o > 0; o >>= 1) {
        if (threadIdx.x < o) { s1[threadIdx.x] += s1[threadIdx.x + o]; s2[threadIdx.x] += s2[threadIdx.x + o]; }
        __syncthreads();
    }
    if (threadIdx.x == 0) consts[blockIdx.x] = s1[0] / sqrtf(s2[0]);
}

// ============== conv1: atomic-free two-level partition ==============
// Phase A: per-chunk histogram of dst>>BSH (vec4 nt streaming)
__global__ void __launch_bounds__(256) k_ehist2(const int* __restrict__ dst,
                                                unsigned* __restrict__ hist,
                                                int e0, int e1) {
    __shared__ unsigned h[NB2];
    int t = threadIdx.x;
    h[t] = 0;
    __syncthreads();
    int cs = e0 + blockIdx.x * EPB;
    int ce = cs + EPB; if (ce > e1) ce = e1;
    for (int eb = cs; eb < ce; eb += RND) {
        int i = eb + t * 4;
        if (eb + RND <= ce) {
            i32x4 d4 = ntld4i(dst + i);
            atomicAdd(&h[((unsigned)d4.x) >> BSH], 1u);
            atomicAdd(&h[((unsigned)d4.y) >> BSH], 1u);
            atomicAdd(&h[((unsigned)d4.z) >> BSH], 1u);
            atomicAdd(&h[((unsigned)d4.w) >> BSH], 1u);
        } else {
            #pragma unroll
            for (int j = 0; j < 4; ++j)
                if (i + j < ce) atomicAdd(&h[((unsigned)dst[i + j]) >> BSH], 1u);
        }
    }
    __syncthreads();
    hist[(size_t)blockIdx.x * NB2 + t] = h[t];
}

// generic scanA: one block per digit d; within-digit exclusive prefix over blocks
__global__ void k_scanA(const unsigned* __restrict__ hist, unsigned* __restrict__ offs,
                        unsigned* __restrict__ tot, int G) {
    int d = blockIdx.x, ND = gridDim.x, t = threadIdx.x;
    __shared__ unsigned s[256];
    unsigned carry = 0;
    for (int tile = 0; tile * 256 < G; ++tile) {
        int g = tile * 256 + t;
        unsigned v = (g < G) ? hist[(size_t)g * ND + d] : 0u;
        s[t] = v; __syncthreads();
        for (int o = 1; o < 256; o <<= 1) {
            unsigned u = (t >= o) ? s[t - o] : 0u;
            __syncthreads();
            s[t] += u; __syncthreads();
        }
        if (g < G) offs[(size_t)g * ND + d] = s[t] - v + carry;
        unsigned tl = s[255]; __syncthreads();
        carry += tl;
    }
    if (t == 0) tot[d] = carry;
}

// generic scanB: exclusive scan of tot[ND] -> base[ND]; totals rounded up by rmask
__global__ void k_scanB(const unsigned* __restrict__ tot, unsigned* __restrict__ base,
                        int ND, unsigned rmask) {
    __shared__ unsigned s[256];
    int t = threadIdx.x;
    unsigned carry = 0;
    for (int tile = 0; tile * 256 < ND; ++tile) {
        int d = tile * 256 + t;
        unsigned v = (d < ND) ? ((tot[d] + rmask) & ~rmask) : 0u;
        s[t] = v; __syncthreads();
        for (int o = 1; o < 256; o <<= 1) {
            unsigned u = (t >= o) ? s[t - o] : 0u;
            __syncthreads();
            s[t] += u; __syncthreads();
        }
        if (d < ND) base[d] = s[t] - v + carry;
        unsigned tl = s[255]; __syncthreads();
        carry += tl;
    }
    if (t == 0) base[ND] = carry;
}

// Phase C: compute m, stage 8B records per bin in LDS, flush 128B groups
__global__ void __launch_bounds__(256) k_part(
        const float* __restrict__ x, const float* __restrict__ ea,
        const int* __restrict__ src, const int* __restrict__ dst,
        const float* __restrict__ Wf, const float* __restrict__ bf,
        const float* __restrict__ Ws, const float* __restrict__ bs,
        const unsigned* __restrict__ offs, const unsigned* __restrict__ binBase,
        uint2* __restrict__ rec, int e0, int e1) {
    __shared__ unsigned stage[NB2 * CAPW];
    __shared__ unsigned gcur[NB2], fil[NB2];
    int t = threadIdx.x;
    gcur[t] = binBase[t] + offs[(size_t)blockIdx.x * NB2 + t];
    fil[t] = 0;
    __syncthreads();
    int cs = e0 + blockIdx.x * EPB;
    int ce = cs + EPB; if (ce > e1) ce = e1;
    float wf0 = Wf[0], wf1 = Wf[1], wf2 = Wf[2], b0 = bf[0];
    float ws0 = Ws[0], ws1 = Ws[1], ws2 = Ws[2], b1 = bs[0];
    for (int rb = cs; rb < ce; rb += RND) {
        int s4[4], d4[4]; float a4[4]; bool vl[4];
        int eb = rb + t * 4;
        if (rb + RND <= ce) {
            i32x4 sv = ntld4i(src + eb);
            i32x4 dv = ntld4i(dst + eb);
            f32x4 av = ntld4f(ea + eb);
            s4[0]=sv.x; s4[1]=sv.y; s4[2]=sv.z; s4[3]=sv.w;
            d4[0]=dv.x; d4[1]=dv.y; d4[2]=dv.z; d4[3]=dv.w;
            a4[0]=av.x; a4[1]=av.y; a4[2]=av.z; a4[3]=av.w;
            vl[0]=vl[1]=vl[2]=vl[3]=true;
        } else {
            #pragma unroll
            for (int j = 0; j < 4; ++j) {
                int e = eb + j;
                vl[j] = e < ce;
                s4[j] = vl[j] ? src[e] : 0;
                d4[j] = vl[j] ? dst[e] : 0;
                a4[j] = vl[j] ? ea[e]  : 0.f;
            }
        }
        #pragma unroll
        for (int j = 0; j < 4; ++j) {
            if (!vl[j]) continue;
            int d = d4[j];
            float m = edge_m(x[d], x[s4[j]], a4[j], wf0, wf1, wf2, b0, ws0, ws1, ws2, b1);
            unsigned bin = ((unsigned)d) >> BSH;
            unsigned dl  = (unsigned)(d & ((1 << BSH) - 1));
            unsigned slot = atomicAdd(&fil[bin], 1u);
            if (slot < CAP) {
                stage[bin * CAPW + 2 * slot]     = __float_as_uint(m);
                stage[bin * CAPW + 2 * slot + 1] = dl;
            } else {
                rec[gcur[bin] + slot] = make_uint2(__float_as_uint(m), dl);  // rare
            }
        }
        __syncthreads();
        {   // flush phase: thread t owns bin t
            unsigned c = fil[t], g = gcur[t];
            unsigned* st = &stage[t * CAPW];
            if (c > CAP) {           // rare drain-all (overflow already in place)
                for (unsigned k = 0; k < CAP; ++k)
                    rec[g + k] = make_uint2(st[2 * k], st[2 * k + 1]);
                gcur[t] = g + c; fil[t] = 0;
            } else {
                unsigned ngrp = c >> 4;
                if (ngrp) {
                    unsigned nfl = ngrp << 4;
                    for (unsigned k = 0; k < nfl; ++k)
                        rec[g + k] = make_uint2(st[2 * k], st[2 * k + 1]);
                    unsigned rem = c - nfl;
                    for (unsigned k = 0; k < rem; ++k) {
                        st[2 * k]     = st[2 * (nfl + k)];
                        st[2 * k + 1] = st[2 * (nfl + k) + 1];
                    }
                    gcur[t] = g + nfl; fil[t] = rem;
                }
            }
        }
        __syncthreads();
    }
    // tail drain
    {
        unsigned c = fil[t], g = gcur[t];
        unsigned* st = &stage[t * CAPW];
        unsigned cc = c < CAP ? c : CAP;
        for (unsigned k = 0; k < cc; ++k)
            rec[g + k] = make_uint2(st[2 * k], st[2 * k + 1]);
    }
}

// Phase D: per-bin LDS aggregation -> aggr, optional fused sum/sumsq stats
__global__ void __launch_bounds__(256) k_aggr2(
        const uint2* __restrict__ rec, const unsigned* __restrict__ base,
        const unsigned* __restrict__ tot, float* __restrict__ aggr,
        float* __restrict__ stats, int N, int accumulate, int doStats) {
    __shared__ float acc[1 << BSH];
    int t = threadIdx.x, b = blockIdx.x;
    for (int i = t; i < (1 << BSH); i += 256) acc[i] = 0.f;
    __syncthreads();
    unsigned lo = base[b], hi = lo + tot[b];
    for (unsigned i = lo + t; i < hi; i += 256) {
        u32x2 r = __builtin_nontemporal_load((const u32x2*)&rec[i]);
        atomicAdd(&acc[r.y], __uint_as_float(r.x));
    }
    __syncthreads();
    int nb = b << BSH;
    float s = 0.f, q = 0.f;
    for (int i = t; i < (1 << BSH); i += 256) {
        int node = nb + i;
        if (node < N) {
            float v = acc[i];
            if (accumulate) v += aggr[node];
            aggr[node] = v;
            if (doStats) { s += v; q += v * v; }
        }
    }
    if (doStats) {
        __shared__ float s1[256], s2[256];
        s1[t] = s; s2[t] = q; __syncthreads();
        for (int o = 128; o > 0; o >>= 1) {
            if (t < o) { s1[t] += s1[t + o]; s2[t] += s2[t + o]; }
            __syncthreads();
        }
        if (t == 0) { atomicAdd(&stats[0], s1[0]); atomicAdd(&stats[1], s2[0]); }
    }
}

// ---------------- conv1 atomic fallback (ws too small) ----------------
__global__ void k_conv1(const float* __restrict__ x, const float* __restrict__ ea,
                        const int* __restrict__ src, const int* __restrict__ dst,
                        const float* __restrict__ Wf, const float* __restrict__ bf,
                        const float* __restrict__ Ws, const float* __restrict__ bs,
                        float* __restrict__ aggr, int E) {
    int e = blockIdx.x * blockDim.x + threadIdx.x;
    if (e >= E) return;
    int s = src[e], d = dst[e];
    atomicAdd(&aggr[d], edge_m(x[d], x[s], ea[e], Wf[0], Wf[1], Wf[2], bf[0],
                               Ws[0], Ws[1], Ws[2], bs[0]));
}

// ---------------- conv2: filtered edges (vec4 nt, dst-first), sparse atomics ----------------
__global__ void __launch_bounds__(256) k_conv2(
        const float* __restrict__ x2, const float* __restrict__ ea,
        const int* __restrict__ src, const int* __restrict__ dst,
        const int* __restrict__ nidx,
        const float* __restrict__ Wf, const float* __restrict__ bf,
        const float* __restrict__ Ws, const float* __restrict__ bs,
        float* __restrict__ aggr, int E) {
    int base = (blockIdx.x * 256 + threadIdx.x) * 4;
    if (base >= E) return;
    float wf0 = Wf[0], wf1 = Wf[1], wf2 = Wf[2], b0 = bf[0];
    float ws0 = Ws[0], ws1 = Ws[1], ws2 = Ws[2], b1 = bs[0];
    int d4[4]; int cnt;
    if (base + 4 <= E) {
        i32x4 dv = ntld4i(dst + base);
        d4[0]=dv.x; d4[1]=dv.y; d4[2]=dv.z; d4[3]=dv.w;
        cnt = 4;
    } else {
        cnt = E - base;
        for (int j = 0; j < cnt; ++j) d4[j] = dst[base + j];
    }
    #pragma unroll
    for (int j = 0; j < 4; ++j) {
        if (j >= cnt) break;
        int nd = nidx[d4[j]];
        if (nd < 0) continue;
        int sv = __builtin_nontemporal_load(src + base + j);
        int ns = nidx[sv];
        if (ns < 0) continue;
        float a = __builtin_nontemporal_load(ea + base + j);
        atomicAdd(&aggr[nd], edge_m(x2[nd], x2[ns], a, wf0, wf1, wf2, b0, ws0, ws1, ws2, b1));
    }
}

// ---------------- sum / sumsq reduction ----------------
__global__ void k_stats(const float* __restrict__ a, int n, float* __restrict__ stats) {
    float s = 0.f, q = 0.f;
    int stride = gridDim.x * blockDim.x;
    for (int i = blockIdx.x * blockDim.x + threadIdx.x; i < n; i += stride) {
        float v = a[i]; s += v; q += v * v;
    }
    __shared__ float s1[256], s2[256];
    s1[threadIdx.x] = s; s2[threadIdx.x] = q; __syncthreads();
    for (int o = 128; o > 0; o >>= 1) {
        if (threadIdx.x < o) { s1[threadIdx.x] += s1[threadIdx.x + o]; s2[threadIdx.x] += s2[threadIdx.x + o]; }
        __syncthreads();
    }
    if (threadIdx.x == 0) { atomicAdd(&stats[0], s1[0]); atomicAdd(&stats[1], s2[0]); }
}

// ---------------- batchnorm + residual (+ fused sort-key emit) ----------------
__global__ void k_bn(const float* __restrict__ aggr, const float* __restrict__ xin,
                     const float* __restrict__ stats, const float* __restrict__ g,
                     const float* __restrict__ be, float* __restrict__ xout,
                     int n, float invn, const float* __restrict__ consts, int ci,
                     unsigned* __restrict__ keys, unsigned* __restrict__ vals) {
    int i = blockIdx.x * blockDim.x + threadIdx.x;
    if (i >= n) return;
    float mean = stats[0] * invn;
    float var  = stats[1] * invn - mean * mean;
    float inv  = 1.0f / sqrtf(var + 1e-5f);
    float v = g[0] * (aggr[i] - mean) * inv + be[0] + xin[i];
    xout[i] = v;
    if (keys) {
        float s = tanhf(v * consts[ci]);
        keys[i] = key_desc(s);
        vals[i] = (unsigned)i;
    }
}

// ---------------- radix sort: per-chunk histogram (vec4) ----------------
__global__ void k_hist(const unsigned* __restrict__ keys, unsigned* __restrict__ hist,
                       int n, int shift) {
    __shared__ unsigned h[256];
    int t = threadIdx.x;
    h[t] = 0;
    __syncthreads();
    int base = blockIdx.x * CHUNK;
    if (base + CHUNK <= n) {
        #pragma unroll
        for (int it = 0; it < CHUNK / 1024; ++it) {
            int i = base + it * 1024 + t * 4;
            const unsigned* p = keys + i;
            unsigned k0 = p[0], k1 = p[1], k2 = p[2], k3 = p[3];
            atomicAdd(&h[(k0 >> shift) & 255u], 1u);
            atomicAdd(&h[(k1 >> shift) & 255u], 1u);
            atomicAdd(&h[(k2 >> shift) & 255u], 1u);
            atomicAdd(&h[(k3 >> shift) & 255u], 1u);
        }
    } else {
        int end = n;
        for (int i = base + t; i < end; i += 256)
            atomicAdd(&h[(keys[i] >> shift) & 255u], 1u);
    }
    __syncthreads();
    hist[blockIdx.x * 256 + t] = h[t];
}

// ---------------- radix sort: stable scatter (4 waves / block) ----------------
__global__ void __launch_bounds__(256) k_scatter(const unsigned* __restrict__ keys,
                                                 const unsigned* __restrict__ vals,
                                                 unsigned* __restrict__ okeys,
                                                 unsigned* __restrict__ ovals,
                                                 const unsigned* __restrict__ offs,
                                                 const unsigned* __restrict__ base_,
                                                 int n, int shift) {
    __shared__ unsigned run[256];
    __shared__ unsigned offl[256];
    __shared__ unsigned wcnt[4][256];
    __shared__ unsigned wpre[4][256];
    int t = threadIdx.x;
    int wave = t >> 6, lane = t & 63;
    run[t] = 0;
    offl[t] = offs[(size_t)blockIdx.x * 256 + t] + base_[t];
    __syncthreads();
    int cbase = blockIdx.x * CHUNK;
    const int GROUPS = CHUNK / 256;
    for (int gix = 0; gix < GROUPS; ++gix) {
        int i = cbase + gix * 256 + t;
        bool active = i < n;
        unsigned k = active ? keys[i] : 0u;
        unsigned v = active ? vals[i] : 0u;
        unsigned d = (k >> shift) & 255u;
        unsigned long long amask = __ballot(active);
        unsigned long long bb[8];
        #pragma unroll
        for (int bit = 0; bit < 8; ++bit) bb[bit] = __ballot(active && ((d >> bit) & 1u));
        unsigned long long m = amask;
        #pragma unroll
        for (int bit = 0; bit < 8; ++bit) m &= ((d >> bit) & 1u) ? bb[bit] : ~bb[bit];
        unsigned rk = (unsigned)__popcll(m & ((1ull << lane) - 1ull));
        #pragma unroll
        for (int j = 0; j < 4; ++j) {
            unsigned dd = (unsigned)lane + j * 64u;
            unsigned long long mm = amask;
            #pragma unroll
            for (int bit = 0; bit < 8; ++bit) mm &= ((dd >> bit) & 1u) ? bb[bit] : ~bb[bit];
            wcnt[wave][dd] = (unsigned)__popcll(mm);
        }
        __syncthreads();
        {
            unsigned r = run[t];
            unsigned c0 = wcnt[0][t], c1 = wcnt[1][t], c2 = wcnt[2][t], c3 = wcnt[3][t];
            wpre[0][t] = r;
            wpre[1][t] = r + c0;
            wpre[2][t] = r + c0 + c1;
            wpre[3][t] = r + c0 + c1 + c2;
            run[t] = r + c0 + c1 + c2 + c3;
        }
        __syncthreads();
        if (active) {
            unsigned pos = offl[d] + wpre[wave][d] + rk;
            okeys[pos] = k;
            ovals[pos] = v;
        }
    }
}

// ---------------- pool gather (+ optional new_idx, + optional next-sort keys) ----------------
__global__ void k_pool(const unsigned* __restrict__ perm, const float* __restrict__ xin,
                       const float* __restrict__ consts, int ci,
                       float* __restrict__ xout, int* __restrict__ newidx, int k,
                       unsigned* __restrict__ okeys, unsigned* __restrict__ ovals, int nci) {
    int r = blockIdx.x * blockDim.x + threadIdx.x;
    if (r >= k) return;
    unsigned p = perm[r];
    float xv = xin[p];
    float s = tanhf(xv * consts[ci]);
    float o = xv * s;
    xout[r] = o;
    if (newidx) newidx[p] = r;
    if (okeys) {
        float s2 = tanhf(o * consts[nci]);
        okeys[r] = key_desc(s2);
        ovals[r] = (unsigned)r;
    }
}

// ---------------- single-block: 4-pass radix sort + pool3 + MLP + log_softmax ----------------
__global__ void __launch_bounds__(1024) k_smallsort(
        unsigned* __restrict__ kIn, unsigned* __restrict__ vIn,
        unsigned* __restrict__ kTmp, unsigned* __restrict__ vTmp,
        int n, int k3, const float* __restrict__ xin,
        const float* __restrict__ consts, int ci,
        const float* __restrict__ Wl1, const float* __restrict__ bl1,
        const float* __restrict__ Wl2, const float* __restrict__ bl2,
        float* __restrict__ out) {
    __shared__ unsigned hist[256], sc[256], run[256], offl[256];
    __shared__ unsigned wcnt[16][256];
    __shared__ unsigned wpre[16][256];
    int t = threadIdx.x;
    int wave = t >> 6, lane = t & 63;
    unsigned *ki = kIn, *vi = vIn, *ko = kTmp, *vo = vTmp;
    for (int p = 0; p < 4; ++p) {
        int shift = p * 8;
        if (t < 256) hist[t] = 0;
        __syncthreads();
        for (int i = t; i < n; i += 1024)
            atomicAdd(&hist[(ki[i] >> shift) & 255u], 1u);
        __syncthreads();
        if (t < 256) sc[t] = hist[t];
        __syncthreads();
        for (int o = 1; o < 256; o <<= 1) {
            unsigned u = 0;
            if (t < 256 && t >= o) u = sc[t - o];
            __syncthreads();
            if (t < 256) sc[t] += u;
            __syncthreads();
        }
        if (t < 256) { offl[t] = sc[t] - hist[t]; run[t] = 0; }
        __syncthreads();
        int G = (n + 1023) / 1024;
        for (int gix = 0; gix < G; ++gix) {
            int i = gix * 1024 + t;
            bool active = i < n;
            unsigned k = active ? ki[i] : 0u;
            unsigned v = active ? vi[i] : 0u;
            unsigned d = (k >> shift) & 255u;
            unsigned long long amask = __ballot(active);
            unsigned long long bb[8];
            #pragma unroll
            for (int bit = 0; bit < 8; ++bit) bb[bit] = __ballot(active && ((d >> bit) & 1u));
            unsigned long long m = amask;
            #pragma unroll
            for (int bit = 0; bit < 8; ++bit) m &= ((d >> bit) & 1u) ? bb[bit] : ~bb[bit];
            unsigned rk = (unsigned)__popcll(m & ((1ull << lane) - 1ull));
            #pragma unroll
            for (int j = 0; j < 4; ++j) {
                unsigned dd = (unsigned)lane + j * 64u;
                unsigned long long mm = amask;
                #pragma unroll
                for (int bit = 0; bit < 8; ++bit) mm &= ((dd >> bit) & 1u) ? bb[bit] : ~bb[bit];
                wcnt[wave][dd] = (unsigned)__popcll(mm);
            }
            __syncthreads();
            if (t < 256) {
                unsigned acc = run[t];
                #pragma unroll
                for (int w2 = 0; w2 < 16; ++w2) { wpre[w2][t] = acc; acc += wcnt[w2][t]; }
                run[t] = acc;
            }
            __syncthreads();
            if (active) {
                unsigned pos = offl[d] + wpre[wave][d] + rk;
                ko[pos] = k;
                vo[pos] = v;
            }
            __syncthreads();
        }
        unsigned* tp;
        tp = ki; ki = ko; ko = tp;
        tp = vi; vi = vo; vo = tp;
        __syncthreads();
    }
    // 4 passes (even) -> sorted result in kIn/vIn. pool3 + MLP + log_softmax.
    float c = consts[ci];
    float b20 = bl2[0], b21 = bl2[1];
    for (int r = t; r < k3; r += 1024) {
        unsigned pidx = vIn[r];
        float xv = xin[pidx];
        float s = tanhf(xv * c);
        float o = xv * s;
        float l0 = b20, l1 = b21;
        #pragma unroll
        for (int j = 0; j < 8; ++j) {
            float h = fmaxf(o * Wl1[j] + bl1[j], 0.0f);
            l0 += h * Wl2[2 * j];
            l1 += h * Wl2[2 * j + 1];
        }
        float mx = fmaxf(l0, l1);
        float lse = mx + logf(expf(l0 - mx) + expf(l1 - mx));
        out[2 * r]     = l0 - lse;
        out[2 * r + 1] = l1 - lse;
    }
}

// ---------------- host-side radix sort driver ----------------
static void sort_pairs(hipStream_t stream, unsigned* kA, unsigned* vA,
                       unsigned* kB, unsigned* vB, unsigned* hist, unsigned* offs,
                       unsigned* tot, unsigned* base, int n) {
    int G = (n + CHUNK - 1) / CHUNK;
    unsigned *ki = kA, *vi = vA, *ko = kB, *vo = vB;
    for (int p = 0; p < 4; ++p) {
        int shift = p * 8;
        k_hist<<<G, 256, 0, stream>>>(ki, hist, n, shift);
        k_scanA<<<256, 256, 0, stream>>>(hist, offs, tot, G);
        k_scanB<<<1, 256, 0, stream>>>(tot, base, 256, 0u);
        k_scatter<<<G, 256, 0, stream>>>(ki, vi, ko, vo, offs, base, n, shift);
        unsigned* t;
        t = ki; ki = ko; ko = t;
        t = vi; vi = vo; vo = t;
    }
}

extern "C" void kernel_launch(void* const* d_in, const int* in_sizes, int n_in,
                              void* d_out, int out_size, void* d_ws, size_t ws_size,
                              hipStream_t stream) {
    const float* x   = (const float*)d_in[0];
    const float* ea  = (const float*)d_in[1];
    const int*   src = (const int*)d_in[2];
    const int*   dst = (const int*)d_in[3];
    const float *Wf1 = (const float*)d_in[5],  *bf1 = (const float*)d_in[6];
    const float *Ws1 = (const float*)d_in[7],  *bs1 = (const float*)d_in[8];
    const float *g1  = (const float*)d_in[9],  *be1 = (const float*)d_in[10];
    const float *Wf2 = (const float*)d_in[11], *bf2 = (const float*)d_in[12];
    const float *Ws2 = (const float*)d_in[13], *bs2 = (const float*)d_in[14];
    const float *g2  = (const float*)d_in[15], *be2 = (const float*)d_in[16];
    const float *pw1 = (const float*)d_in[17], *pw2 = (const float*)d_in[18], *pw3 = (const float*)d_in[19];
    const float *Wl1 = (const float*)d_in[20], *bl1 = (const float*)d_in[21];
    const float *Wl2 = (const float*)d_in[22], *bl2 = (const float*)d_in[23];

    const int N  = in_sizes[0];
    const int E  = in_sizes[1];
    const int K1 = 100000, K2 = 10000, K3 = 2500;

    // ---- workspace layout ----
    size_t off = 0;
    auto alloc = [&](size_t bytes) { size_t o = off; off = (off + bytes + 255) & ~(size_t)255; return o; };
    char* ws = (char*)d_ws;
    size_t o_x1    = alloc((size_t)N * 4);
    size_t o_nidx  = alloc((size_t)N * 4);
    size_t o_stats = alloc(256);
    size_t o_const = alloc(256);
    size_t o_tot   = alloc(4096);
    size_t o_base  = alloc(8192);
    size_t o_x2    = alloc((size_t)K1 * 4);
    size_t o_x3    = alloc((size_t)K1 * 4);
    size_t o_ag2   = alloc((size_t)K1 * 4);
    size_t o_x4    = alloc((size_t)K2 * 4);
    size_t o_x5    = alloc((size_t)K3 * 4);
    size_t o_ag1   = alloc((size_t)N * 4);
    size_t o_arena = off;

    // sort scratch (overlay B, live from k_bn onward)
    int G1 = (N + CHUNK - 1) / CHUNK;
    size_t s_kA = 0;
    size_t s_vA = s_kA + (((size_t)N * 4 + 255) & ~(size_t)255);
    size_t s_kB = s_vA + (((size_t)N * 4 + 255) & ~(size_t)255);
    size_t s_vB = s_kB + (((size_t)N * 4 + 255) & ~(size_t)255);
    size_t s_h  = s_vB + (((size_t)N * 4 + 255) & ~(size_t)255);
    size_t s_o  = s_h  + (((size_t)G1 * 256 * 4 + 255) & ~(size_t)255);
    size_t sortSz = s_o + (size_t)G1 * 256 * 4;

    // conv1 partition scratch (overlay A, dead after k_aggr2): pick split H
    int H = 0, Eh = 0;
    size_t p_rec = 0, p_eh = 0, p_eo = 0;
    for (int h = 1; h <= 8; h <<= 1) {
        int eh_ = (E + h - 1) / h;
        eh_ = (eh_ + RND - 1) & ~(RND - 1);
        int gc_ = (eh_ + EPB - 1) / EPB;
        size_t recB = (((size_t)(eh_ + NB2 * FG) * 8) + 255) & ~(size_t)255;
        size_t ehB  = (((size_t)gc_ * NB2 * 4) + 255) & ~(size_t)255;
        size_t eoB  = (((size_t)gc_ * NB2 * 4) + 255) & ~(size_t)255;
        size_t partSz = recB + ehB + eoB;
        size_t arenaSz = partSz > sortSz ? partSz : sortSz;
        if (o_arena + arenaSz <= ws_size && N <= (NB2 << BSH)) {
            H = h; Eh = eh_;
            p_rec = 0; p_eh = p_rec + recB; p_eo = p_eh + ehB;
            break;
        }
    }

    float*    x1     = (float*)(ws + o_x1);
    int*      nidx   = (int*)(ws + o_nidx);
    float*    stats  = (float*)(ws + o_stats);
    float*    consts = (float*)(ws + o_const);
    unsigned* tot    = (unsigned*)(ws + o_tot);
    unsigned* base   = (unsigned*)(ws + o_base);
    float*    x2     = (float*)(ws + o_x2);
    float*    x3     = (float*)(ws + o_x3);
    float*    aggr2  = (float*)(ws + o_ag2);
    float*    x4     = (float*)(ws + o_x4);
    float*    aggr1  = (float*)(ws + o_ag1);
    unsigned* kA     = (unsigned*)(ws + o_arena + s_kA);
    unsigned* vA     = (unsigned*)(ws + o_arena + s_vA);
    unsigned* kB     = (unsigned*)(ws + o_arena + s_kB);
    unsigned* vB     = (unsigned*)(ws + o_arena + s_vB);
    unsigned* hist   = (unsigned*)(ws + o_arena + s_h);
    unsigned* offs   = (unsigned*)(ws + o_arena + s_o);

    // init (harness does not re-poison between replays)
    hipMemsetAsync(nidx, 0xFF, (size_t)N * 4, stream);   // -1
    hipMemsetAsync(stats, 0, 64, stream);
    hipMemsetAsync(aggr2, 0, (size_t)K1 * 4, stream);

    k_consts<<<3, 256, 0, stream>>>(pw1, pw2, pw3, consts,
                                    in_sizes[17], in_sizes[18], in_sizes[19]);

    // ---- cgconv 1 (atomic-free partition path) ----
    if (H > 0) {
        uint2*    rec = (uint2*)(ws + o_arena + p_rec);
        unsigned* eh  = (unsigned*)(ws + o_arena + p_eh);
        unsigned* eo  = (unsigned*)(ws + o_arena + p_eo);
        int NBN = (N + (1 << BSH) - 1) >> BSH;
        for (int h = 0; h < H; ++h) {
            int e0 = h * Eh;
            int e1 = e0 + Eh; if (e1 > E) e1 = E;
            if (e0 >= e1) break;
            int GCh = (e1 - e0 + EPB - 1) / EPB;
            k_ehist2<<<GCh, 256, 0, stream>>>(dst, eh, e0, e1);
            k_scanA<<<NB2, 256, 0, stream>>>(eh, eo, tot, GCh);
            k_scanB<<<1, 256, 0, stream>>>(tot, base, NB2, (unsigned)(FG - 1));
            k_part<<<GCh, 256, 0, stream>>>(x, ea, src, dst, Wf1, bf1, Ws1, bs1,
                                            eo, base, rec, e0, e1);
            k_aggr2<<<NBN, 256, 0, stream>>>(rec, base, tot, aggr1, stats, N,
                                             h > 0, h == H - 1 ? 1 : 0);
        }
    } else {
        hipMemsetAsync(aggr1, 0, (size_t)N * 4, stream);
        k_conv1<<<(E + 255) / 256, 256, 0, stream>>>(x, ea, src, dst, Wf1, bf1, Ws1, bs1, aggr1, E);
        k_stats<<<1024, 256, 0, stream>>>(aggr1, N, stats);
    }
    k_bn<<<(N + 255) / 256, 256, 0, stream>>>(aggr1, x, stats, g1, be1, x1, N, 1.0f / (float)N,
                                              consts, 0, kA, vA);

    // ---- pool 1 : top 100K of 1M ----
    sort_pairs(stream, kA, vA, kB, vB, hist, offs, tot, base, N);
    k_pool<<<(K1 + 255) / 256, 256, 0, stream>>>(vA, x1, consts, 0, x2, nidx, K1,
                                                 (unsigned*)nullptr, (unsigned*)nullptr, 0);

    // ---- cgconv 2 (filtered edges; sparse atomics) ----
    k_conv2<<<(E / 4 + 255) / 256, 256, 0, stream>>>(x2, ea, src, dst, nidx,
                                                     Wf2, bf2, Ws2, bs2, aggr2, E);
    k_stats<<<256, 256, 0, stream>>>(aggr2, K1, stats + 2);
    k_bn<<<(K1 + 255) / 256, 256, 0, stream>>>(aggr2, x2, stats + 2, g2, be2, x3, K1, 1.0f / (float)K1,
                                               consts, 1, kA, vA);

    // ---- pool 2 : top 10K of 100K (emits keys for pool-3 sort into kB/vB) ----
    sort_pairs(stream, kA, vA, kB, vB, hist, offs, tot, base, K1);
    k_pool<<<(K2 + 255) / 256, 256, 0, stream>>>(vA, x3, consts, 1, x4, (int*)nullptr, K2,
                                                 kB, vB, 2);

    // ---- pool 3 + sort + MLP + log_softmax : one single-block kernel ----
    k_smallsort<<<1, 1024, 0, stream>>>(kB, vB, kA, vA, K2, K3, x4, consts, 2,
                                        Wl1, bl1, Wl2, bl2, (float*)d_out);
}

// Round 7
// 882.720 us; speedup vs baseline: 2.3667x; 1.0222x over previous
//
#include <hip/hip_runtime.h>
#include <math.h>

#define CHUNK 4096               // elements per radix-sort block
#define NB2   256                // conv1 partition bins
#define BSH   12                 // bin = dst >> BSH ; 4096 nodes per bin
#define CAP   24                 // LDS stage capacity per bin (records)
#define CAPW  49                 // LDS words per bin (odd -> conflict-free)
#define FG    16                 // flush group: 16 records = 128 B
#define RND   1024               // edges per staging round (256 thr * 4)
#define EPB   16384              // edges per k_part block

typedef int      i32x4 __attribute__((ext_vector_type(4)));
typedef float    f32x4 __attribute__((ext_vector_type(4)));
typedef unsigned u32x2 __attribute__((ext_vector_type(2)));

__device__ __forceinline__ i32x4 ntld4i(const int* p)   { return __builtin_nontemporal_load((const i32x4*)p); }
__device__ __forceinline__ f32x4 ntld4f(const float* p) { return __builtin_nontemporal_load((const f32x4*)p); }

__device__ __forceinline__ float sigmoidf_(float x) {
    if (x >= 0.0f) { float e = expf(-x); return 1.0f / (1.0f + e); }
    float e = expf(x); return e / (1.0f + e);
}
__device__ __forceinline__ float softplusf_(float x) {
    return fmaxf(x, 0.0f) + log1pf(expf(-fabsf(x)));
}
__device__ __forceinline__ unsigned key_desc(float f) {
    unsigned u = __float_as_uint(f);
    unsigned ka = (u & 0x80000000u) ? ~u : (u | 0x80000000u);  // ascending map
    return ~ka;                                                 // descending
}
__device__ __forceinline__ float edge_m(float xd, float xs, float a,
                                        float wf0, float wf1, float wf2, float b0,
                                        float ws0, float ws1, float ws2, float b1) {
    float f = xd * wf0 + xs * wf1 + a * wf2 + b0;
    float g = xd * ws0 + xs * ws1 + a * ws2 + b1;
    return sigmoidf_(f) * softplusf_(g);
}

// ---------------- score constants + stats zeroing ----------------
__global__ void k_consts(const float* __restrict__ pw1, const float* __restrict__ pw2,
                         const float* __restrict__ pw3, float* __restrict__ consts,
                         float* __restrict__ stats, int n1, int n2, int n3) {
    if (blockIdx.x == 0 && threadIdx.x < 16) stats[threadIdx.x] = 0.f;
    const float* w; int n;
    if (blockIdx.x == 0)      { w = pw1; n = n1; }
    else if (blockIdx.x == 1) { w = pw2; n = n2; }
    else                      { w = pw3; n = n3; }
    __shared__ float s1[256], s2[256];
    float a = 0.f, b = 0.f;
    for (int i = threadIdx.x; i < n; i += 256) { float v = w[i]; a += v; b += v * v; }
    s1[threadIdx.x] = a; s2[threadIdx.x] = b; __syncthreads();
    for (int o = 128; o > 0; o >>= 1) {
        if (threadIdx.x < o) { s1[threadIdx.x] += s1[threadIdx.x + o]; s2[threadIdx.x] += s2[threadIdx.x + o]; }
        __syncthreads();
    }
    if (threadIdx.x == 0) consts[blockIdx.x] = s1[0] / sqrtf(s2[0]);
}

// ============== conv1: atomic-free two-level partition ==============
// Phase A: per-chunk histogram of dst>>BSH (vec4 nt streaming)
__global__ void __launch_bounds__(256) k_ehist2(const int* __restrict__ dst,
                                                unsigned* __restrict__ hist,
                                                int e0, int e1) {
    __shared__ unsigned h[NB2];
    int t = threadIdx.x;
    h[t] = 0;
    __syncthreads();
    int cs = e0 + blockIdx.x * EPB;
    int ce = cs + EPB; if (ce > e1) ce = e1;
    for (int eb = cs; eb < ce; eb += RND) {
        int i = eb + t * 4;
        if (eb + RND <= ce) {
            i32x4 d4 = ntld4i(dst + i);
            atomicAdd(&h[((unsigned)d4.x) >> BSH], 1u);
            atomicAdd(&h[((unsigned)d4.y) >> BSH], 1u);
            atomicAdd(&h[((unsigned)d4.z) >> BSH], 1u);
            atomicAdd(&h[((unsigned)d4.w) >> BSH], 1u);
        } else {
            #pragma unroll
            for (int j = 0; j < 4; ++j)
                if (i + j < ce) atomicAdd(&h[((unsigned)dst[i + j]) >> BSH], 1u);
        }
    }
    __syncthreads();
    hist[(size_t)blockIdx.x * NB2 + t] = h[t];
}

// scanA: one block per digit d; within-digit exclusive prefix over blocks; writes tot[d]
__global__ void k_scanA(const unsigned* __restrict__ hist, unsigned* __restrict__ offs,
                        unsigned* __restrict__ tot, int G) {
    int d = blockIdx.x, ND = gridDim.x, t = threadIdx.x;
    __shared__ unsigned s[256];
    unsigned carry = 0;
    for (int tile = 0; tile * 256 < G; ++tile) {
        int g = tile * 256 + t;
        unsigned v = (g < G) ? hist[(size_t)g * ND + d] : 0u;
        s[t] = v; __syncthreads();
        for (int o = 1; o < 256; o <<= 1) {
            unsigned u = (t >= o) ? s[t - o] : 0u;
            __syncthreads();
            s[t] += u; __syncthreads();
        }
        if (g < G) offs[(size_t)g * ND + d] = s[t] - v + carry;
        unsigned tl = s[255]; __syncthreads();
        carry += tl;
    }
    if (t == 0) tot[d] = carry;
}

// Phase C: compute m, stage 8B records/bin in LDS, cooperative 128B-group flush
__global__ void __launch_bounds__(256) k_part(
        const float* __restrict__ x, const float* __restrict__ ea,
        const int* __restrict__ src, const int* __restrict__ dst,
        const float* __restrict__ Wf, const float* __restrict__ bf,
        const float* __restrict__ Ws, const float* __restrict__ bs,
        const unsigned* __restrict__ offs, const unsigned* __restrict__ tot,
        uint2* __restrict__ rec, int e0, int e1) {
    __shared__ unsigned stage[NB2 * CAPW];
    __shared__ unsigned gcur[NB2], fil[NB2];
    int t = threadIdx.x;
    {   // binBase (FG-rounded exclusive scan of tot) + per-block offs -> gcur
        unsigned v = (tot[t] + FG - 1) & ~(unsigned)(FG - 1);
        stage[t] = v; __syncthreads();
        for (int o = 1; o < 256; o <<= 1) {
            unsigned u = (t >= o) ? stage[t - o] : 0u;
            __syncthreads();
            stage[t] += u; __syncthreads();
        }
        gcur[t] = (stage[t] - v) + offs[(size_t)blockIdx.x * NB2 + t];
        fil[t] = 0;
    }
    __syncthreads();
    int cs = e0 + blockIdx.x * EPB;
    int ce = cs + EPB; if (ce > e1) ce = e1;
    float wf0 = Wf[0], wf1 = Wf[1], wf2 = Wf[2], b0 = bf[0];
    float ws0 = Ws[0], ws1 = Ws[1], ws2 = Ws[2], b1 = bs[0];
    int sg = t >> 4, ln = t & 15;
    for (int rb = cs; rb < ce; rb += RND) {
        int s4[4], d4[4]; float a4[4]; bool vl[4];
        int eb = rb + t * 4;
        if (rb + RND <= ce) {
            i32x4 sv = ntld4i(src + eb);
            i32x4 dv = ntld4i(dst + eb);
            f32x4 av = ntld4f(ea + eb);
            s4[0]=sv.x; s4[1]=sv.y; s4[2]=sv.z; s4[3]=sv.w;
            d4[0]=dv.x; d4[1]=dv.y; d4[2]=dv.z; d4[3]=dv.w;
            a4[0]=av.x; a4[1]=av.y; a4[2]=av.z; a4[3]=av.w;
            vl[0]=vl[1]=vl[2]=vl[3]=true;
        } else {
            #pragma unroll
            for (int j = 0; j < 4; ++j) {
                int e = eb + j;
                vl[j] = e < ce;
                s4[j] = vl[j] ? src[e] : 0;
                d4[j] = vl[j] ? dst[e] : 0;
                a4[j] = vl[j] ? ea[e]  : 0.f;
            }
        }
        #pragma unroll
        for (int j = 0; j < 4; ++j) {
            if (!vl[j]) continue;
            int d = d4[j];
            float m = edge_m(x[d], x[s4[j]], a4[j], wf0, wf1, wf2, b0, ws0, ws1, ws2, b1);
            unsigned bin = ((unsigned)d) >> BSH;
            unsigned dl  = (unsigned)(d & ((1 << BSH) - 1));
            unsigned slot = atomicAdd(&fil[bin], 1u);
            if (slot < CAP) {
                stage[bin * CAPW + 2 * slot]     = __float_as_uint(m);
                stage[bin * CAPW + 2 * slot + 1] = dl;
            } else {
                rec[gcur[bin] + slot] = make_uint2(__float_as_uint(m), dl);  // rare
            }
        }
        __syncthreads();
        // cooperative flush: subgroup sg handles bins sg, sg+16, ...
        for (int i = 0; i < NB2 / 16; ++i) {
            int b = sg + (i << 4);
            unsigned c = fil[b];
            if (c < FG) continue;
            unsigned g = gcur[b];
            unsigned* st = &stage[b * CAPW];
            if (c > CAP) {           // rare drain-all (overflow already in place)
                rec[g + ln] = make_uint2(st[2 * ln], st[2 * ln + 1]);
                if (ln < CAP - 16)
                    rec[g + 16 + ln] = make_uint2(st[2 * (16 + ln)], st[2 * (16 + ln) + 1]);
                if (ln == 0) { gcur[b] = g + c; fil[b] = 0; }
            } else {                 // flush one 128B group, compact remainder
                rec[g + ln] = make_uint2(st[2 * ln], st[2 * ln + 1]);
                unsigned rem = c - FG;
                unsigned lo0 = 0, lo1 = 0;
                if (ln < rem) { lo0 = st[2 * (FG + ln)]; lo1 = st[2 * (FG + ln) + 1]; }
                if (ln < rem) { st[2 * ln] = lo0; st[2 * ln + 1] = lo1; }
                if (ln == 0) { gcur[b] = g + FG; fil[b] = rem; }
            }
        }
        __syncthreads();
    }
    // tail drain (fil < FG guaranteed)
    for (int i = 0; i < NB2 / 16; ++i) {
        int b = sg + (i << 4);
        unsigned c = fil[b], g = gcur[b];
        unsigned* st = &stage[b * CAPW];
        if (ln < c) rec[g + ln] = make_uint2(st[2 * ln], st[2 * ln + 1]);
    }
}

// Phase D: per-bin LDS aggregation -> aggr, optional fused sum/sumsq stats
__global__ void __launch_bounds__(256) k_aggr2(
        const uint2* __restrict__ rec, const unsigned* __restrict__ tot,
        float* __restrict__ aggr, float* __restrict__ stats,
        int N, int accumulate, int doStats) {
    __shared__ float acc[1 << BSH];
    __shared__ unsigned sc[256];
    __shared__ unsigned sBase, sCnt;
    int t = threadIdx.x, b = blockIdx.x;
    {   // recompute FG-rounded exclusive base for bin b
        unsigned v = (tot[t] + FG - 1) & ~(unsigned)(FG - 1);
        sc[t] = v; __syncthreads();
        for (int o = 1; o < 256; o <<= 1) {
            unsigned u = (t >= o) ? sc[t - o] : 0u;
            __syncthreads();
            sc[t] += u; __syncthreads();
        }
        if (t == b) { sBase = sc[t] - v; sCnt = tot[t]; }
    }
    for (int i = t; i < (1 << BSH); i += 256) acc[i] = 0.f;
    __syncthreads();
    unsigned lo = sBase, hi = lo + sCnt;
    for (unsigned i = lo + t; i < hi; i += 256) {
        u32x2 r = __builtin_nontemporal_load((const u32x2*)&rec[i]);
        atomicAdd(&acc[r.y], __uint_as_float(r.x));
    }
    __syncthreads();
    int nb = b << BSH;
    float s = 0.f, q = 0.f;
    for (int i = t; i < (1 << BSH); i += 256) {
        int node = nb + i;
        if (node < N) {
            float v = acc[i];
            if (accumulate) v += aggr[node];
            aggr[node] = v;
            if (doStats) { s += v; q += v * v; }
        }
    }
    if (doStats) {
        __shared__ float s1[256], s2[256];
        s1[t] = s; s2[t] = q; __syncthreads();
        for (int o = 128; o > 0; o >>= 1) {
            if (t < o) { s1[t] += s1[t + o]; s2[t] += s2[t + o]; }
            __syncthreads();
        }
        if (t == 0) { atomicAdd(&stats[0], s1[0]); atomicAdd(&stats[1], s2[0]); }
    }
}

// ---------------- conv1 atomic fallback (ws too small) ----------------
__global__ void k_conv1(const float* __restrict__ x, const float* __restrict__ ea,
                        const int* __restrict__ src, const int* __restrict__ dst,
                        const float* __restrict__ Wf, const float* __restrict__ bf,
                        const float* __restrict__ Ws, const float* __restrict__ bs,
                        float* __restrict__ aggr, int E) {
    int e = blockIdx.x * blockDim.x + threadIdx.x;
    if (e >= E) return;
    int s = src[e], d = dst[e];
    atomicAdd(&aggr[d], edge_m(x[d], x[s], ea[e], Wf[0], Wf[1], Wf[2], bf[0],
                               Ws[0], Ws[1], Ws[2], bs[0]));
}

// ---------------- conv2: streamed vec4 src/dst, sparse atomics ----------------
__global__ void __launch_bounds__(256) k_conv2(
        const float* __restrict__ x2, const float* __restrict__ ea,
        const int* __restrict__ src, const int* __restrict__ dst,
        const int* __restrict__ nidx,
        const float* __restrict__ Wf, const float* __restrict__ bf,
        const float* __restrict__ Ws, const float* __restrict__ bs,
        float* __restrict__ aggr, int E) {
    int base = (blockIdx.x * 256 + threadIdx.x) * 4;
    if (base >= E) return;
    float wf0 = Wf[0], wf1 = Wf[1], wf2 = Wf[2], b0 = bf[0];
    float ws0 = Ws[0], ws1 = Ws[1], ws2 = Ws[2], b1 = bs[0];
    int d4[4], s4[4]; int cnt;
    if (base + 4 <= E) {
        i32x4 dv = ntld4i(dst + base);
        i32x4 sv = ntld4i(src + base);
        d4[0]=dv.x; d4[1]=dv.y; d4[2]=dv.z; d4[3]=dv.w;
        s4[0]=sv.x; s4[1]=sv.y; s4[2]=sv.z; s4[3]=sv.w;
        cnt = 4;
    } else {
        cnt = E - base;
        for (int j = 0; j < cnt; ++j) { d4[j] = dst[base + j]; s4[j] = src[base + j]; }
    }
    #pragma unroll
    for (int j = 0; j < 4; ++j) {
        if (j >= cnt) break;
        int nd = nidx[d4[j]];
        if (nd < 0) continue;
        int ns = nidx[s4[j]];
        if (ns < 0) continue;
        float a = __builtin_nontemporal_load(ea + base + j);
        atomicAdd(&aggr[nd], edge_m(x2[nd], x2[ns], a, wf0, wf1, wf2, b0, ws0, ws1, ws2, b1));
    }
}

// ---------------- sum / sumsq reduction ----------------
__global__ void k_stats(const float* __restrict__ a, int n, float* __restrict__ stats) {
    float s = 0.f, q = 0.f;
    int stride = gridDim.x * blockDim.x;
    for (int i = blockIdx.x * blockDim.x + threadIdx.x; i < n; i += stride) {
        float v = a[i]; s += v; q += v * v;
    }
    __shared__ float s1[256], s2[256];
    s1[threadIdx.x] = s; s2[threadIdx.x] = q; __syncthreads();
    for (int o = 128; o > 0; o >>= 1) {
        if (threadIdx.x < o) { s1[threadIdx.x] += s1[threadIdx.x + o]; s2[threadIdx.x] += s2[threadIdx.x + o]; }
        __syncthreads();
    }
    if (threadIdx.x == 0) { atomicAdd(&stats[0], s1[0]); atomicAdd(&stats[1], s2[0]); }
}

// ------ batchnorm + residual (+ sort-key emit, + optional nidx/aggr2 init) ------
__global__ void k_bn(const float* __restrict__ aggr, const float* __restrict__ xin,
                     const float* __restrict__ stats, const float* __restrict__ g,
                     const float* __restrict__ be, float* __restrict__ xout,
                     int n, float invn, const float* __restrict__ consts, int ci,
                     unsigned* __restrict__ keys, unsigned* __restrict__ vals,
                     int* __restrict__ nidxInit, float* __restrict__ zeroArr, int nZero) {
    int i = blockIdx.x * blockDim.x + threadIdx.x;
    if (i >= n) return;
    if (nidxInit) nidxInit[i] = -1;
    if (zeroArr && i < nZero) zeroArr[i] = 0.f;
    float mean = stats[0] * invn;
    float var  = stats[1] * invn - mean * mean;
    float inv  = 1.0f / sqrtf(var + 1e-5f);
    float v = g[0] * (aggr[i] - mean) * inv + be[0] + xin[i];
    xout[i] = v;
    float s = tanhf(v * consts[ci]);
    keys[i] = key_desc(s);
    vals[i] = (unsigned)i;
}

// ---------------- radix sort: per-chunk histogram (vec4) ----------------
__global__ void k_hist(const unsigned* __restrict__ keys, unsigned* __restrict__ hist,
                       int n, int shift) {
    __shared__ unsigned h[256];
    int t = threadIdx.x;
    h[t] = 0;
    __syncthreads();
    int base = blockIdx.x * CHUNK;
    if (base + CHUNK <= n) {
        #pragma unroll
        for (int it = 0; it < CHUNK / 1024; ++it) {
            int i = base + it * 1024 + t * 4;
            const unsigned* p = keys + i;
            unsigned k0 = p[0], k1 = p[1], k2 = p[2], k3 = p[3];
            atomicAdd(&h[(k0 >> shift) & 255u], 1u);
            atomicAdd(&h[(k1 >> shift) & 255u], 1u);
            atomicAdd(&h[(k2 >> shift) & 255u], 1u);
            atomicAdd(&h[(k3 >> shift) & 255u], 1u);
        }
    } else {
        for (int i = base + t; i < n; i += 256)
            atomicAdd(&h[(keys[i] >> shift) & 255u], 1u);
    }
    __syncthreads();
    hist[blockIdx.x * 256 + t] = h[t];
}

// ---------------- radix sort: stable scatter (4 waves; internal base scan) ----------------
__global__ void __launch_bounds__(256) k_scatter(const unsigned* __restrict__ keys,
                                                 const unsigned* __restrict__ vals,
                                                 unsigned* __restrict__ okeys,
                                                 unsigned* __restrict__ ovals,
                                                 const unsigned* __restrict__ offs,
                                                 const unsigned* __restrict__ tot,
                                                 int n, int shift) {
    __shared__ unsigned run[256];
    __shared__ unsigned offl[256];
    __shared__ unsigned wcnt[4][256];
    __shared__ unsigned wpre[4][256];
    __shared__ unsigned sc[256];
    int t = threadIdx.x;
    int wave = t >> 6, lane = t & 63;
    {   // digit base = exclusive scan of tot
        unsigned v = tot[t];
        sc[t] = v; __syncthreads();
        for (int o = 1; o < 256; o <<= 1) {
            unsigned u = (t >= o) ? sc[t - o] : 0u;
            __syncthreads();
            sc[t] += u; __syncthreads();
        }
        offl[t] = offs[(size_t)blockIdx.x * 256 + t] + (sc[t] - v);
        run[t] = 0;
    }
    __syncthreads();
    int cbase = blockIdx.x * CHUNK;
    const int GROUPS = CHUNK / 256;
    for (int gix = 0; gix < GROUPS; ++gix) {
        int i = cbase + gix * 256 + t;
        bool active = i < n;
        unsigned k = active ? keys[i] : 0u;
        unsigned v = active ? vals[i] : 0u;
        unsigned d = (k >> shift) & 255u;
        unsigned long long amask = __ballot(active);
        unsigned long long bb[8];
        #pragma unroll
        for (int bit = 0; bit < 8; ++bit) bb[bit] = __ballot(active && ((d >> bit) & 1u));
        unsigned long long m = amask;
        #pragma unroll
        for (int bit = 0; bit < 8; ++bit) m &= ((d >> bit) & 1u) ? bb[bit] : ~bb[bit];
        unsigned rk = (unsigned)__popcll(m & ((1ull << lane) - 1ull));
        #pragma unroll
        for (int j = 0; j < 4; ++j) {
            unsigned dd = (unsigned)lane + j * 64u;
            unsigned long long mm = amask;
            #pragma unroll
            for (int bit = 0; bit < 8; ++bit) mm &= ((dd >> bit) & 1u) ? bb[bit] : ~bb[bit];
            wcnt[wave][dd] = (unsigned)__popcll(mm);
        }
        __syncthreads();
        {
            unsigned r = run[t];
            unsigned c0 = wcnt[0][t], c1 = wcnt[1][t], c2 = wcnt[2][t], c3 = wcnt[3][t];
            wpre[0][t] = r;
            wpre[1][t] = r + c0;
            wpre[2][t] = r + c0 + c1;
            wpre[3][t] = r + c0 + c1 + c2;
            run[t] = r + c0 + c1 + c2 + c3;
        }
        __syncthreads();
        if (active) {
            unsigned pos = offl[d] + wpre[wave][d] + rk;
            okeys[pos] = k;
            ovals[pos] = v;
        }
    }
}

// ---------------- pool gather (+ optional new_idx, + optional next-sort keys) ----------------
__global__ void k_pool(const unsigned* __restrict__ perm, const float* __restrict__ xin,
                       const float* __restrict__ consts, int ci,
                       float* __restrict__ xout, int* __restrict__ newidx, int k,
                       unsigned* __restrict__ okeys, unsigned* __restrict__ ovals, int nci) {
    int r = blockIdx.x * blockDim.x + threadIdx.x;
    if (r >= k) return;
    unsigned p = perm[r];
    float xv = xin[p];
    float s = tanhf(xv * consts[ci]);
    float o = xv * s;
    xout[r] = o;
    if (newidx) newidx[p] = r;
    if (okeys) {
        float s2 = tanhf(o * consts[nci]);
        okeys[r] = key_desc(s2);
        ovals[r] = (unsigned)r;
    }
}

// ---------------- single-block: 4-pass radix sort + pool3 + MLP + log_softmax ----------------
__global__ void __launch_bounds__(1024) k_smallsort(
        unsigned* __restrict__ kIn, unsigned* __restrict__ vIn,
        unsigned* __restrict__ kTmp, unsigned* __restrict__ vTmp,
        int n, int k3, const float* __restrict__ xin,
        const float* __restrict__ consts, int ci,
        const float* __restrict__ Wl1, const float* __restrict__ bl1,
        const float* __restrict__ Wl2, const float* __restrict__ bl2,
        float* __restrict__ out) {
    __shared__ unsigned hist[256], sc[256], run[256], offl[256];
    __shared__ unsigned wcnt[16][256];
    __shared__ unsigned wpre[16][256];
    int t = threadIdx.x;
    int wave = t >> 6, lane = t & 63;
    unsigned *ki = kIn, *vi = vIn, *ko = kTmp, *vo = vTmp;
    for (int p = 0; p < 4; ++p) {
        int shift = p * 8;
        if (t < 256) hist[t] = 0;
        __syncthreads();
        for (int i = t; i < n; i += 1024)
            atomicAdd(&hist[(ki[i] >> shift) & 255u], 1u);
        __syncthreads();
        if (t < 256) sc[t] = hist[t];
        __syncthreads();
        for (int o = 1; o < 256; o <<= 1) {
            unsigned u = 0;
            if (t < 256 && t >= o) u = sc[t - o];
            __syncthreads();
            if (t < 256) sc[t] += u;
            __syncthreads();
        }
        if (t < 256) { offl[t] = sc[t] - hist[t]; run[t] = 0; }
        __syncthreads();
        int G = (n + 1023) / 1024;
        for (int gix = 0; gix < G; ++gix) {
            int i = gix * 1024 + t;
            bool active = i < n;
            unsigned k = active ? ki[i] : 0u;
            unsigned v = active ? vi[i] : 0u;
            unsigned d = (k >> shift) & 255u;
            unsigned long long amask = __ballot(active);
            unsigned long long bb[8];
            #pragma unroll
            for (int bit = 0; bit < 8; ++bit) bb[bit] = __ballot(active && ((d >> bit) & 1u));
            unsigned long long m = amask;
            #pragma unroll
            for (int bit = 0; bit < 8; ++bit) m &= ((d >> bit) & 1u) ? bb[bit] : ~bb[bit];
            unsigned rk = (unsigned)__popcll(m & ((1ull << lane) - 1ull));
            #pragma unroll
            for (int j = 0; j < 4; ++j) {
                unsigned dd = (unsigned)lane + j * 64u;
                unsigned long long mm = amask;
                #pragma unroll
                for (int bit = 0; bit < 8; ++bit) mm &= ((dd >> bit) & 1u) ? bb[bit] : ~bb[bit];
                wcnt[wave][dd] = (unsigned)__popcll(mm);
            }
            __syncthreads();
            if (t < 256) {
                unsigned acc = run[t];
                #pragma unroll
                for (int w2 = 0; w2 < 16; ++w2) { wpre[w2][t] = acc; acc += wcnt[w2][t]; }
                run[t] = acc;
            }
            __syncthreads();
            if (active) {
                unsigned pos = offl[d] + wpre[wave][d] + rk;
                ko[pos] = k;
                vo[pos] = v;
            }
            __syncthreads();
        }
        unsigned* tp;
        tp = ki; ki = ko; ko = tp;
        tp = vi; vi = vo; vo = tp;
        __syncthreads();
    }
    // sorted in kIn/vIn (4 passes even). pool3 + MLP + log_softmax.
    float c = consts[ci];
    float b20 = bl2[0], b21 = bl2[1];
    for (int r = t; r < k3; r += 1024) {
        unsigned pidx = vIn[r];
        float xv = xin[pidx];
        float s = tanhf(xv * c);
        float o = xv * s;
        float l0 = b20, l1 = b21;
        #pragma unroll
        for (int j = 0; j < 8; ++j) {
            float h = fmaxf(o * Wl1[j] + bl1[j], 0.0f);
            l0 += h * Wl2[2 * j];
            l1 += h * Wl2[2 * j + 1];
        }
        float mx = fmaxf(l0, l1);
        float lse = mx + logf(expf(l0 - mx) + expf(l1 - mx));
        out[2 * r]     = l0 - lse;
        out[2 * r + 1] = l1 - lse;
    }
}

// ---------------- host-side radix sort driver (3 launches/pass) ----------------
static void sort_pairs(hipStream_t stream, unsigned* kA, unsigned* vA,
                       unsigned* kB, unsigned* vB, unsigned* hist, unsigned* offs,
                       unsigned* tot, int n) {
    int G = (n + CHUNK - 1) / CHUNK;
    unsigned *ki = kA, *vi = vA, *ko = kB, *vo = vB;
    for (int p = 0; p < 4; ++p) {
        int shift = p * 8;
        k_hist<<<G, 256, 0, stream>>>(ki, hist, n, shift);
        k_scanA<<<256, 256, 0, stream>>>(hist, offs, tot, G);
        k_scatter<<<G, 256, 0, stream>>>(ki, vi, ko, vo, offs, tot, n, shift);
        unsigned* t;
        t = ki; ki = ko; ko = t;
        t = vi; vi = vo; vo = t;
    }
}

extern "C" void kernel_launch(void* const* d_in, const int* in_sizes, int n_in,
                              void* d_out, int out_size, void* d_ws, size_t ws_size,
                              hipStream_t stream) {
    const float* x   = (const float*)d_in[0];
    const float* ea  = (const float*)d_in[1];
    const int*   src = (const int*)d_in[2];
    const int*   dst = (const int*)d_in[3];
    const float *Wf1 = (const float*)d_in[5],  *bf1 = (const float*)d_in[6];
    const float *Ws1 = (const float*)d_in[7],  *bs1 = (const float*)d_in[8];
    const float *g1  = (const float*)d_in[9],  *be1 = (const float*)d_in[10];
    const float *Wf2 = (const float*)d_in[11], *bf2 = (const float*)d_in[12];
    const float *Ws2 = (const float*)d_in[13], *bs2 = (const float*)d_in[14];
    const float *g2  = (const float*)d_in[15], *be2 = (const float*)d_in[16];
    const float *pw1 = (const float*)d_in[17], *pw2 = (const float*)d_in[18], *pw3 = (const float*)d_in[19];
    const float *Wl1 = (const float*)d_in[20], *bl1 = (const float*)d_in[21];
    const float *Wl2 = (const float*)d_in[22], *bl2 = (const float*)d_in[23];

    const int N  = in_sizes[0];
    const int E  = in_sizes[1];
    const int K1 = 100000, K2 = 10000, K3 = 2500;

    // ---- workspace layout ----
    size_t off = 0;
    auto alloc = [&](size_t bytes) { size_t o = off; off = (off + bytes + 255) & ~(size_t)255; return o; };
    char* ws = (char*)d_ws;
    size_t o_x1    = alloc((size_t)N * 4);
    size_t o_nidx  = alloc((size_t)N * 4);
    size_t o_stats = alloc(256);
    size_t o_const = alloc(256);
    size_t o_tot   = alloc(4096);
    size_t o_x2    = alloc((size_t)K1 * 4);
    size_t o_x3    = alloc((size_t)K1 * 4);
    size_t o_ag2   = alloc((size_t)K1 * 4);
    size_t o_x4    = alloc((size_t)K2 * 4);
    size_t o_ag1   = alloc((size_t)N * 4);
    size_t o_arena = off;

    // sort scratch (overlay B, live from k_bn onward)
    int G1 = (N + CHUNK - 1) / CHUNK;
    size_t s_kA = 0;
    size_t s_vA = s_kA + (((size_t)N * 4 + 255) & ~(size_t)255);
    size_t s_kB = s_vA + (((size_t)N * 4 + 255) & ~(size_t)255);
    size_t s_vB = s_kB + (((size_t)N * 4 + 255) & ~(size_t)255);
    size_t s_h  = s_vB + (((size_t)N * 4 + 255) & ~(size_t)255);
    size_t s_o  = s_h  + (((size_t)G1 * 256 * 4 + 255) & ~(size_t)255);
    size_t sortSz = s_o + (size_t)G1 * 256 * 4;

    // conv1 partition scratch (overlay A, dead after k_aggr2): pick split H
    int H = 0, Eh = 0;
    size_t p_rec = 0, p_eh = 0, p_eo = 0;
    for (int h = 1; h <= 8; h <<= 1) {
        int eh_ = (E + h - 1) / h;
        eh_ = (eh_ + RND - 1) & ~(RND - 1);
        int gc_ = (eh_ + EPB - 1) / EPB;
        size_t recB = (((size_t)(eh_ + NB2 * FG) * 8) + 255) & ~(size_t)255;
        size_t ehB  = (((size_t)gc_ * NB2 * 4) + 255) & ~(size_t)255;
        size_t eoB  = (((size_t)gc_ * NB2 * 4) + 255) & ~(size_t)255;
        size_t partSz = recB + ehB + eoB;
        size_t arenaSz = partSz > sortSz ? partSz : sortSz;
        if (o_arena + arenaSz <= ws_size && N <= (NB2 << BSH)) {
            H = h; Eh = eh_;
            p_rec = 0; p_eh = p_rec + recB; p_eo = p_eh + ehB;
            break;
        }
    }

    float*    x1     = (float*)(ws + o_x1);
    int*      nidx   = (int*)(ws + o_nidx);
    float*    stats  = (float*)(ws + o_stats);
    float*    consts = (float*)(ws + o_const);
    unsigned* tot    = (unsigned*)(ws + o_tot);
    float*    x2     = (float*)(ws + o_x2);
    float*    x3     = (float*)(ws + o_x3);
    float*    aggr2  = (float*)(ws + o_ag2);
    float*    x4     = (float*)(ws + o_x4);
    float*    aggr1  = (float*)(ws + o_ag1);
    unsigned* kA     = (unsigned*)(ws + o_arena + s_kA);
    unsigned* vA     = (unsigned*)(ws + o_arena + s_vA);
    unsigned* kB     = (unsigned*)(ws + o_arena + s_kB);
    unsigned* vB     = (unsigned*)(ws + o_arena + s_vB);
    unsigned* hist   = (unsigned*)(ws + o_arena + s_h);
    unsigned* offs   = (unsigned*)(ws + o_arena + s_o);

    // stats zeroed in k_consts; nidx/-1 + aggr2/0 initialized in first k_bn
    k_consts<<<3, 256, 0, stream>>>(pw1, pw2, pw3, consts, stats,
                                    in_sizes[17], in_sizes[18], in_sizes[19]);

    // ---- cgconv 1 (atomic-free partition path) ----
    if (H > 0) {
        uint2*    rec = (uint2*)(ws + o_arena + p_rec);
        unsigned* eh  = (unsigned*)(ws + o_arena + p_eh);
        unsigned* eo  = (unsigned*)(ws + o_arena + p_eo);
        int NBN = (N + (1 << BSH) - 1) >> BSH;
        for (int h = 0; h < H; ++h) {
            int e0 = h * Eh;
            int e1 = e0 + Eh; if (e1 > E) e1 = E;
            if (e0 >= e1) break;
            int GCh = (e1 - e0 + EPB - 1) / EPB;
            k_ehist2<<<GCh, 256, 0, stream>>>(dst, eh, e0, e1);
            k_scanA<<<NB2, 256, 0, stream>>>(eh, eo, tot, GCh);
            k_part<<<GCh, 256, 0, stream>>>(x, ea, src, dst, Wf1, bf1, Ws1, bs1,
                                            eo, tot, rec, e0, e1);
            k_aggr2<<<NBN, 256, 0, stream>>>(rec, tot, aggr1, stats, N,
                                             h > 0, h == H - 1 ? 1 : 0);
        }
    } else {
        hipMemsetAsync(aggr1, 0, (size_t)N * 4, stream);
        k_conv1<<<(E + 255) / 256, 256, 0, stream>>>(x, ea, src, dst, Wf1, bf1, Ws1, bs1, aggr1, E);
        k_stats<<<1024, 256, 0, stream>>>(aggr1, N, stats);
    }
    k_bn<<<(N + 255) / 256, 256, 0, stream>>>(aggr1, x, stats, g1, be1, x1, N, 1.0f / (float)N,
                                              consts, 0, kA, vA, nidx, aggr2, K1);

    // ---- pool 1 : top 100K of 1M ----
    sort_pairs(stream, kA, vA, kB, vB, hist, offs, tot, N);
    k_pool<<<(K1 + 255) / 256, 256, 0, stream>>>(vA, x1, consts, 0, x2, nidx, K1,
                                                 (unsigned*)nullptr, (unsigned*)nullptr, 0);

    // ---- cgconv 2 (filtered edges; sparse atomics) ----
    k_conv2<<<(E / 4 + 255) / 256, 256, 0, stream>>>(x2, ea, src, dst, nidx,
                                                     Wf2, bf2, Ws2, bs2, aggr2, E);
    k_stats<<<256, 256, 0, stream>>>(aggr2, K1, stats + 2);
    k_bn<<<(K1 + 255) / 256, 256, 0, stream>>>(aggr2, x2, stats + 2, g2, be2, x3, K1, 1.0f / (float)K1,
                                               consts, 1, kA, vA,
                                               (int*)nullptr, (float*)nullptr, 0);

    // ---- pool 2 : top 10K of 100K (emits keys for pool-3 sort into kB/vB) ----
    sort_pairs(stream, kA, vA, kB, vB, hist, offs, tot, K1);
    k_pool<<<(K2 + 255) / 256, 256, 0, stream>>>(vA, x3, consts, 1, x4, (int*)nullptr, K2,
                                                 kB, vB, 2);

    // ---- pool 3 + sort + MLP + log_softmax : one single-block kernel ----
    k_smallsort<<<1, 1024, 0, stream>>>(kB, vB, kA, vA, K2, K3, x4, consts, 2,
                                        Wl1, bl1, Wl2, bl2, (float*)d_out);
}

// Round 8
// 845.533 us; speedup vs baseline: 2.4708x; 1.0440x over previous
//
#include <hip/hip_runtime.h>
#include <math.h>

#define CHUNK 4096               // elements per radix-sort block
#define NB2   256                // conv1 partition bins
#define BSH   12                 // bin = dst >> BSH ; 4096 nodes per bin
#define CAP   24                 // LDS stage capacity per bin (records)
#define CAPW  49                 // LDS words per bin (odd -> conflict-free)
#define FG    16                 // flush group: 16 records = 128 B
#define RND   1024               // edges per staging round (256 thr * 4)
#define EPB   16384              // edges per k_part block

typedef int      i32x4 __attribute__((ext_vector_type(4)));
typedef float    f32x4 __attribute__((ext_vector_type(4)));
typedef unsigned u32x2 __attribute__((ext_vector_type(2)));
typedef unsigned u32x4 __attribute__((ext_vector_type(4)));

__device__ __forceinline__ i32x4 ntld4i(const int* p)   { return __builtin_nontemporal_load((const i32x4*)p); }
__device__ __forceinline__ f32x4 ntld4f(const float* p) { return __builtin_nontemporal_load((const f32x4*)p); }

__device__ __forceinline__ float sigmoidf_(float x) {
    if (x >= 0.0f) { float e = expf(-x); return 1.0f / (1.0f + e); }
    float e = expf(x); return e / (1.0f + e);
}
__device__ __forceinline__ float softplusf_(float x) {
    return fmaxf(x, 0.0f) + log1pf(expf(-fabsf(x)));
}
__device__ __forceinline__ unsigned key_desc(float f) {
    unsigned u = __float_as_uint(f);
    unsigned ka = (u & 0x80000000u) ? ~u : (u | 0x80000000u);  // ascending map
    return ~ka;                                                 // descending
}
__device__ __forceinline__ float edge_m(float xd, float xs, float a,
                                        float wf0, float wf1, float wf2, float b0,
                                        float ws0, float ws1, float ws2, float b1) {
    float f = xd * wf0 + xs * wf1 + a * wf2 + b0;
    float g = xd * ws0 + xs * ws1 + a * ws2 + b1;
    return sigmoidf_(f) * softplusf_(g);
}

// ---------------- score constants + stats/ghist zeroing ----------------
__global__ void k_consts(const float* __restrict__ pw1, const float* __restrict__ pw2,
                         const float* __restrict__ pw3, float* __restrict__ consts,
                         float* __restrict__ stats, unsigned* __restrict__ ghist,
                         int n1, int n2, int n3) {
    if (blockIdx.x == 0) {
        if (threadIdx.x < 16) stats[threadIdx.x] = 0.f;
        for (int i = threadIdx.x; i < 2048; i += 256) ghist[i] = 0u;
    }
    const float* w; int n;
    if (blockIdx.x == 0)      { w = pw1; n = n1; }
    else if (blockIdx.x == 1) { w = pw2; n = n2; }
    else                      { w = pw3; n = n3; }
    __shared__ float s1[256], s2[256];
    float a = 0.f, b = 0.f;
    for (int i = threadIdx.x; i < n; i += 256) { float v = w[i]; a += v; b += v * v; }
    s1[threadIdx.x] = a; s2[threadIdx.x] = b; __syncthreads();
    for (int o = 128; o > 0; o >>= 1) {
        if (threadIdx.x < o) { s1[threadIdx.x] += s1[threadIdx.x + o]; s2[threadIdx.x] += s2[threadIdx.x + o]; }
        __syncthreads();
    }
    if (threadIdx.x == 0) consts[blockIdx.x] = s1[0] / sqrtf(s2[0]);
}

// ============== conv1: atomic-free two-level partition ==============
__global__ void __launch_bounds__(256) k_ehist2(const int* __restrict__ dst,
                                                unsigned* __restrict__ hist,
                                                int e0, int e1) {
    __shared__ unsigned h[NB2];
    int t = threadIdx.x;
    h[t] = 0;
    __syncthreads();
    int cs = e0 + blockIdx.x * EPB;
    int ce = cs + EPB; if (ce > e1) ce = e1;
    for (int eb = cs; eb < ce; eb += RND) {
        int i = eb + t * 4;
        if (eb + RND <= ce) {
            i32x4 d4 = ntld4i(dst + i);
            atomicAdd(&h[((unsigned)d4.x) >> BSH], 1u);
            atomicAdd(&h[((unsigned)d4.y) >> BSH], 1u);
            atomicAdd(&h[((unsigned)d4.z) >> BSH], 1u);
            atomicAdd(&h[((unsigned)d4.w) >> BSH], 1u);
        } else {
            #pragma unroll
            for (int j = 0; j < 4; ++j)
                if (i + j < ce) atomicAdd(&h[((unsigned)dst[i + j]) >> BSH], 1u);
        }
    }
    __syncthreads();
    hist[(size_t)blockIdx.x * NB2 + t] = h[t];
}

// scanA: one block per digit; within-digit exclusive prefix over blocks.
// rmask: per-entry round-up (0 for sorts, FG-1 for conv1 -> 128B-aligned regions)
__global__ void k_scanA(const unsigned* __restrict__ hist, unsigned* __restrict__ offs,
                        unsigned* __restrict__ tot, int G, unsigned rmask) {
    int d = blockIdx.x, ND = gridDim.x, t = threadIdx.x;
    __shared__ unsigned s[256];
    unsigned carry = 0;
    for (int tile = 0; tile * 256 < G; ++tile) {
        int g = tile * 256 + t;
        unsigned v = (g < G) ? ((hist[(size_t)g * ND + d] + rmask) & ~rmask) : 0u;
        s[t] = v; __syncthreads();
        for (int o = 1; o < 256; o <<= 1) {
            unsigned u = (t >= o) ? s[t - o] : 0u;
            __syncthreads();
            s[t] += u; __syncthreads();
        }
        if (g < G) offs[(size_t)g * ND + d] = s[t] - v + carry;
        unsigned tl = s[255]; __syncthreads();
        carry += tl;
    }
    if (t == 0) tot[d] = carry;
}

// Phase C: stage 8B records/bin in LDS; worklist-driven aligned 128B flush
__global__ void __launch_bounds__(256) k_part(
        const float* __restrict__ x, const float* __restrict__ ea,
        const int* __restrict__ src, const int* __restrict__ dst,
        const float* __restrict__ Wf, const float* __restrict__ bf,
        const float* __restrict__ Ws, const float* __restrict__ bs,
        const unsigned* __restrict__ offs, const unsigned* __restrict__ tot,
        const unsigned* __restrict__ eh,
        uint2* __restrict__ rec, int e0, int e1) {
    __shared__ unsigned stage[NB2 * CAPW];
    __shared__ unsigned gcur[NB2], fil[NB2], gend[NB2];
    __shared__ unsigned short wl[2][NB2];
    __shared__ unsigned wlc[2];
    int t = threadIdx.x;
    {   // bin bases: exclusive scan of (pre-rounded) tot + per-block offs
        unsigned v = tot[t];
        stage[t] = v; __syncthreads();
        for (int o = 1; o < 256; o <<= 1) {
            unsigned u = (t >= o) ? stage[t - o] : 0u;
            __syncthreads();
            stage[t] += u; __syncthreads();
        }
        unsigned g0 = (stage[t] - v) + offs[(size_t)blockIdx.x * NB2 + t];
        unsigned cnt = eh[(size_t)blockIdx.x * NB2 + t];
        gcur[t] = g0;
        gend[t] = g0 + ((cnt + FG - 1) & ~(unsigned)(FG - 1));
        fil[t] = 0;
        if (t < 2) wlc[t] = 0;
    }
    __syncthreads();
    int cs = e0 + blockIdx.x * EPB;
    int ce = cs + EPB; if (ce > e1) ce = e1;
    float wf0 = Wf[0], wf1 = Wf[1], wf2 = Wf[2], b0 = bf[0];
    float ws0 = Ws[0], ws1 = Ws[1], ws2 = Ws[2], b1 = bs[0];
    int sg = t >> 4, ln = t & 15;
    int rnd = 0;
    for (int rb = cs; rb < ce; rb += RND, ++rnd) {
        int cur = rnd & 1;
        int s4[4], d4[4]; float a4[4]; bool vl[4];
        int eb = rb + t * 4;
        if (rb + RND <= ce) {
            i32x4 sv = ntld4i(src + eb);
            i32x4 dv = ntld4i(dst + eb);
            f32x4 av = ntld4f(ea + eb);
            s4[0]=sv.x; s4[1]=sv.y; s4[2]=sv.z; s4[3]=sv.w;
            d4[0]=dv.x; d4[1]=dv.y; d4[2]=dv.z; d4[3]=dv.w;
            a4[0]=av.x; a4[1]=av.y; a4[2]=av.z; a4[3]=av.w;
            vl[0]=vl[1]=vl[2]=vl[3]=true;
        } else {
            #pragma unroll
            for (int j = 0; j < 4; ++j) {
                int e = eb + j;
                vl[j] = e < ce;
                s4[j] = vl[j] ? src[e] : 0;
                d4[j] = vl[j] ? dst[e] : 0;
                a4[j] = vl[j] ? ea[e]  : 0.f;
            }
        }
        #pragma unroll
        for (int j = 0; j < 4; ++j) {
            if (!vl[j]) continue;
            int d = d4[j];
            float m = edge_m(x[d], x[s4[j]], a4[j], wf0, wf1, wf2, b0, ws0, ws1, ws2, b1);
            unsigned bin = ((unsigned)d) >> BSH;
            unsigned dl  = (unsigned)(d & ((1 << BSH) - 1));
            unsigned slot = atomicAdd(&fil[bin], 1u);
            if (slot == FG - 1) {                       // bin crossed 16 -> worklist
                unsigned w = atomicAdd(&wlc[cur], 1u);
                wl[cur][w] = (unsigned short)bin;
            }
            if (slot < CAP) {
                stage[bin * CAPW + 2 * slot]     = __float_as_uint(m);
                stage[bin * CAPW + 2 * slot + 1] = dl;
            } else {
                rec[gcur[bin] + slot] = make_uint2(__float_as_uint(m), dl);  // rare
            }
        }
        __syncthreads();
        unsigned nw = wlc[cur];
        for (unsigned i = sg; i < nw; i += 16) {
            int b = wl[cur][i];
            unsigned c = fil[b], g = gcur[b];
            unsigned* st = &stage[b * CAPW];
            if (c > CAP) {           // rare drain-all (overflow already in place)
                rec[g + ln] = make_uint2(st[2 * ln], st[2 * ln + 1]);
                if (ln < CAP - 16)
                    rec[g + 16 + ln] = make_uint2(st[2 * (16 + ln)], st[2 * (16 + ln) + 1]);
                if (ln == 0) { gcur[b] = g + c; fil[b] = 0; }
            } else {                 // flush one aligned 128B group, compact remainder
                rec[g + ln] = make_uint2(st[2 * ln], st[2 * ln + 1]);
                unsigned rem = c - FG;
                unsigned a0 = 0, a1 = 0;
                if (ln < rem) { a0 = st[2 * (FG + ln)]; a1 = st[2 * (FG + ln) + 1]; }
                if (ln < rem) { st[2 * ln] = a0; st[2 * ln + 1] = a1; }
                if (ln == 0) { gcur[b] = g + FG; fil[b] = rem; }
            }
        }
        if (t == 0) wlc[cur ^ 1] = 0;
        __syncthreads();
    }
    // tail: fill to region end (zero-pad -> aggr2-benign)
    for (int i = 0; i < NB2 / 16; ++i) {
        int b = sg + (i << 4);
        unsigned g = gcur[b], c = fil[b], ge = gend[b];
        unsigned* st = &stage[b * CAPW];
        for (unsigned p = g + ln; p < ge; p += 16) {
            unsigned k2 = p - g;
            rec[p] = (k2 < c) ? make_uint2(st[2 * k2], st[2 * k2 + 1]) : make_uint2(0u, 0u);
        }
    }
}

// Phase D: per-bin LDS aggregation -> aggr, optional fused sum/sumsq stats
__global__ void __launch_bounds__(256) k_aggr2(
        const uint2* __restrict__ rec, const unsigned* __restrict__ tot,
        float* __restrict__ aggr, float* __restrict__ stats,
        int N, int accumulate, int doStats) {
    __shared__ float acc[1 << BSH];
    __shared__ unsigned sc[256];
    __shared__ unsigned sBase, sCnt;
    int t = threadIdx.x, b = blockIdx.x;
    {   // exclusive base for bin b (tot pre-rounded to FG multiples)
        unsigned v = tot[t];
        sc[t] = v; __syncthreads();
        for (int o = 1; o < 256; o <<= 1) {
            unsigned u = (t >= o) ? sc[t - o] : 0u;
            __syncthreads();
            sc[t] += u; __syncthreads();
        }
        if (t == b) { sBase = sc[t] - v; sCnt = tot[t]; }
    }
    for (int i = t; i < (1 << BSH); i += 256) acc[i] = 0.f;
    __syncthreads();
    unsigned lo = sBase, hi = lo + sCnt;
    for (unsigned i = lo + t; i < hi; i += 256) {
        u32x2 r = __builtin_nontemporal_load((const u32x2*)&rec[i]);
        atomicAdd(&acc[r.y], __uint_as_float(r.x));
    }
    __syncthreads();
    int nb = b << BSH;
    float s = 0.f, q = 0.f;
    for (int i = t; i < (1 << BSH); i += 256) {
        int node = nb + i;
        if (node < N) {
            float v = acc[i];
            if (accumulate) v += aggr[node];
            aggr[node] = v;
            if (doStats) { s += v; q += v * v; }
        }
    }
    if (doStats) {
        __shared__ float s1[256], s2[256];
        s1[t] = s; s2[t] = q; __syncthreads();
        for (int o = 128; o > 0; o >>= 1) {
            if (t < o) { s1[t] += s1[t + o]; s2[t] += s2[t + o]; }
            __syncthreads();
        }
        if (t == 0) { atomicAdd(&stats[0], s1[0]); atomicAdd(&stats[1], s2[0]); }
    }
}

// ---------------- conv1 atomic fallback (ws too small) ----------------
__global__ void k_conv1(const float* __restrict__ x, const float* __restrict__ ea,
                        const int* __restrict__ src, const int* __restrict__ dst,
                        const float* __restrict__ Wf, const float* __restrict__ bf,
                        const float* __restrict__ Ws, const float* __restrict__ bs,
                        float* __restrict__ aggr, int E) {
    int e = blockIdx.x * blockDim.x + threadIdx.x;
    if (e >= E) return;
    int s = src[e], d = dst[e];
    atomicAdd(&aggr[d], edge_m(x[d], x[s], ea[e], Wf[0], Wf[1], Wf[2], bf[0],
                               Ws[0], Ws[1], Ws[2], bs[0]));
}

// ---------------- conv2: streamed vec4 src/dst, sparse atomics ----------------
__global__ void __launch_bounds__(256) k_conv2(
        const float* __restrict__ x2, const float* __restrict__ ea,
        const int* __restrict__ src, const int* __restrict__ dst,
        const int* __restrict__ nidx,
        const float* __restrict__ Wf, const float* __restrict__ bf,
        const float* __restrict__ Ws, const float* __restrict__ bs,
        float* __restrict__ aggr, int E) {
    int base = (blockIdx.x * 256 + threadIdx.x) * 4;
    if (base >= E) return;
    float wf0 = Wf[0], wf1 = Wf[1], wf2 = Wf[2], b0 = bf[0];
    float ws0 = Ws[0], ws1 = Ws[1], ws2 = Ws[2], b1 = bs[0];
    int d4[4], s4[4]; int cnt;
    if (base + 4 <= E) {
        i32x4 dv = ntld4i(dst + base);
        i32x4 sv = ntld4i(src + base);
        d4[0]=dv.x; d4[1]=dv.y; d4[2]=dv.z; d4[3]=dv.w;
        s4[0]=sv.x; s4[1]=sv.y; s4[2]=sv.z; s4[3]=sv.w;
        cnt = 4;
    } else {
        cnt = E - base;
        for (int j = 0; j < cnt; ++j) { d4[j] = dst[base + j]; s4[j] = src[base + j]; }
    }
    #pragma unroll
    for (int j = 0; j < 4; ++j) {
        if (j >= cnt) break;
        int nd = nidx[d4[j]];
        if (nd < 0) continue;
        int ns = nidx[s4[j]];
        if (ns < 0) continue;
        float a = __builtin_nontemporal_load(ea + base + j);
        atomicAdd(&aggr[nd], edge_m(x2[nd], x2[ns], a, wf0, wf1, wf2, b0, ws0, ws1, ws2, b1));
    }
}

// ---------------- sum / sumsq reduction ----------------
__global__ void k_stats(const float* __restrict__ a, int n, float* __restrict__ stats) {
    float s = 0.f, q = 0.f;
    int stride = gridDim.x * blockDim.x;
    for (int i = blockIdx.x * blockDim.x + threadIdx.x; i < n; i += stride) {
        float v = a[i]; s += v; q += v * v;
    }
    __shared__ float s1[256], s2[256];
    s1[threadIdx.x] = s; s2[threadIdx.x] = q; __syncthreads();
    for (int o = 128; o > 0; o >>= 1) {
        if (threadIdx.x < o) { s1[threadIdx.x] += s1[threadIdx.x + o]; s2[threadIdx.x] += s2[threadIdx.x + o]; }
        __syncthreads();
    }
    if (threadIdx.x == 0) { atomicAdd(&stats[0], s1[0]); atomicAdd(&stats[1], s2[0]); }
}

// ------ batchnorm + residual (+ sort-key emit, + optional nidx/aggr2 init) ------
__global__ void k_bn(const float* __restrict__ aggr, const float* __restrict__ xin,
                     const float* __restrict__ stats, const float* __restrict__ g,
                     const float* __restrict__ be, float* __restrict__ xout,
                     int n, float invn, const float* __restrict__ consts, int ci,
                     unsigned* __restrict__ keys, unsigned* __restrict__ vals,
                     int* __restrict__ nidxInit, float* __restrict__ zeroArr, int nZero) {
    int i = blockIdx.x * blockDim.x + threadIdx.x;
    if (i >= n) return;
    if (nidxInit) nidxInit[i] = -1;
    if (zeroArr && i < nZero) zeroArr[i] = 0.f;
    float mean = stats[0] * invn;
    float var  = stats[1] * invn - mean * mean;
    float inv  = 1.0f / sqrtf(var + 1e-5f);
    float v = g[0] * (aggr[i] - mean) * inv + be[0] + xin[i];
    xout[i] = v;
    float s = tanhf(v * consts[ci]);
    keys[i] = key_desc(s);
    vals[i] = (unsigned)i;
}

// ============== top-K select: ghist -> findT -> count -> compact ==============
__global__ void __launch_bounds__(256) k_ghist(const unsigned* __restrict__ keys,
                                               unsigned* __restrict__ ghist, int n) {
    __shared__ unsigned h[2048];
    int t = threadIdx.x;
    for (int i = t; i < 2048; i += 256) h[i] = 0;
    __syncthreads();
    int stride = gridDim.x * 1024;
    for (int base = blockIdx.x * 1024 + t * 4; base + 3 < n; base += stride) {
        u32x4 k4 = __builtin_nontemporal_load((const u32x4*)(keys + base));
        atomicAdd(&h[k4.x >> 21], 1u);
        atomicAdd(&h[k4.y >> 21], 1u);
        atomicAdd(&h[k4.z >> 21], 1u);
        atomicAdd(&h[k4.w >> 21], 1u);
    }
    if (blockIdx.x == 0) {
        int tail = n & ~3;
        for (int i = tail + t; i < n; i += 256)
            atomicAdd(&h[keys[i] >> 21], 1u);
    }
    __syncthreads();
    for (int i = t; i < 2048; i += 256) { unsigned v = h[i]; if (v) atomicAdd(&ghist[i], v); }
}

__global__ void k_findT(const unsigned* __restrict__ ghist, unsigned* __restrict__ sel, int K) {
    __shared__ unsigned s[256];
    int t = threadIdx.x;
    unsigned carry = 0;
    for (int tile = 0; tile < 8; ++tile) {
        unsigned v = ghist[tile * 256 + t];
        s[t] = v; __syncthreads();
        for (int o = 1; o < 256; o <<= 1) {
            unsigned u = (t >= o) ? s[t - o] : 0u;
            __syncthreads();
            s[t] += u; __syncthreads();
        }
        unsigned cum = s[t] + carry;          // inclusive over buckets
        if (cum >= (unsigned)K && cum - v < (unsigned)K) {
            sel[0] = (unsigned)(tile * 256 + t);   // threshold bucket T
            sel[1] = cum;                          // C1 = count(bucket <= T)
        }
        unsigned tl = s[255]; __syncthreads();
        carry += tl;
    }
}

__global__ void __launch_bounds__(256) k_selcnt(const unsigned* __restrict__ keys,
                                                const unsigned* __restrict__ sel,
                                                unsigned* __restrict__ chist, int n) {
    unsigned T = sel[0];
    int t = threadIdx.x;
    int base = blockIdx.x * CHUNK;
    int end = base + CHUNK; if (end > n) end = n;
    unsigned c = 0;
    for (int i = base + t; i < end; i += 256)
        c += ((keys[i] >> 21) <= T) ? 1u : 0u;
    __shared__ unsigned s[256];
    s[t] = c; __syncthreads();
    for (int o = 128; o > 0; o >>= 1) { if (t < o) s[t] += s[t + o]; __syncthreads(); }
    if (t == 0) chist[blockIdx.x] = s[0];
}

__global__ void __launch_bounds__(256) k_selcompact(
        const unsigned* __restrict__ keys, const unsigned* __restrict__ vals,
        const unsigned* __restrict__ sel, const unsigned* __restrict__ chist,
        unsigned* __restrict__ okeys, unsigned* __restrict__ ovals, int n, int G) {
    __shared__ unsigned s[256];
    __shared__ unsigned wsum[4];
    __shared__ unsigned runS;
    unsigned T = sel[0];
    int t = threadIdx.x, wave = t >> 6, lane = t & 63;
    unsigned v = (t < G) ? chist[t] : 0u;           // G <= 256
    s[t] = v; __syncthreads();
    for (int o = 1; o < 256; o <<= 1) {
        unsigned u = (t >= o) ? s[t - o] : 0u;
        __syncthreads();
        s[t] += u; __syncthreads();
    }
    if (t == (int)blockIdx.x) runS = s[t] - v;
    __syncthreads();
    int cbase = blockIdx.x * CHUNK;
    for (int gix = 0; gix < CHUNK / 256; ++gix) {
        int i = cbase + gix * 256 + t;
        bool selq = (i < n) && ((keys[i] >> 21) <= T);
        unsigned long long mk = __ballot(selq);
        unsigned pre = (unsigned)__popcll(mk & ((1ull << lane) - 1ull));
        if (lane == 0) wsum[wave] = (unsigned)__popcll(mk);
        __syncthreads();
        unsigned wb = runS;
        #pragma unroll
        for (int w = 0; w < 4; ++w) if (w < wave) wb += wsum[w];
        if (selq) { unsigned pos = wb + pre; okeys[pos] = keys[i]; ovals[pos] = vals[i]; }
        __syncthreads();
        if (t == 0) runS += wsum[0] + wsum[1] + wsum[2] + wsum[3];
        __syncthreads();
    }
}

// ---------------- radix sort: per-chunk histogram (vec4, runtime-count aware) ----------------
__global__ void k_hist(const unsigned* __restrict__ keys, unsigned* __restrict__ hist,
                       int n, const unsigned* __restrict__ pn, int shift) {
    if (pn) n = (int)*pn;
    __shared__ unsigned h[256];
    int t = threadIdx.x;
    h[t] = 0;
    __syncthreads();
    int base = blockIdx.x * CHUNK;
    if (base + CHUNK <= n) {
        #pragma unroll
        for (int it = 0; it < CHUNK / 1024; ++it) {
            int i = base + it * 1024 + t * 4;
            const unsigned* p = keys + i;
            unsigned k0 = p[0], k1 = p[1], k2 = p[2], k3 = p[3];
            atomicAdd(&h[(k0 >> shift) & 255u], 1u);
            atomicAdd(&h[(k1 >> shift) & 255u], 1u);
            atomicAdd(&h[(k2 >> shift) & 255u], 1u);
            atomicAdd(&h[(k3 >> shift) & 255u], 1u);
        }
    } else {
        for (int i = base + t; i < n; i += 256)
            atomicAdd(&h[(keys[i] >> shift) & 255u], 1u);
    }
    __syncthreads();
    hist[blockIdx.x * 256 + t] = h[t];
}

// ---------------- radix sort: stable scatter (4 waves; internal base scan) ----------------
__global__ void __launch_bounds__(256) k_scatter(const unsigned* __restrict__ keys,
                                                 const unsigned* __restrict__ vals,
                                                 unsigned* __restrict__ okeys,
                                                 unsigned* __restrict__ ovals,
                                                 const unsigned* __restrict__ offs,
                                                 const unsigned* __restrict__ tot,
                                                 int n, const unsigned* __restrict__ pn,
                                                 int shift) {
    if (pn) n = (int)*pn;
    if ((int)blockIdx.x * CHUNK >= n) return;
    __shared__ unsigned run[256];
    __shared__ unsigned offl[256];
    __shared__ unsigned wcnt[4][256];
    __shared__ unsigned wpre[4][256];
    __shared__ unsigned sc[256];
    int t = threadIdx.x;
    int wave = t >> 6, lane = t & 63;
    {   // digit base = exclusive scan of tot
        unsigned v = tot[t];
        sc[t] = v; __syncthreads();
        for (int o = 1; o < 256; o <<= 1) {
            unsigned u = (t >= o) ? sc[t - o] : 0u;
            __syncthreads();
            sc[t] += u; __syncthreads();
        }
        offl[t] = offs[(size_t)blockIdx.x * 256 + t] + (sc[t] - v);
        run[t] = 0;
    }
    __syncthreads();
    int cbase = blockIdx.x * CHUNK;
    const int GROUPS = CHUNK / 256;
    for (int gix = 0; gix < GROUPS; ++gix) {
        int i = cbase + gix * 256 + t;
        bool active = i < n;
        unsigned k = active ? keys[i] : 0u;
        unsigned v = active ? vals[i] : 0u;
        unsigned d = (k >> shift) & 255u;
        unsigned long long amask = __ballot(active);
        unsigned long long bb[8];
        #pragma unroll
        for (int bit = 0; bit < 8; ++bit) bb[bit] = __ballot(active && ((d >> bit) & 1u));
        unsigned long long m = amask;
        #pragma unroll
        for (int bit = 0; bit < 8; ++bit) m &= ((d >> bit) & 1u) ? bb[bit] : ~bb[bit];
        unsigned rk = (unsigned)__popcll(m & ((1ull << lane) - 1ull));
        #pragma unroll
        for (int j = 0; j < 4; ++j) {
            unsigned dd = (unsigned)lane + j * 64u;
            unsigned long long mm = amask;
            #pragma unroll
            for (int bit = 0; bit < 8; ++bit) mm &= ((dd >> bit) & 1u) ? bb[bit] : ~bb[bit];
            wcnt[wave][dd] = (unsigned)__popcll(mm);
        }
        __syncthreads();
        {
            unsigned r = run[t];
            unsigned c0 = wcnt[0][t], c1 = wcnt[1][t], c2 = wcnt[2][t], c3 = wcnt[3][t];
            wpre[0][t] = r;
            wpre[1][t] = r + c0;
            wpre[2][t] = r + c0 + c1;
            wpre[3][t] = r + c0 + c1 + c2;
            run[t] = r + c0 + c1 + c2 + c3;
        }
        __syncthreads();
        if (active) {
            unsigned pos = offl[d] + wpre[wave][d] + rk;
            okeys[pos] = k;
            ovals[pos] = v;
        }
    }
}

// ---------------- pool gather (+ optional new_idx, + optional next-sort keys) ----------------
__global__ void k_pool(const unsigned* __restrict__ perm, const float* __restrict__ xin,
                       const float* __restrict__ consts, int ci,
                       float* __restrict__ xout, int* __restrict__ newidx, int k,
                       unsigned* __restrict__ okeys, unsigned* __restrict__ ovals, int nci) {
    int r = blockIdx.x * blockDim.x + threadIdx.x;
    if (r >= k) return;
    unsigned p = perm[r];
    float xv = xin[p];
    float s = tanhf(xv * consts[ci]);
    float o = xv * s;
    xout[r] = o;
    if (newidx) newidx[p] = r;
    if (okeys) {
        float s2 = tanhf(o * consts[nci]);
        okeys[r] = key_desc(s2);
        ovals[r] = (unsigned)r;
    }
}

// ---------------- single-block: 4-pass radix sort + pool3 + MLP + log_softmax ----------------
__global__ void __launch_bounds__(1024) k_smallsort(
        unsigned* __restrict__ kIn, unsigned* __restrict__ vIn,
        unsigned* __restrict__ kTmp, unsigned* __restrict__ vTmp,
        int n, int k3, const float* __restrict__ xin,
        const float* __restrict__ consts, int ci,
        const float* __restrict__ Wl1, const float* __restrict__ bl1,
        const float* __restrict__ Wl2, const float* __restrict__ bl2,
        float* __restrict__ out) {
    __shared__ unsigned hist[256], sc[256], run[256], offl[256];
    __shared__ unsigned wcnt[16][256];
    __shared__ unsigned wpre[16][256];
    int t = threadIdx.x;
    int wave = t >> 6, lane = t & 63;
    unsigned *ki = kIn, *vi = vIn, *ko = kTmp, *vo = vTmp;
    for (int p = 0; p < 4; ++p) {
        int shift = p * 8;
        if (t < 256) hist[t] = 0;
        __syncthreads();
        for (int i = t; i < n; i += 1024)
            atomicAdd(&hist[(ki[i] >> shift) & 255u], 1u);
        __syncthreads();
        if (t < 256) sc[t] = hist[t];
        __syncthreads();
        for (int o = 1; o < 256; o <<= 1) {
            unsigned u = 0;
            if (t < 256 && t >= o) u = sc[t - o];
            __syncthreads();
            if (t < 256) sc[t] += u;
            __syncthreads();
        }
        if (t < 256) { offl[t] = sc[t] - hist[t]; run[t] = 0; }
        __syncthreads();
        int G = (n + 1023) / 1024;
        for (int gix = 0; gix < G; ++gix) {
            int i = gix * 1024 + t;
            bool active = i < n;
            unsigned k = active ? ki[i] : 0u;
            unsigned v = active ? vi[i] : 0u;
            unsigned d = (k >> shift) & 255u;
            unsigned long long amask = __ballot(active);
            unsigned long long bb[8];
            #pragma unroll
            for (int bit = 0; bit < 8; ++bit) bb[bit] = __ballot(active && ((d >> bit) & 1u));
            unsigned long long m = amask;
            #pragma unroll
            for (int bit = 0; bit < 8; ++bit) m &= ((d >> bit) & 1u) ? bb[bit] : ~bb[bit];
            unsigned rk = (unsigned)__popcll(m & ((1ull << lane) - 1ull));
            #pragma unroll
            for (int j = 0; j < 4; ++j) {
                unsigned dd = (unsigned)lane + j * 64u;
                unsigned long long mm = amask;
                #pragma unroll
                for (int bit = 0; bit < 8; ++bit) mm &= ((dd >> bit) & 1u) ? bb[bit] : ~bb[bit];
                wcnt[wave][dd] = (unsigned)__popcll(mm);
            }
            __syncthreads();
            if (t < 256) {
                unsigned acc = run[t];
                #pragma unroll
                for (int w2 = 0; w2 < 16; ++w2) { wpre[w2][t] = acc; acc += wcnt[w2][t]; }
                run[t] = acc;
            }
            __syncthreads();
            if (active) {
                unsigned pos = offl[d] + wpre[wave][d] + rk;
                ko[pos] = k;
                vo[pos] = v;
            }
            __syncthreads();
        }
        unsigned* tp;
        tp = ki; ki = ko; ko = tp;
        tp = vi; vi = vo; vo = tp;
        __syncthreads();
    }
    float c = consts[ci];
    float b20 = bl2[0], b21 = bl2[1];
    for (int r = t; r < k3; r += 1024) {
        unsigned pidx = vIn[r];
        float xv = xin[pidx];
        float s = tanhf(xv * c);
        float o = xv * s;
        float l0 = b20, l1 = b21;
        #pragma unroll
        for (int j = 0; j < 8; ++j) {
            float h = fmaxf(o * Wl1[j] + bl1[j], 0.0f);
            l0 += h * Wl2[2 * j];
            l1 += h * Wl2[2 * j + 1];
        }
        float mx = fmaxf(l0, l1);
        float lse = mx + logf(expf(l0 - mx) + expf(l1 - mx));
        out[2 * r]     = l0 - lse;
        out[2 * r + 1] = l1 - lse;
    }
}

// ---------------- host-side radix sort driver ----------------
static void sort_pairs(hipStream_t stream, unsigned* kI, unsigned* vI,
                       unsigned* kT, unsigned* vT, unsigned* hist, unsigned* offs,
                       unsigned* tot, int n, int G, const unsigned* pn) {
    unsigned *ki = kI, *vi = vI, *ko = kT, *vo = vT;
    for (int p = 0; p < 4; ++p) {
        int shift = p * 8;
        k_hist<<<G, 256, 0, stream>>>(ki, hist, n, pn, shift);
        k_scanA<<<256, 256, 0, stream>>>(hist, offs, tot, G, 0u);
        k_scatter<<<G, 256, 0, stream>>>(ki, vi, ko, vo, offs, tot, n, pn, shift);
        unsigned* t;
        t = ki; ki = ko; ko = t;
        t = vi; vi = vo; vo = t;
    }
    // 4 passes (even): result ends in the (kI,vI) buffers
}

extern "C" void kernel_launch(void* const* d_in, const int* in_sizes, int n_in,
                              void* d_out, int out_size, void* d_ws, size_t ws_size,
                              hipStream_t stream) {
    const float* x   = (const float*)d_in[0];
    const float* ea  = (const float*)d_in[1];
    const int*   src = (const int*)d_in[2];
    const int*   dst = (const int*)d_in[3];
    const float *Wf1 = (const float*)d_in[5],  *bf1 = (const float*)d_in[6];
    const float *Ws1 = (const float*)d_in[7],  *bs1 = (const float*)d_in[8];
    const float *g1  = (const float*)d_in[9],  *be1 = (const float*)d_in[10];
    const float *Wf2 = (const float*)d_in[11], *bf2 = (const float*)d_in[12];
    const float *Ws2 = (const float*)d_in[13], *bs2 = (const float*)d_in[14];
    const float *g2  = (const float*)d_in[15], *be2 = (const float*)d_in[16];
    const float *pw1 = (const float*)d_in[17], *pw2 = (const float*)d_in[18], *pw3 = (const float*)d_in[19];
    const float *Wl1 = (const float*)d_in[20], *bl1 = (const float*)d_in[21];
    const float *Wl2 = (const float*)d_in[22], *bl2 = (const float*)d_in[23];

    const int N  = in_sizes[0];
    const int E  = in_sizes[1];
    const int K1 = 100000, K2 = 10000, K3 = 2500;

    // ---- workspace layout ----
    size_t off = 0;
    auto alloc = [&](size_t bytes) { size_t o = off; off = (off + bytes + 255) & ~(size_t)255; return o; };
    char* ws = (char*)d_ws;
    size_t o_x1    = alloc((size_t)N * 4);
    size_t o_nidx  = alloc((size_t)N * 4);
    size_t o_stats = alloc(256);
    size_t o_const = alloc(256);
    size_t o_tot   = alloc(4096);
    size_t o_gh    = alloc(8192);
    size_t o_x2    = alloc((size_t)K1 * 4);
    size_t o_x3    = alloc((size_t)K1 * 4);
    size_t o_ag2   = alloc((size_t)K1 * 4);
    size_t o_x4    = alloc((size_t)K2 * 4);
    size_t o_ag1   = alloc((size_t)N * 4);
    size_t o_arena = off;

    // sort scratch (overlay B, live from k_bn onward)
    int G1 = (N + CHUNK - 1) / CHUNK;
    size_t s_kA = 0;
    size_t s_vA = s_kA + (((size_t)N * 4 + 255) & ~(size_t)255);
    size_t s_kB = s_vA + (((size_t)N * 4 + 255) & ~(size_t)255);
    size_t s_vB = s_kB + (((size_t)N * 4 + 255) & ~(size_t)255);
    size_t s_h  = s_vB + (((size_t)N * 4 + 255) & ~(size_t)255);
    size_t s_o  = s_h  + (((size_t)G1 * 256 * 4 + 255) & ~(size_t)255);
    size_t sortSz = s_o + (size_t)G1 * 256 * 4;

    // conv1 partition scratch (overlay A): pick split H; pad-aware rec sizing
    int H = 0, Eh = 0;
    size_t p_rec = 0, p_eh = 0, p_eo = 0;
    for (int h = 1; h <= 8; h <<= 1) {
        int eh_ = (E + h - 1) / h;
        eh_ = (eh_ + RND - 1) & ~(RND - 1);
        int gc_ = (eh_ + EPB - 1) / EPB;
        size_t recB = (((size_t)eh_ + (size_t)gc_ * NB2 * FG + NB2 * FG) * 8 + 255) & ~(size_t)255;
        size_t ehB  = (((size_t)gc_ * NB2 * 4) + 255) & ~(size_t)255;
        size_t eoB  = (((size_t)gc_ * NB2 * 4) + 255) & ~(size_t)255;
        size_t partSz = recB + ehB + eoB;
        size_t arenaSz = partSz > sortSz ? partSz : sortSz;
        if (o_arena + arenaSz <= ws_size && N <= (NB2 << BSH)) {
            H = h; Eh = eh_;
            p_rec = 0; p_eh = p_rec + recB; p_eo = p_eh + ehB;
            break;
        }
    }

    float*    x1     = (float*)(ws + o_x1);
    int*      nidx   = (int*)(ws + o_nidx);
    float*    stats  = (float*)(ws + o_stats);
    float*    consts = (float*)(ws + o_const);
    unsigned* tot    = (unsigned*)(ws + o_tot);
    unsigned* selp   = tot + 512;
    unsigned* ghist  = (unsigned*)(ws + o_gh);
    float*    x2     = (float*)(ws + o_x2);
    float*    x3     = (float*)(ws + o_x3);
    float*    aggr2  = (float*)(ws + o_ag2);
    float*    x4     = (float*)(ws + o_x4);
    float*    aggr1  = (float*)(ws + o_ag1);
    unsigned* kA     = (unsigned*)(ws + o_arena + s_kA);
    unsigned* vA     = (unsigned*)(ws + o_arena + s_vA);
    unsigned* kB     = (unsigned*)(ws + o_arena + s_kB);
    unsigned* vB     = (unsigned*)(ws + o_arena + s_vB);
    unsigned* hist   = (unsigned*)(ws + o_arena + s_h);
    unsigned* offs   = (unsigned*)(ws + o_arena + s_o);

    // stats + ghist zeroed in k_consts; nidx/-1 + aggr2/0 in first k_bn
    k_consts<<<3, 256, 0, stream>>>(pw1, pw2, pw3, consts, stats, ghist,
                                    in_sizes[17], in_sizes[18], in_sizes[19]);

    // ---- cgconv 1 (atomic-free partition path) ----
    if (H > 0) {
        uint2*    rec = (uint2*)(ws + o_arena + p_rec);
        unsigned* eh  = (unsigned*)(ws + o_arena + p_eh);
        unsigned* eo  = (unsigned*)(ws + o_arena + p_eo);
        int NBN = (N + (1 << BSH) - 1) >> BSH;
        for (int h = 0; h < H; ++h) {
            int e0 = h * Eh;
            int e1 = e0 + Eh; if (e1 > E) e1 = E;
            if (e0 >= e1) break;
            int GCh = (e1 - e0 + EPB - 1) / EPB;
            k_ehist2<<<GCh, 256, 0, stream>>>(dst, eh, e0, e1);
            k_scanA<<<NB2, 256, 0, stream>>>(eh, eo, tot, GCh, (unsigned)(FG - 1));
            k_part<<<GCh, 256, 0, stream>>>(x, ea, src, dst, Wf1, bf1, Ws1, bs1,
                                            eo, tot, eh, rec, e0, e1);
            k_aggr2<<<NBN, 256, 0, stream>>>(rec, tot, aggr1, stats, N,
                                             h > 0, h == H - 1 ? 1 : 0);
        }
    } else {
        hipMemsetAsync(aggr1, 0, (size_t)N * 4, stream);
        k_conv1<<<(E + 255) / 256, 256, 0, stream>>>(x, ea, src, dst, Wf1, bf1, Ws1, bs1, aggr1, E);
        k_stats<<<1024, 256, 0, stream>>>(aggr1, N, stats);
    }
    k_bn<<<(N + 255) / 256, 256, 0, stream>>>(aggr1, x, stats, g1, be1, x1, N, 1.0f / (float)N,
                                              consts, 0, kA, vA, nidx, aggr2, K1);

    // ---- pool 1 : top 100K of 1M via select + compact + small sort ----
    k_ghist<<<256, 256, 0, stream>>>(kA, ghist, N);
    k_findT<<<1, 256, 0, stream>>>(ghist, selp, K1);
    k_selcnt<<<G1, 256, 0, stream>>>(kA, selp, hist, N);
    k_selcompact<<<G1, 256, 0, stream>>>(kA, vA, selp, hist, kB, vB, N, G1);
    sort_pairs(stream, kB, vB, kA, vA, hist, offs, tot, N, G1, selp + 1);  // ends in kB/vB
    k_pool<<<(K1 + 255) / 256, 256, 0, stream>>>(vB, x1, consts, 0, x2, nidx, K1,
                                                 (unsigned*)nullptr, (unsigned*)nullptr, 0);

    // ---- cgconv 2 (filtered edges; sparse atomics) ----
    k_conv2<<<(E / 4 + 255) / 256, 256, 0, stream>>>(x2, ea, src, dst, nidx,
                                                     Wf2, bf2, Ws2, bs2, aggr2, E);
    k_stats<<<256, 256, 0, stream>>>(aggr2, K1, stats + 2);
    k_bn<<<(K1 + 255) / 256, 256, 0, stream>>>(aggr2, x2, stats + 2, g2, be2, x3, K1, 1.0f / (float)K1,
                                               consts, 1, kA, vA,
                                               (int*)nullptr, (float*)nullptr, 0);

    // ---- pool 2 : top 10K of 100K (full sort; emits pool-3 keys into kB/vB) ----
    sort_pairs(stream, kA, vA, kB, vB, hist, offs, tot, K1,
               (K1 + CHUNK - 1) / CHUNK, (const unsigned*)nullptr);   // ends in kA/vA
    k_pool<<<(K2 + 255) / 256, 256, 0, stream>>>(vA, x3, consts, 1, x4, (int*)nullptr, K2,
                                                 kB, vB, 2);

    // ---- pool 3 + sort + MLP + log_softmax : one single-block kernel ----
    k_smallsort<<<1, 1024, 0, stream>>>(kB, vB, kA, vA, K2, K3, x4, consts, 2,
                                        Wl1, bl1, Wl2, bl2, (float*)d_out);
}